// Round 17
// baseline (806.036 us; speedup 1.0000x reference)
//
#include <hip/hip_runtime.h>

#define AS1 __attribute__((address_space(1)))
#define AS3 __attribute__((address_space(3)))

typedef __bf16 bf16;
using bf16x8 = __attribute__((ext_vector_type(8))) __bf16;
using bf16x4 = __attribute__((ext_vector_type(4))) __bf16;
using bf16x2 = __attribute__((ext_vector_type(2))) __bf16;
using f32x4  = __attribute__((ext_vector_type(4))) float;

// Problem constants: B=1, S=2048, D=3072, H=24, HD=128, FFN=8192

__device__ inline float wsum(float v) {
#pragma unroll
  for (int o = 32; o; o >>= 1) v += __shfl_xor(v, o, 64);
  return v;
}

// ---------------------------------------------------------------------------
// gemm256 — K-loop byte-identical to R11-R16 (single barrier/phase, vmcnt(6);
// do NOT refactor LDS decl or loop body — R8/R9 lesson).
// EPI: 0=f32, 1=bf16, 2=fused silu(w1)*w3 with 16-granular interleaved B.
// ---------------------------------------------------------------------------
template <int EPI>
__global__ __launch_bounds__(512, 1) void gemm256(
    const bf16* __restrict__ A, const bf16* __restrict__ Bt, void* __restrict__ Cv,
    int K, int lda, int ldb, int ldc, long long kOff, long long sC) {
  __shared__ bf16 lds[2][2][256 * 64];  // [buf][A/B][row*64+col]
  const int t = threadIdx.x;
  const int lane = t & 63, wid = t >> 6;
  const int wm = wid >> 2, wn = wid & 3;
  const int row16 = lane & 15, kg = lane >> 4;
  const int m0 = blockIdx.x * 256, n0 = blockIdx.y * 256;
  const int NT = K >> 6;
  const int sgran = (lane & 7) ^ (lane >> 3);  // pre-swizzled source granule
  A += (long long)blockIdx.z * kOff;
  Bt += (long long)blockIdx.z * kOff;

  auto stageA = [&](int buf, int r, int tk) {
    const int wrow = ((wid & 4) << 5) + (r << 5) + ((wid & 3) << 3);  // wave-uniform
    __builtin_amdgcn_global_load_lds(
        (const AS1 void*)(A + (long long)(m0 + wrow + (lane >> 3)) * lda + tk * 64 +
                          (sgran << 3)),
        (AS3 void*)&lds[buf][0][wrow * 64], 16, 0, 0);
  };
  auto stageB = [&](int buf, int r, int tk) {
    const int wrow = ((wid & 4) << 5) + (r << 5) + ((wid & 3) << 3);
    __builtin_amdgcn_global_load_lds(
        (const AS1 void*)(Bt + (long long)(n0 + wrow + (lane >> 3)) * ldb + tk * 64 +
                          (sgran << 3)),
        (AS3 void*)&lds[buf][1][wrow * 64], 16, 0, 0);
  };

  f32x4 acc[8][4];
#pragma unroll
  for (int i = 0; i < 8; ++i)
#pragma unroll
    for (int j = 0; j < 4; ++j) acc[i][j] = (f32x4){0.f, 0.f, 0.f, 0.f};

  // prologue: stage tile0 fully (8), tile1 rounds 0-2 (6)
#pragma unroll
  for (int r = 0; r < 4; ++r) { stageA(0, r, 0); stageB(0, r, 0); }
#pragma unroll
  for (int r = 0; r < 3; ++r) { stageA(1, r, 1); stageB(1, r, 1); }

  bf16x8 bfr[4][2], af[2][2];

  for (int kt = 0; kt < NT; ++kt) {
    const int cb = kt & 1, nb = cb ^ 1;
    if (kt + 1 < NT) asm volatile("s_waitcnt vmcnt(6)" ::: "memory");
    else             asm volatile("s_waitcnt vmcnt(0)" ::: "memory");
    __builtin_amdgcn_s_barrier();

    // ---- phase 0: stage(t+1) round 3; read all B frags + A quad 0
    if (kt + 1 < NT) { stageA(nb, 3, kt + 1); stageB(nb, 3, kt + 1); }
#pragma unroll
    for (int ni = 0; ni < 4; ++ni)
#pragma unroll
      for (int kk = 0; kk < 2; ++kk) {
        const int r = wn * 64 + ni * 16 + row16;
        bfr[ni][kk] = *(const bf16x8*)&lds[cb][1][r * 64 + (((kk * 4 + kg) ^ (r & 7)) << 3)];
      }
#pragma unroll
    for (int mi = 0; mi < 2; ++mi)
#pragma unroll
      for (int kk = 0; kk < 2; ++kk) {
        const int r = wm * 128 + mi * 16 + row16;
        af[mi][kk] = *(const bf16x8*)&lds[cb][0][r * 64 + (((kk * 4 + kg) ^ (r & 7)) << 3)];
      }
    asm volatile("s_waitcnt lgkmcnt(0)" ::: "memory");
    __builtin_amdgcn_s_setprio(1);
#pragma unroll
    for (int kk = 0; kk < 2; ++kk)
#pragma unroll
      for (int mi = 0; mi < 2; ++mi)
#pragma unroll
        for (int ni = 0; ni < 4; ++ni)
          acc[mi][ni] =
              __builtin_amdgcn_mfma_f32_16x16x32_bf16(af[mi][kk], bfr[ni][kk], acc[mi][ni], 0, 0, 0);
    __builtin_amdgcn_s_setprio(0);

    // ---- phases 1..3: stage(t+2) round q-1; read A quad q
#pragma unroll
    for (int q = 1; q < 4; ++q) {
      __builtin_amdgcn_s_barrier();
      if (kt + 2 < NT) { stageA(cb, q - 1, kt + 2); stageB(cb, q - 1, kt + 2); }
#pragma unroll
      for (int mi = 0; mi < 2; ++mi)
#pragma unroll
        for (int kk = 0; kk < 2; ++kk) {
          const int r = wm * 128 + q * 32 + mi * 16 + row16;
          af[mi][kk] = *(const bf16x8*)&lds[cb][0][r * 64 + (((kk * 4 + kg) ^ (r & 7)) << 3)];
        }
      asm volatile("s_waitcnt lgkmcnt(0)" ::: "memory");
      __builtin_amdgcn_s_setprio(1);
#pragma unroll
      for (int kk = 0; kk < 2; ++kk)
#pragma unroll
        for (int mi = 0; mi < 2; ++mi)
#pragma unroll
          for (int ni = 0; ni < 4; ++ni)
            acc[q * 2 + mi][ni] = __builtin_amdgcn_mfma_f32_16x16x32_bf16(
                af[mi][kk], bfr[ni][kk], acc[q * 2 + mi][ni], 0, 0, 0);
      __builtin_amdgcn_s_setprio(0);
    }
  }

  float* Cf = (float*)Cv;
  bf16* Cb = (bf16*)Cv;
  const long long cz = (long long)blockIdx.z * sC;
  if constexpr (EPI == 2) {
#pragma unroll
    for (int mf = 0; mf < 8; ++mf)
#pragma unroll
      for (int np = 0; np < 2; ++np)
#pragma unroll
        for (int rr = 0; rr < 4; ++rr) {
          const int row = m0 + wm * 128 + (mf >> 1) * 32 + (mf & 1) * 16 + kg * 4 + rr;
          const int col = (n0 >> 1) + wn * 32 + np * 16 + row16;
          const float a = acc[mf][np * 2][rr];
          const float b = acc[mf][np * 2 + 1][rr];
          const float sl = a / (1.f + __expf(-a));
          Cb[cz + (long long)row * ldc + col] = (bf16)(sl * b);
        }
  } else {
#pragma unroll
    for (int mf = 0; mf < 8; ++mf)
#pragma unroll
      for (int ni = 0; ni < 4; ++ni)
#pragma unroll
        for (int rr = 0; rr < 4; ++rr) {
          const int row = m0 + wm * 128 + (mf >> 1) * 32 + (mf & 1) * 16 + kg * 4 + rr;
          const int col = n0 + wn * 64 + ni * 16 + row16;
          const long long idx = cz + (long long)row * ldc + col;
          const float v = acc[mf][ni][rr];
          if constexpr (EPI == 0) Cf[idx] = v;
          else Cb[idx] = (bf16)v;
        }
  }
}

// ---------------------------------------------------------------------------
// gemm192 — UNTOUCHED (healthy since R10).  Two barriers per phase, vmcnt(6),
// single LDS array (A rows 0-255, B rows 256-447).  Split-K via blockIdx.z.
// EPI: 0=f32 store, 1=bf16 store.
// ---------------------------------------------------------------------------
template <int EPI>
__global__ __launch_bounds__(512, 1) void gemm192(
    const bf16* __restrict__ A, const bf16* __restrict__ Bt, void* __restrict__ Cv,
    int K, int lda, int ldb, int ldc, long long kOff, long long sC) {
  __shared__ bf16 lds[2][448 * 64];  // [buf][A(0-255)|B(256-447)][col]
  const int t = threadIdx.x;
  const int lane = t & 63, wid = t >> 6;
  const int wm = wid >> 2, wn = wid & 3;
  const int row16 = lane & 15, kg = lane >> 4;
  const int m0 = blockIdx.x * 256, n0 = blockIdx.y * 192;
  const int NT = K >> 6;
  const int sgran = (lane & 7) ^ (lane >> 3);
  A += (long long)blockIdx.z * kOff;
  Bt += (long long)blockIdx.z * kOff;

  auto stageA = [&](int buf, int r, int tk) {
    const int wrow = ((wid & 4) << 5) + (r << 5) + ((wid & 3) << 3);
    __builtin_amdgcn_global_load_lds(
        (const AS1 void*)(A + (long long)(m0 + wrow + (lane >> 3)) * lda + tk * 64 +
                          (sgran << 3)),
        (AS3 void*)&lds[buf][wrow * 64], 16, 0, 0);
  };
  auto stageB = [&](int buf, int r, int tk) {
    const int wrow = r * 64 + wid * 8;  // r in 0..2 covers 192 rows
    __builtin_amdgcn_global_load_lds(
        (const AS1 void*)(Bt + (long long)(n0 + wrow + (lane >> 3)) * ldb + tk * 64 +
                          (sgran << 3)),
        (AS3 void*)&lds[buf][(256 + wrow) * 64], 16, 0, 0);
  };

  f32x4 acc[8][3];
#pragma unroll
  for (int i = 0; i < 8; ++i)
#pragma unroll
    for (int j = 0; j < 3; ++j) acc[i][j] = (f32x4){0.f, 0.f, 0.f, 0.f};

  // prologue: tile0 fully (4A+3B), tile1 rounds 0-2 (3A+3B)
#pragma unroll
  for (int r = 0; r < 4; ++r) stageA(0, r, 0);
#pragma unroll
  for (int r = 0; r < 3; ++r) stageB(0, r, 0);
#pragma unroll
  for (int r = 0; r < 3; ++r) { stageA(1, r, 1); stageB(1, r, 1); }

  bf16x8 bfr[3][2], af[2][2];

  for (int kt = 0; kt < NT; ++kt) {
    const int cb = kt & 1, nb = cb ^ 1;
    if (kt + 1 < NT) asm volatile("s_waitcnt vmcnt(6)" ::: "memory");
    else             asm volatile("s_waitcnt vmcnt(0)" ::: "memory");
    __builtin_amdgcn_s_barrier();

    // ---- phase 0: stage(t+1) A round 3; read all B frags + A quad 0
    if (kt + 1 < NT) stageA(nb, 3, kt + 1);
#pragma unroll
    for (int ni = 0; ni < 3; ++ni)
#pragma unroll
      for (int kk = 0; kk < 2; ++kk) {
        const int r = wn * 48 + ni * 16 + row16;
        bfr[ni][kk] =
            *(const bf16x8*)&lds[cb][(256 + r) * 64 + (((kk * 4 + kg) ^ (r & 7)) << 3)];
      }
#pragma unroll
    for (int mi = 0; mi < 2; ++mi)
#pragma unroll
      for (int kk = 0; kk < 2; ++kk) {
        const int r = wm * 128 + mi * 16 + row16;
        af[mi][kk] = *(const bf16x8*)&lds[cb][r * 64 + (((kk * 4 + kg) ^ (r & 7)) << 3)];
      }
    __builtin_amdgcn_s_barrier();
    asm volatile("s_waitcnt lgkmcnt(0)" ::: "memory");
    __builtin_amdgcn_s_setprio(1);
#pragma unroll
    for (int kk = 0; kk < 2; ++kk)
#pragma unroll
      for (int mi = 0; mi < 2; ++mi)
#pragma unroll
        for (int ni = 0; ni < 3; ++ni)
          acc[mi][ni] =
              __builtin_amdgcn_mfma_f32_16x16x32_bf16(af[mi][kk], bfr[ni][kk], acc[mi][ni], 0, 0, 0);
    __builtin_amdgcn_s_setprio(0);

    // ---- phases 1..3: stage(t+2) round q-1 (A and B); read A quad q
#pragma unroll
    for (int q = 1; q < 4; ++q) {
      __builtin_amdgcn_s_barrier();
      if (kt + 2 < NT) { stageA(cb, q - 1, kt + 2); stageB(cb, q - 1, kt + 2); }
#pragma unroll
      for (int mi = 0; mi < 2; ++mi)
#pragma unroll
        for (int kk = 0; kk < 2; ++kk) {
          const int r = wm * 128 + q * 32 + mi * 16 + row16;
          af[mi][kk] = *(const bf16x8*)&lds[cb][r * 64 + (((kk * 4 + kg) ^ (r & 7)) << 3)];
        }
      __builtin_amdgcn_s_barrier();
      asm volatile("s_waitcnt lgkmcnt(0)" ::: "memory");
      __builtin_amdgcn_s_setprio(1);
#pragma unroll
      for (int kk = 0; kk < 2; ++kk)
#pragma unroll
        for (int mi = 0; mi < 2; ++mi)
#pragma unroll
          for (int ni = 0; ni < 3; ++ni)
            acc[q * 2 + mi][ni] = __builtin_amdgcn_mfma_f32_16x16x32_bf16(
                af[mi][kk], bfr[ni][kk], acc[q * 2 + mi][ni], 0, 0, 0);
      __builtin_amdgcn_s_setprio(0);
    }
  }

  float* Cf = (float*)Cv;
  bf16* Cb = (bf16*)Cv;
  const long long cz = (long long)blockIdx.z * sC;
#pragma unroll
  for (int mf = 0; mf < 8; ++mf)
#pragma unroll
    for (int ni = 0; ni < 3; ++ni)
#pragma unroll
      for (int rr = 0; rr < 4; ++rr) {
        const int row = m0 + wm * 128 + (mf >> 1) * 32 + (mf & 1) * 16 + kg * 4 + rr;
        const int col = n0 + wn * 48 + ni * 16 + row16;
        const long long idx = cz + (long long)row * ldc + col;
        const float v = acc[mf][ni][rr];
        if constexpr (EPI == 0) Cf[idx] = v;
        else Cb[idx] = (bf16)v;
      }
}

// sum two bf16 split-K partial buffers: out[i] = p[i] + p[i + 18874368]
__global__ __launch_bounds__(256) void qkvsum_k(const bf16* __restrict__ p,
                                                bf16* __restrict__ out) {
  const long long i8 = ((long long)blockIdx.x * 256 + threadIdx.x) * 8;
  const bf16x8 a = *(const bf16x8*)&p[i8];
  const bf16x8 b = *(const bf16x8*)&p[i8 + 18874368LL];
  bf16x8 o;
#pragma unroll
  for (int j = 0; j < 8; ++j) o[j] = (bf16)((float)a[j] + (float)b[j]);
  *(bf16x8*)&out[i8] = o;
}

// ---------------------------------------------------------------------------
// Flash attention, KV-split.  Grid (16 q-tiles, 24 heads, 2 kv-splits).
// Writes unnormalized O (bf16) + per-row (m, l) f32.  Byte-identical to R16.
// ---------------------------------------------------------------------------
__global__ __launch_bounds__(256) void flash_attn_k(const bf16* __restrict__ qkv,
                                                    const bf16* __restrict__ vt,
                                                    bf16* __restrict__ Opb,
                                                    float* __restrict__ mlp) {
  __shared__ bf16 Ks[64 * 128];
  __shared__ bf16 Vs[128 * 64];
  __shared__ bf16 Ps[4 * 32 * 64];
  const int t = threadIdx.x, lane = t & 63, wid = t >> 6;
  const int row16 = lane & 15, kg = lane >> 4;
  const int q0 = blockIdx.x * 128;
  const int h = blockIdx.y;
  const int z = blockIdx.z;
  const bf16* Qp = qkv + h * 128;
  const bf16* Kp = qkv + 3072 + h * 128;
  const bf16* Vt = vt + (long long)h * 262144;
  const float iscale = 0.08838834764831845f;

  bf16x8 qf[2][4];
#pragma unroll
  for (int mi = 0; mi < 2; ++mi)
#pragma unroll
    for (int kc = 0; kc < 4; ++kc)
      qf[mi][kc] = *(const bf16x8*)&Qp[(long long)(q0 + wid * 32 + mi * 16 + row16) * 9216 +
                                       kc * 32 + kg * 8];
  bf16x8 ones;
#pragma unroll
  for (int j = 0; j < 8; ++j) ones[j] = (bf16)1.0f;

  f32x4 oacc[2][8];
#pragma unroll
  for (int mi = 0; mi < 2; ++mi)
#pragma unroll
    for (int nd = 0; nd < 8; ++nd) oacc[mi][nd] = (f32x4){0.f, 0.f, 0.f, 0.f};
  f32x4 lacc[2] = {(f32x4){0.f, 0.f, 0.f, 0.f}, (f32x4){0.f, 0.f, 0.f, 0.f}};
  float mst[2][4];
#pragma unroll
  for (int mi = 0; mi < 2; ++mi)
#pragma unroll
    for (int r = 0; r < 4; ++r) mst[mi][r] = -1e30f;

  bf16* Pw = &Ps[wid * 2048];
  const int kvbase = z << 10;

  for (int kv0 = kvbase; kv0 < kvbase + 1024; kv0 += 64) {
#pragma unroll
    for (int p = 0; p < 4; ++p) {
      const int gi = p * 256 + t;
      const int row = gi >> 4, g = gi & 15;
      __builtin_amdgcn_global_load_lds(
          (const AS1 void*)(Kp + (long long)(kv0 + row) * 9216 + ((g ^ (row & 7)) << 3)),
          (AS3 void*)&Ks[(p * 256 + wid * 64) * 8], 16, 0, 0);
    }
#pragma unroll
    for (int p = 0; p < 4; ++p) {
      const int gi = p * 256 + t;
      const int row = gi >> 3, g = gi & 7;
      __builtin_amdgcn_global_load_lds(
          (const AS1 void*)(Vt + (long long)row * 2048 + kv0 + ((g ^ (row & 7)) << 3)),
          (AS3 void*)&Vs[(p * 256 + wid * 64) * 8], 16, 0, 0);
    }
    __syncthreads();

    f32x4 sacc[2][4];
#pragma unroll
    for (int mi = 0; mi < 2; ++mi)
#pragma unroll
      for (int nf = 0; nf < 4; ++nf) sacc[mi][nf] = (f32x4){0.f, 0.f, 0.f, 0.f};
#pragma unroll
    for (int kc = 0; kc < 4; ++kc) {
      bf16x8 kf[4];
#pragma unroll
      for (int nf = 0; nf < 4; ++nf) {
        const int row = nf * 16 + row16;
        kf[nf] = *(const bf16x8*)&Ks[(row * 16 + ((kc * 4 + kg) ^ (row & 7))) * 8];
      }
#pragma unroll
      for (int mi = 0; mi < 2; ++mi)
#pragma unroll
        for (int nf = 0; nf < 4; ++nf)
          sacc[mi][nf] =
              __builtin_amdgcn_mfma_f32_16x16x32_bf16(qf[mi][kc], kf[nf], sacc[mi][nf], 0, 0, 0);
    }

    float fac[2][4];
#pragma unroll
    for (int mi = 0; mi < 2; ++mi)
#pragma unroll
      for (int r = 0; r < 4; ++r) {
        float rm = sacc[mi][0][r];
#pragma unroll
        for (int nf = 1; nf < 4; ++nf) rm = fmaxf(rm, sacc[mi][nf][r]);
        rm = fmaxf(rm, __shfl_xor(rm, 1, 64));
        rm = fmaxf(rm, __shfl_xor(rm, 2, 64));
        rm = fmaxf(rm, __shfl_xor(rm, 4, 64));
        rm = fmaxf(rm, __shfl_xor(rm, 8, 64));
        const float mnew = fmaxf(mst[mi][r], rm * iscale);
        fac[mi][r] = __expf(mst[mi][r] - mnew);
        mst[mi][r] = mnew;
#pragma unroll
        for (int nf = 0; nf < 4; ++nf)
          sacc[mi][nf][r] = __expf(sacc[mi][nf][r] * iscale - mnew);
      }
#pragma unroll
    for (int mi = 0; mi < 2; ++mi)
#pragma unroll
      for (int r = 0; r < 4; ++r) {
        lacc[mi][r] *= fac[mi][r];
#pragma unroll
        for (int nd = 0; nd < 8; ++nd) oacc[mi][nd][r] *= fac[mi][r];
      }

#pragma unroll
    for (int mi = 0; mi < 2; ++mi)
#pragma unroll
      for (int nf = 0; nf < 4; ++nf)
#pragma unroll
        for (int r = 0; r < 4; ++r) {
          const int row = mi * 16 + kg * 4 + r;
          const int col = nf * 16 + row16;
          Pw[(row * 8 + ((col >> 3) ^ (row & 7))) * 8 + (col & 7)] = (bf16)sacc[mi][nf][r];
        }

#pragma unroll
    for (int kvc = 0; kvc < 2; ++kvc) {
      bf16x8 pf[2], vf[8];
#pragma unroll
      for (int mi = 0; mi < 2; ++mi) {
        const int row = mi * 16 + row16;
        pf[mi] = *(const bf16x8*)&Pw[(row * 8 + ((kvc * 4 + kg) ^ (row & 7))) * 8];
      }
#pragma unroll
      for (int nd = 0; nd < 8; ++nd) {
        const int row = nd * 16 + row16;
        vf[nd] = *(const bf16x8*)&Vs[(row * 8 + ((kvc * 4 + kg) ^ (row & 7))) * 8];
      }
#pragma unroll
      for (int mi = 0; mi < 2; ++mi) {
        lacc[mi] = __builtin_amdgcn_mfma_f32_16x16x32_bf16(pf[mi], ones, lacc[mi], 0, 0, 0);
#pragma unroll
        for (int nd = 0; nd < 8; ++nd)
          oacc[mi][nd] =
              __builtin_amdgcn_mfma_f32_16x16x32_bf16(pf[mi], vf[nd], oacc[mi][nd], 0, 0, 0);
      }
    }
    __syncthreads();
  }

  // epilogue: store unnormalized O (bf16) and per-row (m, l)
  bf16* Oz = Opb + (long long)z * 6291456;
#pragma unroll
  for (int mi = 0; mi < 2; ++mi)
#pragma unroll
    for (int nd = 0; nd < 8; ++nd)
#pragma unroll
      for (int r = 0; r < 4; ++r) {
        const int row = q0 + wid * 32 + mi * 16 + kg * 4 + r;
        const int col = h * 128 + nd * 16 + row16;
        Oz[(long long)row * 3072 + col] = (bf16)oacc[mi][nd][r];
      }
  if (row16 == 0) {
#pragma unroll
    for (int mi = 0; mi < 2; ++mi)
#pragma unroll
      for (int r = 0; r < 4; ++r) {
        const int s = q0 + wid * 32 + mi * 16 + kg * 4 + r;
        const long long mi2 = ((long long)z * 49152 + s * 24 + h) * 2;
        mlp[mi2] = mst[mi][r];
        mlp[mi2 + 1] = lacc[mi][r];
      }
  }
}

// combine the 2 KV splits: attn = (O0*a0 + O1*a1) / (l0*a0 + l1*a1)
__global__ __launch_bounds__(256) void fa_combine_k(const bf16* __restrict__ Opb,
                                                    const float* __restrict__ mlp,
                                                    bf16* __restrict__ attn) {
  const int t = threadIdx.x, lane = t & 63, wid = t >> 6;
  const int pair = blockIdx.x * 4 + wid;  // s*24 + h
  const int s = pair / 24, h = pair % 24;
  const float2 ml0 = *(const float2*)&mlp[(long long)pair * 2];
  const float2 ml1 = *(const float2*)&mlp[(49152LL + pair) * 2];
  const float m = fmaxf(ml0.x, ml1.x);
  const float a0 = __expf(ml0.x - m), a1 = __expf(ml1.x - m);
  const float inv = 1.f / (ml0.y * a0 + ml1.y * a1);
  const long long base = (long long)s * 3072 + h * 128 + lane * 2;
  const bf16x2 o0 = *(const bf16x2*)&Opb[base];
  const bf16x2 o1 = *(const bf16x2*)&Opb[6291456LL + base];
  bf16x2 o;
  o[0] = (bf16)(((float)o0[0] * a0 + (float)o1[0] * a1) * inv);
  o[1] = (bf16)(((float)o0[1] * a0 + (float)o1[1] * a1) * inv);
  *(bf16x2*)&attn[base] = o;
}

// ---------------------------------------------------------------------------
// convAll: all 7 weight conversions (f32 [R][C] -> bf16 [C][R]) in one launch.
// interleave16: out row = c0*2 + ((cl>>4)<<5) + (cl&15) + roff (w1/w3
// 16-granular interleave for the fused FFN-up epilogue).
// ---------------------------------------------------------------------------
__device__ inline void convT_tile(const float* __restrict__ in, bf16* __restrict__ out,
                                  int R, int C, int bx, int by, int interleave16,
                                  int roff) {
  __shared__ float tile[64][65];
  const int t = threadIdx.x;
  const int r0 = by * 64, c0 = bx * 64;
#pragma unroll
  for (int it = 0; it < 4; ++it) {
    const int idx = it * 256 + t;
    const int rl = idx >> 4, c4 = (idx & 15) << 2;
    const float4 v = *(const float4*)&in[(long long)(r0 + rl) * C + c0 + c4];
    tile[rl][c4 + 0] = v.x;
    tile[rl][c4 + 1] = v.y;
    tile[rl][c4 + 2] = v.z;
    tile[rl][c4 + 3] = v.w;
  }
  __syncthreads();
#pragma unroll
  for (int it = 0; it < 4; ++it) {
    const int idx = it * 256 + t;
    const int cl = idx >> 4, r4 = (idx & 15) << 2;
    bf16x4 o;
    o[0] = (bf16)tile[r4 + 0][cl];
    o[1] = (bf16)tile[r4 + 1][cl];
    o[2] = (bf16)tile[r4 + 2][cl];
    o[3] = (bf16)tile[r4 + 3][cl];
    const long long orow = interleave16 ? (long long)(c0 * 2 + ((cl >> 4) << 5) +
                                                      (cl & 15) + roff)
                                        : (long long)(c0 + cl);
    *(bf16x4*)&out[orow * R + r0 + r4] = o;
  }
}

__global__ __launch_bounds__(256) void convAll(
    const float* __restrict__ wq, const float* __restrict__ wk,
    const float* __restrict__ wv, const float* __restrict__ wo,
    const float* __restrict__ w1, const float* __restrict__ w3,
    const float* __restrict__ w2, bf16* __restrict__ wqkvT, bf16* __restrict__ woT,
    bf16* __restrict__ w13T, bf16* __restrict__ w2T) {
  const int id = blockIdx.x;
  if (id < 9216) {
    const int m = id / 2304, l = id % 2304;
    const float* in = m == 0 ? wq : m == 1 ? wk : m == 2 ? wv : wo;
    bf16* out = m < 3 ? wqkvT + (long long)m * 9437184 : woT;
    convT_tile(in, out, 3072, 3072, l % 48, l / 48, 0, 0);
  } else if (id < 21504) {
    int l = id - 9216;
    const int m = l / 6144;
    l %= 6144;
    convT_tile(m ? w3 : w1, w13T, 3072, 8192, l % 128, l / 128, 1, m * 16);
  } else {
    const int l = id - 21504;
    convT_tile(w2, w2T, 8192, 3072, l % 48, l / 48, 0, 0);
  }
}

// cos/sin tables: [S][64]
__global__ __launch_bounds__(256) void ropetab_k(const int* __restrict__ ids,
                                                 float* __restrict__ cosT,
                                                 float* __restrict__ sinT) {
  const int i = blockIdx.x * 256 + threadIdx.x;
  const int s = i >> 6, j = i & 63;
  int ax, fi;
  float d;
  if (j < 8) { ax = 0; fi = j; d = 16.f; }
  else if (j < 36) { ax = 1; fi = j - 8; d = 56.f; }
  else { ax = 2; fi = j - 36; d = 56.f; }
  const float freq = exp2f(-16.f * (float)fi / d);
  const float ang = (float)ids[s * 3 + ax] * freq;
  cosT[i] = cosf(ang);
  sinT[i] = sinf(ang);
}

__global__ __launch_bounds__(256) void adaln_kernel(const float* __restrict__ ain,
                                                    const float* __restrict__ W,
                                                    const float* __restrict__ b,
                                                    float* __restrict__ out) {
  __shared__ float a[256];
  const int t = threadIdx.x;
  a[t] = ain[t];
  __syncthreads();
  const int n = blockIdx.x * 256 + t;
  float acc = b[n];
  for (int k = 0; k < 256; ++k) acc = fmaf(a[k], W[(long long)k * 12288 + n], acc);
  const int chunk = n / 3072;
  out[n] = (chunk & 1) ? tanhf(acc) : (1.f + acc);
}

// xs = rmsnorm(x, w, 1e-6) * scale  -> bf16
__global__ __launch_bounds__(256) void rmsnorm_scale_k(const float* __restrict__ x,
                                                       const float* __restrict__ w,
                                                       const float* __restrict__ scale,
                                                       bf16* __restrict__ out) {
  __shared__ float red[4];
  const int t = threadIdx.x, lane = t & 63, wid = t >> 6;
  const long long base = (long long)blockIdx.x * 3072;
  float v[12];
  float ss = 0.f;
#pragma unroll
  for (int ch = 0; ch < 3; ++ch) {
    const float4 f = *(const float4*)&x[base + ch * 1024 + t * 4];
    v[ch * 4 + 0] = f.x; v[ch * 4 + 1] = f.y; v[ch * 4 + 2] = f.z; v[ch * 4 + 3] = f.w;
    ss += f.x * f.x + f.y * f.y + f.z * f.z + f.w * f.w;
  }
  ss = wsum(ss);
  if (!lane) red[wid] = ss;
  __syncthreads();
  const float r = rsqrtf((red[0] + red[1] + red[2] + red[3]) / 3072.f + 1e-6f);
#pragma unroll
  for (int ch = 0; ch < 3; ++ch) {
    const int col = ch * 1024 + t * 4;
    bf16x4 o;
#pragma unroll
    for (int j = 0; j < 4; ++j) o[j] = (bf16)(v[ch * 4 + j] * r * w[col + j] * scale[col + j]);
    *(bf16x4*)&out[base + col] = o;
  }
}

// per (s,h): rmsnorm(QK_EPS) over 128 + RoPE, in place on q,k inside qkv buffer
__global__ __launch_bounds__(256) void qknorm_rope_k(bf16* __restrict__ qkv,
                                                     const float* __restrict__ cosT,
                                                     const float* __restrict__ sinT,
                                                     const float* __restrict__ wq,
                                                     const float* __restrict__ wk) {
  const int t = threadIdx.x, lane = t & 63, wid = t >> 6;
  const int idx = blockIdx.x * 4 + wid;
  const int s = idx / 24, h = idx % 24;
  const int isK = blockIdx.y;
  bf16* base = qkv + (long long)s * 9216 + isK * 3072 + h * 128;
  bf16x2 p = *(const bf16x2*)(base + 2 * lane);
  float xr = (float)p[0], xi = (float)p[1];
  const float ss = wsum(xr * xr + xi * xi);
  const float r = rsqrtf(ss / 128.f + 1e-5f);
  const float* w = isK ? wk : wq;
  const float2 wv = *(const float2*)&w[2 * lane];
  xr *= r * wv.x;
  xi *= r * wv.y;
  const float c = cosT[s * 64 + lane], sn = sinT[s * 64 + lane];
  bf16x2 o;
  o[0] = (bf16)(xr * c - xi * sn);
  o[1] = (bf16)(xr * sn + xi * c);
  *(bf16x2*)(base + 2 * lane) = o;
}

// vt[h][d][s] = qkv[s][6144 + h*128 + d]
__global__ __launch_bounds__(256) void vtrans_k(const bf16* __restrict__ qkv,
                                                bf16* __restrict__ vt) {
  __shared__ bf16 tile[64][72];
  const int t = threadIdx.x;
  const int s0 = blockIdx.x * 64, d0 = blockIdx.y * 64, h = blockIdx.z;
#pragma unroll
  for (int it = 0; it < 2; ++it) {
    const int idx = it * 256 + t;
    const int sl = idx >> 3, c8 = (idx & 7) << 3;
    const bf16x8 v =
        *(const bf16x8*)&qkv[(long long)(s0 + sl) * 9216 + 6144 + h * 128 + d0 + c8];
    *(bf16x8*)&tile[sl][c8] = v;
  }
  __syncthreads();
#pragma unroll
  for (int it = 0; it < 2; ++it) {
    const int idx = it * 256 + t;
    const int dl = idx >> 3, s8 = (idx & 7) << 3;
    bf16x8 o;
#pragma unroll
    for (int j = 0; j < 8; ++j) o[j] = tile[s8 + j][dl];
    *(bf16x8*)&vt[(long long)h * 262144 + (long long)(d0 + dl) * 2048 + s0 + s8] = o;
  }
}

// x1 = x + gate*rmsnorm(p0+p1, n2w, 1e-6); xf = rmsnorm(x1, f1w, 1e-6)*smlp (bf16)
// p0/p1 are bf16 split-K partials.
__global__ __launch_bounds__(256) void resid1_k(
    const float* __restrict__ x, const bf16* __restrict__ p0, const bf16* __restrict__ p1,
    const float* __restrict__ n2w, const float* __restrict__ gate,
    const float* __restrict__ f1w, const float* __restrict__ smlp,
    float* __restrict__ x1, bf16* __restrict__ xf) {
  __shared__ float red[8];
  const int t = threadIdx.x, lane = t & 63, wid = t >> 6;
  const long long base = (long long)blockIdx.x * 3072;
  float av[12];
  float ss = 0.f;
#pragma unroll
  for (int ch = 0; ch < 3; ++ch) {
    const bf16x4 f0 = *(const bf16x4*)&p0[base + ch * 1024 + t * 4];
    const bf16x4 f1 = *(const bf16x4*)&p1[base + ch * 1024 + t * 4];
#pragma unroll
    for (int j = 0; j < 4; ++j) {
      const float a = (float)f0[j] + (float)f1[j];
      av[ch * 4 + j] = a;
      ss += a * a;
    }
  }
  ss = wsum(ss);
  if (!lane) red[wid] = ss;
  __syncthreads();
  const float r = rsqrtf((red[0] + red[1] + red[2] + red[3]) / 3072.f + 1e-6f);
  float xv[12];
  float ss2 = 0.f;
#pragma unroll
  for (int ch = 0; ch < 3; ++ch) {
    const int col = ch * 1024 + t * 4;
    const float4 f = *(const float4*)&x[base + col];
    float4 o;
    o.x = f.x + gate[col + 0] * (av[ch * 4 + 0] * r * n2w[col + 0]);
    o.y = f.y + gate[col + 1] * (av[ch * 4 + 1] * r * n2w[col + 1]);
    o.z = f.z + gate[col + 2] * (av[ch * 4 + 2] * r * n2w[col + 2]);
    o.w = f.w + gate[col + 3] * (av[ch * 4 + 3] * r * n2w[col + 3]);
    *(float4*)&x1[base + col] = o;
    xv[ch * 4 + 0] = o.x; xv[ch * 4 + 1] = o.y; xv[ch * 4 + 2] = o.z; xv[ch * 4 + 3] = o.w;
    ss2 += o.x * o.x + o.y * o.y + o.z * o.z + o.w * o.w;
  }
  ss2 = wsum(ss2);
  if (!lane) red[4 + wid] = ss2;
  __syncthreads();
  const float r2 = rsqrtf((red[4] + red[5] + red[6] + red[7]) / 3072.f + 1e-6f);
#pragma unroll
  for (int ch = 0; ch < 3; ++ch) {
    const int col = ch * 1024 + t * 4;
    bf16x4 o;
#pragma unroll
    for (int j = 0; j < 4; ++j)
      o[j] = (bf16)(xv[ch * 4 + j] * r2 * f1w[col + j] * smlp[col + j]);
    *(bf16x4*)&xf[base + col] = o;
  }
}

// out = x1 + gate*rmsnorm(f0+f1, nw, 1e-6)  (f32 output; f0/f1 bf16 partials)
__global__ __launch_bounds__(256) void resid2_k(const float* __restrict__ x1,
                                                const bf16* __restrict__ f0,
                                                const bf16* __restrict__ f1,
                                                const float* __restrict__ nw,
                                                const float* __restrict__ gate,
                                                float* __restrict__ out) {
  __shared__ float red[4];
  const int t = threadIdx.x, lane = t & 63, wid = t >> 6;
  const long long base = (long long)blockIdx.x * 3072;
  float fv[12];
  float ss = 0.f;
#pragma unroll
  for (int ch = 0; ch < 3; ++ch) {
    const bf16x4 a = *(const bf16x4*)&f0[base + ch * 1024 + t * 4];
    const bf16x4 b = *(const bf16x4*)&f1[base + ch * 1024 + t * 4];
#pragma unroll
    for (int j = 0; j < 4; ++j) {
      const float v = (float)a[j] + (float)b[j];
      fv[ch * 4 + j] = v;
      ss += v * v;
    }
  }
  ss = wsum(ss);
  if (!lane) red[wid] = ss;
  __syncthreads();
  const float r = rsqrtf((red[0] + red[1] + red[2] + red[3]) / 3072.f + 1e-6f);
#pragma unroll
  for (int ch = 0; ch < 3; ++ch) {
    const int col = ch * 1024 + t * 4;
    const float4 f = *(const float4*)&x1[base + col];
    float4 o;
    o.x = f.x + gate[col + 0] * (fv[ch * 4 + 0] * r * nw[col + 0]);
    o.y = f.y + gate[col + 1] * (fv[ch * 4 + 1] * r * nw[col + 1]);
    o.z = f.z + gate[col + 2] * (fv[ch * 4 + 2] * r * nw[col + 2]);
    o.w = f.w + gate[col + 3] * (fv[ch * 4 + 3] * r * nw[col + 3]);
    *(float4*)&out[base + col] = o;
  }
}

extern "C" void kernel_launch(void* const* d_in, const int* in_sizes, int n_in,
                              void* d_out, int out_size, void* d_ws, size_t ws_size,
                              hipStream_t stream) {
  const float* x    = (const float*)d_in[0];
  const float* ain  = (const float*)d_in[1];
  const int* ids    = (const int*)d_in[3];
  const float* n1w  = (const float*)d_in[4];
  const float* n2w  = (const float*)d_in[5];
  const float* fn1w = (const float*)d_in[6];
  const float* fn2w = (const float*)d_in[7];
  const float* nqw  = (const float*)d_in[8];
  const float* nkw  = (const float*)d_in[9];
  const float* wq   = (const float*)d_in[10];
  const float* wk   = (const float*)d_in[11];
  const float* wv   = (const float*)d_in[12];
  const float* wo   = (const float*)d_in[13];
  const float* w1   = (const float*)d_in[14];
  const float* w2   = (const float*)d_in[15];
  const float* w3   = (const float*)d_in[16];
  const float* adw  = (const float*)d_in[17];
  const float* adb  = (const float*)d_in[18];

  if (ws_size < 395362304ULL) return;

  char* ws = (char*)d_ws;
  bf16* wqkvT = (bf16*)(ws + 0LL);             // [9216][3072]
  bf16* woT   = (bf16*)(ws + 56623104LL);      // [3072][3072]
  bf16* w13T  = (bf16*)(ws + 75497472LL);      // [16384][3072] 16-granular interleave
  bf16* w2T   = (bf16*)(ws + 176160768LL);     // [3072][8192]
  float* cosT = (float*)(ws + 226492416LL);    // [2048][64]
  float* sinT = (float*)(ws + 227016704LL);
  float* adv  = (float*)(ws + 227540992LL);    // [4][3072]
  bf16* xs    = (bf16*)(ws + 227590144LL);     // [2048][3072], reused as xf
  char* big   = ws + 240173056LL;              // overlay region (155.2 MB)
  float* x1   = (float*)(big);                 // [2048][3072] f32, long-lived
  bf16* qkv   = (bf16*)(big + 25165824LL);     // [2048][9216] combined
  bf16* qkvP  = (bf16*)(big + 62914560LL);     // [2][2048][9216] partials (dead after qkvsum)
  bf16* vt    = (bf16*)(big + 62914560LL);     // [24][128][2048] (qkvP dead; same as R16)
  bf16* attn  = (bf16*)(big + 75497472LL);     // [2048][3072]
  bf16* Opb   = (bf16*)(big + 88080384LL);     // [2][2048][3072] bf16 flash partials
  bf16* aoP   = (bf16*)(big + 88080384LL);     // [2][2048][3072] bf16 Wo partials (Opb dead)
  float* mlp  = (float*)(big + 138412032LL);   // [2][49152][2] (m,l)
  bf16* hbuf  = (bf16*)(big + 121634816LL);    // [2048][8192] bf16 (after aoP region)
  bf16* ffnP  = (bf16*)(big + 25165824LL);     // [2][2048][3072] bf16 (overlays qkv, dead)

  const dim3 b256(256);
  const dim3 b512(512);

  ropetab_k<<<dim3(512), b256, 0, stream>>>(ids, cosT, sinT);
  adaln_kernel<<<dim3(48), b256, 0, stream>>>(ain, adw, adb, adv);

  convAll<<<dim3(27648), b256, 0, stream>>>(wq, wk, wv, wo, w1, w3, w2, wqkvT, woT, w13T,
                                            w2T);

  rmsnorm_scale_k<<<dim3(2048), b256, 0, stream>>>(x, n1w, adv, xs);

  // QKV: split-K z=2 -> grid (8,48,2)=768 blocks = 3 exact rounds of half
  // blocks (was 384 = 1.5 rounds -> makespan 2 rounds).  Mechanism identical
  // to the proven Wo split-K; partials summed by the trivial qkvsum kernel,
  // so qknorm/vtrans/flash stay byte-identical to R16.
  gemm192<1><<<dim3(8, 48, 2), b512, 0, stream>>>(xs, wqkvT, qkvP, 1536, 3072, 3072, 9216,
                                                  1536LL, 18874368LL);
  qkvsum_k<<<dim3(9216), b256, 0, stream>>>(qkvP, qkv);

  qknorm_rope_k<<<dim3(12288, 2), b256, 0, stream>>>(qkv, cosT, sinT, nqw, nkw);
  vtrans_k<<<dim3(32, 2, 24), b256, 0, stream>>>(qkv, vt);

  // flash attention, 2-way KV split (bf16 partials) + combine
  flash_attn_k<<<dim3(16, 24, 2), b256, 0, stream>>>(qkv, vt, Opb, mlp);
  fa_combine_k<<<dim3(12288), b256, 0, stream>>>(Opb, mlp, attn);

  // Wo: attn @ woT^T, split-K 2, bf16 partials (gemm192: grid 256 exact)
  gemm192<1><<<dim3(8, 16, 2), b512, 0, stream>>>(attn, woT, aoP, 1536, 3072, 3072, 3072,
                                                  1536LL, 6291456LL);
  resid1_k<<<dim3(2048), b256, 0, stream>>>(x, aoP, aoP + 6291456LL, n2w, adv + 3072, fn1w,
                                            adv + 6144, x1, xs);
  // FFN up + fused silu-mul (16-granular interleave): xf @ w13T^T -> hbuf bf16
  gemm256<2><<<dim3(8, 64, 1), b512, 0, stream>>>(xs, w13T, hbuf, 3072, 3072, 3072, 8192,
                                                  0LL, 0LL);
  // FFN down: h @ w2T^T, split-K 2, bf16 partials (gemm192: grid 256 exact)
  gemm192<1><<<dim3(8, 16, 2), b512, 0, stream>>>(hbuf, w2T, ffnP, 4096, 8192, 8192, 3072,
                                                  4096LL, 6291456LL);
  resid2_k<<<dim3(2048), b256, 0, stream>>>(x1, ffnP, ffnP + 6291456LL, fn2w, adv + 9216,
                                            (float*)d_out);
}

// Round 18
// 795.641 us; speedup vs baseline: 1.0131x; 1.0131x over previous
//
#include <hip/hip_runtime.h>

#define AS1 __attribute__((address_space(1)))
#define AS3 __attribute__((address_space(3)))

typedef __bf16 bf16;
using bf16x8 = __attribute__((ext_vector_type(8))) __bf16;
using bf16x4 = __attribute__((ext_vector_type(4))) __bf16;
using bf16x2 = __attribute__((ext_vector_type(2))) __bf16;
using f32x4  = __attribute__((ext_vector_type(4))) float;

// Problem constants: B=1, S=2048, D=3072, H=24, HD=128, FFN=8192

__device__ inline float wsum(float v) {
#pragma unroll
  for (int o = 32; o; o >>= 1) v += __shfl_xor(v, o, 64);
  return v;
}

// ---------------------------------------------------------------------------
// gemm256 — K-loop byte-identical to R11-R17 (single barrier/phase, vmcnt(6);
// do NOT refactor LDS decl or loop body — R8/R9 lesson).
// EPI: 0=f32, 1=bf16, 2=fused silu(w1)*w3 with 16-granular interleaved B.
// ---------------------------------------------------------------------------
template <int EPI>
__global__ __launch_bounds__(512, 1) void gemm256(
    const bf16* __restrict__ A, const bf16* __restrict__ Bt, void* __restrict__ Cv,
    int K, int lda, int ldb, int ldc, long long kOff, long long sC) {
  __shared__ bf16 lds[2][2][256 * 64];  // [buf][A/B][row*64+col]
  const int t = threadIdx.x;
  const int lane = t & 63, wid = t >> 6;
  const int wm = wid >> 2, wn = wid & 3;
  const int row16 = lane & 15, kg = lane >> 4;
  const int m0 = blockIdx.x * 256, n0 = blockIdx.y * 256;
  const int NT = K >> 6;
  const int sgran = (lane & 7) ^ (lane >> 3);  // pre-swizzled source granule
  A += (long long)blockIdx.z * kOff;
  Bt += (long long)blockIdx.z * kOff;

  auto stageA = [&](int buf, int r, int tk) {
    const int wrow = ((wid & 4) << 5) + (r << 5) + ((wid & 3) << 3);  // wave-uniform
    __builtin_amdgcn_global_load_lds(
        (const AS1 void*)(A + (long long)(m0 + wrow + (lane >> 3)) * lda + tk * 64 +
                          (sgran << 3)),
        (AS3 void*)&lds[buf][0][wrow * 64], 16, 0, 0);
  };
  auto stageB = [&](int buf, int r, int tk) {
    const int wrow = ((wid & 4) << 5) + (r << 5) + ((wid & 3) << 3);
    __builtin_amdgcn_global_load_lds(
        (const AS1 void*)(Bt + (long long)(n0 + wrow + (lane >> 3)) * ldb + tk * 64 +
                          (sgran << 3)),
        (AS3 void*)&lds[buf][1][wrow * 64], 16, 0, 0);
  };

  f32x4 acc[8][4];
#pragma unroll
  for (int i = 0; i < 8; ++i)
#pragma unroll
    for (int j = 0; j < 4; ++j) acc[i][j] = (f32x4){0.f, 0.f, 0.f, 0.f};

  // prologue: stage tile0 fully (8), tile1 rounds 0-2 (6)
#pragma unroll
  for (int r = 0; r < 4; ++r) { stageA(0, r, 0); stageB(0, r, 0); }
#pragma unroll
  for (int r = 0; r < 3; ++r) { stageA(1, r, 1); stageB(1, r, 1); }

  bf16x8 bfr[4][2], af[2][2];

  for (int kt = 0; kt < NT; ++kt) {
    const int cb = kt & 1, nb = cb ^ 1;
    if (kt + 1 < NT) asm volatile("s_waitcnt vmcnt(6)" ::: "memory");
    else             asm volatile("s_waitcnt vmcnt(0)" ::: "memory");
    __builtin_amdgcn_s_barrier();

    // ---- phase 0: stage(t+1) round 3; read all B frags + A quad 0
    if (kt + 1 < NT) { stageA(nb, 3, kt + 1); stageB(nb, 3, kt + 1); }
#pragma unroll
    for (int ni = 0; ni < 4; ++ni)
#pragma unroll
      for (int kk = 0; kk < 2; ++kk) {
        const int r = wn * 64 + ni * 16 + row16;
        bfr[ni][kk] = *(const bf16x8*)&lds[cb][1][r * 64 + (((kk * 4 + kg) ^ (r & 7)) << 3)];
      }
#pragma unroll
    for (int mi = 0; mi < 2; ++mi)
#pragma unroll
      for (int kk = 0; kk < 2; ++kk) {
        const int r = wm * 128 + mi * 16 + row16;
        af[mi][kk] = *(const bf16x8*)&lds[cb][0][r * 64 + (((kk * 4 + kg) ^ (r & 7)) << 3)];
      }
    asm volatile("s_waitcnt lgkmcnt(0)" ::: "memory");
    __builtin_amdgcn_s_setprio(1);
#pragma unroll
    for (int kk = 0; kk < 2; ++kk)
#pragma unroll
      for (int mi = 0; mi < 2; ++mi)
#pragma unroll
        for (int ni = 0; ni < 4; ++ni)
          acc[mi][ni] =
              __builtin_amdgcn_mfma_f32_16x16x32_bf16(af[mi][kk], bfr[ni][kk], acc[mi][ni], 0, 0, 0);
    __builtin_amdgcn_s_setprio(0);

    // ---- phases 1..3: stage(t+2) round q-1; read A quad q
#pragma unroll
    for (int q = 1; q < 4; ++q) {
      __builtin_amdgcn_s_barrier();
      if (kt + 2 < NT) { stageA(cb, q - 1, kt + 2); stageB(cb, q - 1, kt + 2); }
#pragma unroll
      for (int mi = 0; mi < 2; ++mi)
#pragma unroll
        for (int kk = 0; kk < 2; ++kk) {
          const int r = wm * 128 + q * 32 + mi * 16 + row16;
          af[mi][kk] = *(const bf16x8*)&lds[cb][0][r * 64 + (((kk * 4 + kg) ^ (r & 7)) << 3)];
        }
      asm volatile("s_waitcnt lgkmcnt(0)" ::: "memory");
      __builtin_amdgcn_s_setprio(1);
#pragma unroll
      for (int kk = 0; kk < 2; ++kk)
#pragma unroll
        for (int mi = 0; mi < 2; ++mi)
#pragma unroll
          for (int ni = 0; ni < 4; ++ni)
            acc[q * 2 + mi][ni] = __builtin_amdgcn_mfma_f32_16x16x32_bf16(
                af[mi][kk], bfr[ni][kk], acc[q * 2 + mi][ni], 0, 0, 0);
      __builtin_amdgcn_s_setprio(0);
    }
  }

  float* Cf = (float*)Cv;
  bf16* Cb = (bf16*)Cv;
  const long long cz = (long long)blockIdx.z * sC;
  if constexpr (EPI == 2) {
#pragma unroll
    for (int mf = 0; mf < 8; ++mf)
#pragma unroll
      for (int np = 0; np < 2; ++np)
#pragma unroll
        for (int rr = 0; rr < 4; ++rr) {
          const int row = m0 + wm * 128 + (mf >> 1) * 32 + (mf & 1) * 16 + kg * 4 + rr;
          const int col = (n0 >> 1) + wn * 32 + np * 16 + row16;
          const float a = acc[mf][np * 2][rr];
          const float b = acc[mf][np * 2 + 1][rr];
          const float sl = a / (1.f + __expf(-a));
          Cb[cz + (long long)row * ldc + col] = (bf16)(sl * b);
        }
  } else {
#pragma unroll
    for (int mf = 0; mf < 8; ++mf)
#pragma unroll
      for (int ni = 0; ni < 4; ++ni)
#pragma unroll
        for (int rr = 0; rr < 4; ++rr) {
          const int row = m0 + wm * 128 + (mf >> 1) * 32 + (mf & 1) * 16 + kg * 4 + rr;
          const int col = n0 + wn * 64 + ni * 16 + row16;
          const long long idx = cz + (long long)row * ldc + col;
          const float v = acc[mf][ni][rr];
          if constexpr (EPI == 0) Cf[idx] = v;
          else Cb[idx] = (bf16)v;
        }
  }
}

// ---------------------------------------------------------------------------
// gemm192 — UNTOUCHED (healthy since R10).  Two barriers per phase, vmcnt(6),
// single LDS array (A rows 0-255, B rows 256-447).  Split-K via blockIdx.z.
// EPI: 0=f32 store, 1=bf16 store.
// ---------------------------------------------------------------------------
template <int EPI>
__global__ __launch_bounds__(512, 1) void gemm192(
    const bf16* __restrict__ A, const bf16* __restrict__ Bt, void* __restrict__ Cv,
    int K, int lda, int ldb, int ldc, long long kOff, long long sC) {
  __shared__ bf16 lds[2][448 * 64];  // [buf][A(0-255)|B(256-447)][col]
  const int t = threadIdx.x;
  const int lane = t & 63, wid = t >> 6;
  const int wm = wid >> 2, wn = wid & 3;
  const int row16 = lane & 15, kg = lane >> 4;
  const int m0 = blockIdx.x * 256, n0 = blockIdx.y * 192;
  const int NT = K >> 6;
  const int sgran = (lane & 7) ^ (lane >> 3);
  A += (long long)blockIdx.z * kOff;
  Bt += (long long)blockIdx.z * kOff;

  auto stageA = [&](int buf, int r, int tk) {
    const int wrow = ((wid & 4) << 5) + (r << 5) + ((wid & 3) << 3);
    __builtin_amdgcn_global_load_lds(
        (const AS1 void*)(A + (long long)(m0 + wrow + (lane >> 3)) * lda + tk * 64 +
                          (sgran << 3)),
        (AS3 void*)&lds[buf][wrow * 64], 16, 0, 0);
  };
  auto stageB = [&](int buf, int r, int tk) {
    const int wrow = r * 64 + wid * 8;  // r in 0..2 covers 192 rows
    __builtin_amdgcn_global_load_lds(
        (const AS1 void*)(Bt + (long long)(n0 + wrow + (lane >> 3)) * ldb + tk * 64 +
                          (sgran << 3)),
        (AS3 void*)&lds[buf][(256 + wrow) * 64], 16, 0, 0);
  };

  f32x4 acc[8][3];
#pragma unroll
  for (int i = 0; i < 8; ++i)
#pragma unroll
    for (int j = 0; j < 3; ++j) acc[i][j] = (f32x4){0.f, 0.f, 0.f, 0.f};

  // prologue: tile0 fully (4A+3B), tile1 rounds 0-2 (3A+3B)
#pragma unroll
  for (int r = 0; r < 4; ++r) stageA(0, r, 0);
#pragma unroll
  for (int r = 0; r < 3; ++r) stageB(0, r, 0);
#pragma unroll
  for (int r = 0; r < 3; ++r) { stageA(1, r, 1); stageB(1, r, 1); }

  bf16x8 bfr[3][2], af[2][2];

  for (int kt = 0; kt < NT; ++kt) {
    const int cb = kt & 1, nb = cb ^ 1;
    if (kt + 1 < NT) asm volatile("s_waitcnt vmcnt(6)" ::: "memory");
    else             asm volatile("s_waitcnt vmcnt(0)" ::: "memory");
    __builtin_amdgcn_s_barrier();

    // ---- phase 0: stage(t+1) A round 3; read all B frags + A quad 0
    if (kt + 1 < NT) stageA(nb, 3, kt + 1);
#pragma unroll
    for (int ni = 0; ni < 3; ++ni)
#pragma unroll
      for (int kk = 0; kk < 2; ++kk) {
        const int r = wn * 48 + ni * 16 + row16;
        bfr[ni][kk] =
            *(const bf16x8*)&lds[cb][(256 + r) * 64 + (((kk * 4 + kg) ^ (r & 7)) << 3)];
      }
#pragma unroll
    for (int mi = 0; mi < 2; ++mi)
#pragma unroll
      for (int kk = 0; kk < 2; ++kk) {
        const int r = wm * 128 + mi * 16 + row16;
        af[mi][kk] = *(const bf16x8*)&lds[cb][r * 64 + (((kk * 4 + kg) ^ (r & 7)) << 3)];
      }
    __builtin_amdgcn_s_barrier();
    asm volatile("s_waitcnt lgkmcnt(0)" ::: "memory");
    __builtin_amdgcn_s_setprio(1);
#pragma unroll
    for (int kk = 0; kk < 2; ++kk)
#pragma unroll
      for (int mi = 0; mi < 2; ++mi)
#pragma unroll
        for (int ni = 0; ni < 3; ++ni)
          acc[mi][ni] =
              __builtin_amdgcn_mfma_f32_16x16x32_bf16(af[mi][kk], bfr[ni][kk], acc[mi][ni], 0, 0, 0);
    __builtin_amdgcn_s_setprio(0);

    // ---- phases 1..3: stage(t+2) round q-1 (A and B); read A quad q
#pragma unroll
    for (int q = 1; q < 4; ++q) {
      __builtin_amdgcn_s_barrier();
      if (kt + 2 < NT) { stageA(cb, q - 1, kt + 2); stageB(cb, q - 1, kt + 2); }
#pragma unroll
      for (int mi = 0; mi < 2; ++mi)
#pragma unroll
        for (int kk = 0; kk < 2; ++kk) {
          const int r = wm * 128 + q * 32 + mi * 16 + row16;
          af[mi][kk] = *(const bf16x8*)&lds[cb][r * 64 + (((kk * 4 + kg) ^ (r & 7)) << 3)];
        }
      __builtin_amdgcn_s_barrier();
      asm volatile("s_waitcnt lgkmcnt(0)" ::: "memory");
      __builtin_amdgcn_s_setprio(1);
#pragma unroll
      for (int kk = 0; kk < 2; ++kk)
#pragma unroll
        for (int mi = 0; mi < 2; ++mi)
#pragma unroll
          for (int ni = 0; ni < 3; ++ni)
            acc[q * 2 + mi][ni] = __builtin_amdgcn_mfma_f32_16x16x32_bf16(
                af[mi][kk], bfr[ni][kk], acc[q * 2 + mi][ni], 0, 0, 0);
      __builtin_amdgcn_s_setprio(0);
    }
  }

  float* Cf = (float*)Cv;
  bf16* Cb = (bf16*)Cv;
  const long long cz = (long long)blockIdx.z * sC;
#pragma unroll
  for (int mf = 0; mf < 8; ++mf)
#pragma unroll
    for (int ni = 0; ni < 3; ++ni)
#pragma unroll
      for (int rr = 0; rr < 4; ++rr) {
        const int row = m0 + wm * 128 + (mf >> 1) * 32 + (mf & 1) * 16 + kg * 4 + rr;
        const int col = n0 + wn * 48 + ni * 16 + row16;
        const long long idx = cz + (long long)row * ldc + col;
        const float v = acc[mf][ni][rr];
        if constexpr (EPI == 0) Cf[idx] = v;
        else Cb[idx] = (bf16)v;
      }
}

// ---------------------------------------------------------------------------
// Flash attention, KV-split.  Grid (16 q-tiles, 24 heads, 2 kv-splits).
// Writes unnormalized O (bf16) + per-row (m, l) f32.  Byte-identical to
// R16/R17 (reads qkv buffer with row stride 9216).
// ---------------------------------------------------------------------------
__global__ __launch_bounds__(256) void flash_attn_k(const bf16* __restrict__ qkv,
                                                    const bf16* __restrict__ vt,
                                                    bf16* __restrict__ Opb,
                                                    float* __restrict__ mlp) {
  __shared__ bf16 Ks[64 * 128];
  __shared__ bf16 Vs[128 * 64];
  __shared__ bf16 Ps[4 * 32 * 64];
  const int t = threadIdx.x, lane = t & 63, wid = t >> 6;
  const int row16 = lane & 15, kg = lane >> 4;
  const int q0 = blockIdx.x * 128;
  const int h = blockIdx.y;
  const int z = blockIdx.z;
  const bf16* Qp = qkv + h * 128;
  const bf16* Kp = qkv + 3072 + h * 128;
  const bf16* Vt = vt + (long long)h * 262144;
  const float iscale = 0.08838834764831845f;

  bf16x8 qf[2][4];
#pragma unroll
  for (int mi = 0; mi < 2; ++mi)
#pragma unroll
    for (int kc = 0; kc < 4; ++kc)
      qf[mi][kc] = *(const bf16x8*)&Qp[(long long)(q0 + wid * 32 + mi * 16 + row16) * 9216 +
                                       kc * 32 + kg * 8];
  bf16x8 ones;
#pragma unroll
  for (int j = 0; j < 8; ++j) ones[j] = (bf16)1.0f;

  f32x4 oacc[2][8];
#pragma unroll
  for (int mi = 0; mi < 2; ++mi)
#pragma unroll
    for (int nd = 0; nd < 8; ++nd) oacc[mi][nd] = (f32x4){0.f, 0.f, 0.f, 0.f};
  f32x4 lacc[2] = {(f32x4){0.f, 0.f, 0.f, 0.f}, (f32x4){0.f, 0.f, 0.f, 0.f}};
  float mst[2][4];
#pragma unroll
  for (int mi = 0; mi < 2; ++mi)
#pragma unroll
    for (int r = 0; r < 4; ++r) mst[mi][r] = -1e30f;

  bf16* Pw = &Ps[wid * 2048];
  const int kvbase = z << 10;

  for (int kv0 = kvbase; kv0 < kvbase + 1024; kv0 += 64) {
#pragma unroll
    for (int p = 0; p < 4; ++p) {
      const int gi = p * 256 + t;
      const int row = gi >> 4, g = gi & 15;
      __builtin_amdgcn_global_load_lds(
          (const AS1 void*)(Kp + (long long)(kv0 + row) * 9216 + ((g ^ (row & 7)) << 3)),
          (AS3 void*)&Ks[(p * 256 + wid * 64) * 8], 16, 0, 0);
    }
#pragma unroll
    for (int p = 0; p < 4; ++p) {
      const int gi = p * 256 + t;
      const int row = gi >> 3, g = gi & 7;
      __builtin_amdgcn_global_load_lds(
          (const AS1 void*)(Vt + (long long)row * 2048 + kv0 + ((g ^ (row & 7)) << 3)),
          (AS3 void*)&Vs[(p * 256 + wid * 64) * 8], 16, 0, 0);
    }
    __syncthreads();

    f32x4 sacc[2][4];
#pragma unroll
    for (int mi = 0; mi < 2; ++mi)
#pragma unroll
      for (int nf = 0; nf < 4; ++nf) sacc[mi][nf] = (f32x4){0.f, 0.f, 0.f, 0.f};
#pragma unroll
    for (int kc = 0; kc < 4; ++kc) {
      bf16x8 kf[4];
#pragma unroll
      for (int nf = 0; nf < 4; ++nf) {
        const int row = nf * 16 + row16;
        kf[nf] = *(const bf16x8*)&Ks[(row * 16 + ((kc * 4 + kg) ^ (row & 7))) * 8];
      }
#pragma unroll
      for (int mi = 0; mi < 2; ++mi)
#pragma unroll
        for (int nf = 0; nf < 4; ++nf)
          sacc[mi][nf] =
              __builtin_amdgcn_mfma_f32_16x16x32_bf16(qf[mi][kc], kf[nf], sacc[mi][nf], 0, 0, 0);
    }

    float fac[2][4];
#pragma unroll
    for (int mi = 0; mi < 2; ++mi)
#pragma unroll
      for (int r = 0; r < 4; ++r) {
        float rm = sacc[mi][0][r];
#pragma unroll
        for (int nf = 1; nf < 4; ++nf) rm = fmaxf(rm, sacc[mi][nf][r]);
        rm = fmaxf(rm, __shfl_xor(rm, 1, 64));
        rm = fmaxf(rm, __shfl_xor(rm, 2, 64));
        rm = fmaxf(rm, __shfl_xor(rm, 4, 64));
        rm = fmaxf(rm, __shfl_xor(rm, 8, 64));
        const float mnew = fmaxf(mst[mi][r], rm * iscale);
        fac[mi][r] = __expf(mst[mi][r] - mnew);
        mst[mi][r] = mnew;
#pragma unroll
        for (int nf = 0; nf < 4; ++nf)
          sacc[mi][nf][r] = __expf(sacc[mi][nf][r] * iscale - mnew);
      }
#pragma unroll
    for (int mi = 0; mi < 2; ++mi)
#pragma unroll
      for (int r = 0; r < 4; ++r) {
        lacc[mi][r] *= fac[mi][r];
#pragma unroll
        for (int nd = 0; nd < 8; ++nd) oacc[mi][nd][r] *= fac[mi][r];
      }

#pragma unroll
    for (int mi = 0; mi < 2; ++mi)
#pragma unroll
      for (int nf = 0; nf < 4; ++nf)
#pragma unroll
        for (int r = 0; r < 4; ++r) {
          const int row = mi * 16 + kg * 4 + r;
          const int col = nf * 16 + row16;
          Pw[(row * 8 + ((col >> 3) ^ (row & 7))) * 8 + (col & 7)] = (bf16)sacc[mi][nf][r];
        }

#pragma unroll
    for (int kvc = 0; kvc < 2; ++kvc) {
      bf16x8 pf[2], vf[8];
#pragma unroll
      for (int mi = 0; mi < 2; ++mi) {
        const int row = mi * 16 + row16;
        pf[mi] = *(const bf16x8*)&Pw[(row * 8 + ((kvc * 4 + kg) ^ (row & 7))) * 8];
      }
#pragma unroll
      for (int nd = 0; nd < 8; ++nd) {
        const int row = nd * 16 + row16;
        vf[nd] = *(const bf16x8*)&Vs[(row * 8 + ((kvc * 4 + kg) ^ (row & 7))) * 8];
      }
#pragma unroll
      for (int mi = 0; mi < 2; ++mi) {
        lacc[mi] = __builtin_amdgcn_mfma_f32_16x16x32_bf16(pf[mi], ones, lacc[mi], 0, 0, 0);
#pragma unroll
        for (int nd = 0; nd < 8; ++nd)
          oacc[mi][nd] =
              __builtin_amdgcn_mfma_f32_16x16x32_bf16(pf[mi], vf[nd], oacc[mi][nd], 0, 0, 0);
      }
    }
    __syncthreads();
  }

  // epilogue: store unnormalized O (bf16) and per-row (m, l)
  bf16* Oz = Opb + (long long)z * 6291456;
#pragma unroll
  for (int mi = 0; mi < 2; ++mi)
#pragma unroll
    for (int nd = 0; nd < 8; ++nd)
#pragma unroll
      for (int r = 0; r < 4; ++r) {
        const int row = q0 + wid * 32 + mi * 16 + kg * 4 + r;
        const int col = h * 128 + nd * 16 + row16;
        Oz[(long long)row * 3072 + col] = (bf16)oacc[mi][nd][r];
      }
  if (row16 == 0) {
#pragma unroll
    for (int mi = 0; mi < 2; ++mi)
#pragma unroll
      for (int r = 0; r < 4; ++r) {
        const int s = q0 + wid * 32 + mi * 16 + kg * 4 + r;
        const long long mi2 = ((long long)z * 49152 + s * 24 + h) * 2;
        mlp[mi2] = mst[mi][r];
        mlp[mi2 + 1] = lacc[mi][r];
      }
  }
}

// combine the 2 KV splits: attn = (O0*a0 + O1*a1) / (l0*a0 + l1*a1)
__global__ __launch_bounds__(256) void fa_combine_k(const bf16* __restrict__ Opb,
                                                    const float* __restrict__ mlp,
                                                    bf16* __restrict__ attn) {
  const int t = threadIdx.x, lane = t & 63, wid = t >> 6;
  const int pair = blockIdx.x * 4 + wid;  // s*24 + h
  const int s = pair / 24, h = pair % 24;
  const float2 ml0 = *(const float2*)&mlp[(long long)pair * 2];
  const float2 ml1 = *(const float2*)&mlp[(49152LL + pair) * 2];
  const float m = fmaxf(ml0.x, ml1.x);
  const float a0 = __expf(ml0.x - m), a1 = __expf(ml1.x - m);
  const float inv = 1.f / (ml0.y * a0 + ml1.y * a1);
  const long long base = (long long)s * 3072 + h * 128 + lane * 2;
  const bf16x2 o0 = *(const bf16x2*)&Opb[base];
  const bf16x2 o1 = *(const bf16x2*)&Opb[6291456LL + base];
  bf16x2 o;
  o[0] = (bf16)(((float)o0[0] * a0 + (float)o1[0] * a1) * inv);
  o[1] = (bf16)(((float)o0[1] * a0 + (float)o1[1] * a1) * inv);
  *(bf16x2*)&attn[base] = o;
}

// ---------------------------------------------------------------------------
// convAll: all 7 weight conversions (f32 [R][C] -> bf16 [C][R]) in one launch.
// interleave16: out row = c0*2 + ((cl>>4)<<5) + (cl&15) + roff (w1/w3
// 16-granular interleave for the fused FFN-up epilogue).
// ---------------------------------------------------------------------------
__device__ inline void convT_tile(const float* __restrict__ in, bf16* __restrict__ out,
                                  int R, int C, int bx, int by, int interleave16,
                                  int roff) {
  __shared__ float tile[64][65];
  const int t = threadIdx.x;
  const int r0 = by * 64, c0 = bx * 64;
#pragma unroll
  for (int it = 0; it < 4; ++it) {
    const int idx = it * 256 + t;
    const int rl = idx >> 4, c4 = (idx & 15) << 2;
    const float4 v = *(const float4*)&in[(long long)(r0 + rl) * C + c0 + c4];
    tile[rl][c4 + 0] = v.x;
    tile[rl][c4 + 1] = v.y;
    tile[rl][c4 + 2] = v.z;
    tile[rl][c4 + 3] = v.w;
  }
  __syncthreads();
#pragma unroll
  for (int it = 0; it < 4; ++it) {
    const int idx = it * 256 + t;
    const int cl = idx >> 4, r4 = (idx & 15) << 2;
    bf16x4 o;
    o[0] = (bf16)tile[r4 + 0][cl];
    o[1] = (bf16)tile[r4 + 1][cl];
    o[2] = (bf16)tile[r4 + 2][cl];
    o[3] = (bf16)tile[r4 + 3][cl];
    const long long orow = interleave16 ? (long long)(c0 * 2 + ((cl >> 4) << 5) +
                                                      (cl & 15) + roff)
                                        : (long long)(c0 + cl);
    *(bf16x4*)&out[orow * R + r0 + r4] = o;
  }
}

__global__ __launch_bounds__(256) void convAll(
    const float* __restrict__ wq, const float* __restrict__ wk,
    const float* __restrict__ wv, const float* __restrict__ wo,
    const float* __restrict__ w1, const float* __restrict__ w3,
    const float* __restrict__ w2, bf16* __restrict__ wqkvT, bf16* __restrict__ woT,
    bf16* __restrict__ w13T, bf16* __restrict__ w2T) {
  const int id = blockIdx.x;
  if (id < 9216) {
    const int m = id / 2304, l = id % 2304;
    const float* in = m == 0 ? wq : m == 1 ? wk : m == 2 ? wv : wo;
    bf16* out = m < 3 ? wqkvT + (long long)m * 9437184 : woT;
    convT_tile(in, out, 3072, 3072, l % 48, l / 48, 0, 0);
  } else if (id < 21504) {
    int l = id - 9216;
    const int m = l / 6144;
    l %= 6144;
    convT_tile(m ? w3 : w1, w13T, 3072, 8192, l % 128, l / 128, 1, m * 16);
  } else {
    const int l = id - 21504;
    convT_tile(w2, w2T, 8192, 3072, l % 48, l / 48, 0, 0);
  }
}

// cos/sin tables: [S][64]
__global__ __launch_bounds__(256) void ropetab_k(const int* __restrict__ ids,
                                                 float* __restrict__ cosT,
                                                 float* __restrict__ sinT) {
  const int i = blockIdx.x * 256 + threadIdx.x;
  const int s = i >> 6, j = i & 63;
  int ax, fi;
  float d;
  if (j < 8) { ax = 0; fi = j; d = 16.f; }
  else if (j < 36) { ax = 1; fi = j - 8; d = 56.f; }
  else { ax = 2; fi = j - 36; d = 56.f; }
  const float freq = exp2f(-16.f * (float)fi / d);
  const float ang = (float)ids[s * 3 + ax] * freq;
  cosT[i] = cosf(ang);
  sinT[i] = sinf(ang);
}

__global__ __launch_bounds__(256) void adaln_kernel(const float* __restrict__ ain,
                                                    const float* __restrict__ W,
                                                    const float* __restrict__ b,
                                                    float* __restrict__ out) {
  __shared__ float a[256];
  const int t = threadIdx.x;
  a[t] = ain[t];
  __syncthreads();
  const int n = blockIdx.x * 256 + t;
  float acc = b[n];
  for (int k = 0; k < 256; ++k) acc = fmaf(a[k], W[(long long)k * 12288 + n], acc);
  const int chunk = n / 3072;
  out[n] = (chunk & 1) ? tanhf(acc) : (1.f + acc);
}

// xs = rmsnorm(x, w, 1e-6) * scale  -> bf16
__global__ __launch_bounds__(256) void rmsnorm_scale_k(const float* __restrict__ x,
                                                       const float* __restrict__ w,
                                                       const float* __restrict__ scale,
                                                       bf16* __restrict__ out) {
  __shared__ float red[4];
  const int t = threadIdx.x, lane = t & 63, wid = t >> 6;
  const long long base = (long long)blockIdx.x * 3072;
  float v[12];
  float ss = 0.f;
#pragma unroll
  for (int ch = 0; ch < 3; ++ch) {
    const float4 f = *(const float4*)&x[base + ch * 1024 + t * 4];
    v[ch * 4 + 0] = f.x; v[ch * 4 + 1] = f.y; v[ch * 4 + 2] = f.z; v[ch * 4 + 3] = f.w;
    ss += f.x * f.x + f.y * f.y + f.z * f.z + f.w * f.w;
  }
  ss = wsum(ss);
  if (!lane) red[wid] = ss;
  __syncthreads();
  const float r = rsqrtf((red[0] + red[1] + red[2] + red[3]) / 3072.f + 1e-6f);
#pragma unroll
  for (int ch = 0; ch < 3; ++ch) {
    const int col = ch * 1024 + t * 4;
    bf16x4 o;
#pragma unroll
    for (int j = 0; j < 4; ++j) o[j] = (bf16)(v[ch * 4 + j] * r * w[col + j] * scale[col + j]);
    *(bf16x4*)&out[base + col] = o;
  }
}

// per (s,h): combine 2 QKV split-K partials (stride 18874368 elements),
// rmsnorm(QK_EPS) over 128 + RoPE; writes combined q,k IN PLACE into the
// partial-0 buffer (row stride 9216, same as R16 layout).
__global__ __launch_bounds__(256) void qknorm_rope_k(bf16* __restrict__ qkvP,
                                                     const float* __restrict__ cosT,
                                                     const float* __restrict__ sinT,
                                                     const float* __restrict__ wq,
                                                     const float* __restrict__ wk) {
  const int t = threadIdx.x, lane = t & 63, wid = t >> 6;
  const int idx = blockIdx.x * 4 + wid;
  const int s = idx / 24, h = idx % 24;
  const int isK = blockIdx.y;
  bf16* base = qkvP + (long long)s * 9216 + isK * 3072 + h * 128;
  const bf16x2 p0 = *(const bf16x2*)(base + 2 * lane);
  const bf16x2 p1 = *(const bf16x2*)(base + 18874368LL + 2 * lane);
  float xr = (float)p0[0] + (float)p1[0];
  float xi = (float)p0[1] + (float)p1[1];
  const float ss = wsum(xr * xr + xi * xi);
  const float r = rsqrtf(ss / 128.f + 1e-5f);
  const float* w = isK ? wk : wq;
  const float2 wv = *(const float2*)&w[2 * lane];
  xr *= r * wv.x;
  xi *= r * wv.y;
  const float c = cosT[s * 64 + lane], sn = sinT[s * 64 + lane];
  bf16x2 o;
  o[0] = (bf16)(xr * c - xi * sn);
  o[1] = (bf16)(xr * sn + xi * c);
  *(bf16x2*)(base + 2 * lane) = o;
}

// vt[h][d][s] = sum of the 2 v partials qkvP[z][s][6144 + h*128 + d]
__global__ __launch_bounds__(256) void vtrans_k(const bf16* __restrict__ qkvP,
                                                bf16* __restrict__ vt) {
  __shared__ bf16 tile[64][72];
  const int t = threadIdx.x;
  const int s0 = blockIdx.x * 64, d0 = blockIdx.y * 64, h = blockIdx.z;
#pragma unroll
  for (int it = 0; it < 2; ++it) {
    const int idx = it * 256 + t;
    const int sl = idx >> 3, c8 = (idx & 7) << 3;
    const long long base = (long long)(s0 + sl) * 9216 + 6144 + h * 128 + d0 + c8;
    const bf16x8 v0 = *(const bf16x8*)&qkvP[base];
    const bf16x8 v1 = *(const bf16x8*)&qkvP[base + 18874368LL];
    bf16x8 v;
#pragma unroll
    for (int j = 0; j < 8; ++j) v[j] = (bf16)((float)v0[j] + (float)v1[j]);
    *(bf16x8*)&tile[sl][c8] = v;
  }
  __syncthreads();
#pragma unroll
  for (int it = 0; it < 2; ++it) {
    const int idx = it * 256 + t;
    const int dl = idx >> 3, s8 = (idx & 7) << 3;
    bf16x8 o;
#pragma unroll
    for (int j = 0; j < 8; ++j) o[j] = tile[s8 + j][dl];
    *(bf16x8*)&vt[(long long)h * 262144 + (long long)(d0 + dl) * 2048 + s0 + s8] = o;
  }
}

// x1 = x + gate*rmsnorm(p0+p1, n2w, 1e-6); xf = rmsnorm(x1, f1w, 1e-6)*smlp (bf16)
// p0/p1 are bf16 split-K partials.
__global__ __launch_bounds__(256) void resid1_k(
    const float* __restrict__ x, const bf16* __restrict__ p0, const bf16* __restrict__ p1,
    const float* __restrict__ n2w, const float* __restrict__ gate,
    const float* __restrict__ f1w, const float* __restrict__ smlp,
    float* __restrict__ x1, bf16* __restrict__ xf) {
  __shared__ float red[8];
  const int t = threadIdx.x, lane = t & 63, wid = t >> 6;
  const long long base = (long long)blockIdx.x * 3072;
  float av[12];
  float ss = 0.f;
#pragma unroll
  for (int ch = 0; ch < 3; ++ch) {
    const bf16x4 f0 = *(const bf16x4*)&p0[base + ch * 1024 + t * 4];
    const bf16x4 f1 = *(const bf16x4*)&p1[base + ch * 1024 + t * 4];
#pragma unroll
    for (int j = 0; j < 4; ++j) {
      const float a = (float)f0[j] + (float)f1[j];
      av[ch * 4 + j] = a;
      ss += a * a;
    }
  }
  ss = wsum(ss);
  if (!lane) red[wid] = ss;
  __syncthreads();
  const float r = rsqrtf((red[0] + red[1] + red[2] + red[3]) / 3072.f + 1e-6f);
  float xv[12];
  float ss2 = 0.f;
#pragma unroll
  for (int ch = 0; ch < 3; ++ch) {
    const int col = ch * 1024 + t * 4;
    const float4 f = *(const float4*)&x[base + col];
    float4 o;
    o.x = f.x + gate[col + 0] * (av[ch * 4 + 0] * r * n2w[col + 0]);
    o.y = f.y + gate[col + 1] * (av[ch * 4 + 1] * r * n2w[col + 1]);
    o.z = f.z + gate[col + 2] * (av[ch * 4 + 2] * r * n2w[col + 2]);
    o.w = f.w + gate[col + 3] * (av[ch * 4 + 3] * r * n2w[col + 3]);
    *(float4*)&x1[base + col] = o;
    xv[ch * 4 + 0] = o.x; xv[ch * 4 + 1] = o.y; xv[ch * 4 + 2] = o.z; xv[ch * 4 + 3] = o.w;
    ss2 += o.x * o.x + o.y * o.y + o.z * o.z + o.w * o.w;
  }
  ss2 = wsum(ss2);
  if (!lane) red[4 + wid] = ss2;
  __syncthreads();
  const float r2 = rsqrtf((red[4] + red[5] + red[6] + red[7]) / 3072.f + 1e-6f);
#pragma unroll
  for (int ch = 0; ch < 3; ++ch) {
    const int col = ch * 1024 + t * 4;
    bf16x4 o;
#pragma unroll
    for (int j = 0; j < 4; ++j)
      o[j] = (bf16)(xv[ch * 4 + j] * r2 * f1w[col + j] * smlp[col + j]);
    *(bf16x4*)&xf[base + col] = o;
  }
}

// out = x1 + gate*rmsnorm(f0+f1, nw, 1e-6)  (f32 output; f0/f1 bf16 partials)
__global__ __launch_bounds__(256) void resid2_k(const float* __restrict__ x1,
                                                const bf16* __restrict__ f0,
                                                const bf16* __restrict__ f1,
                                                const float* __restrict__ nw,
                                                const float* __restrict__ gate,
                                                float* __restrict__ out) {
  __shared__ float red[4];
  const int t = threadIdx.x, lane = t & 63, wid = t >> 6;
  const long long base = (long long)blockIdx.x * 3072;
  float fv[12];
  float ss = 0.f;
#pragma unroll
  for (int ch = 0; ch < 3; ++ch) {
    const bf16x4 a = *(const bf16x4*)&f0[base + ch * 1024 + t * 4];
    const bf16x4 b = *(const bf16x4*)&f1[base + ch * 1024 + t * 4];
#pragma unroll
    for (int j = 0; j < 4; ++j) {
      const float v = (float)a[j] + (float)b[j];
      fv[ch * 4 + j] = v;
      ss += v * v;
    }
  }
  ss = wsum(ss);
  if (!lane) red[wid] = ss;
  __syncthreads();
  const float r = rsqrtf((red[0] + red[1] + red[2] + red[3]) / 3072.f + 1e-6f);
#pragma unroll
  for (int ch = 0; ch < 3; ++ch) {
    const int col = ch * 1024 + t * 4;
    const float4 f = *(const float4*)&x1[base + col];
    float4 o;
    o.x = f.x + gate[col + 0] * (fv[ch * 4 + 0] * r * nw[col + 0]);
    o.y = f.y + gate[col + 1] * (fv[ch * 4 + 1] * r * nw[col + 1]);
    o.z = f.z + gate[col + 2] * (fv[ch * 4 + 2] * r * nw[col + 2]);
    o.w = f.w + gate[col + 3] * (fv[ch * 4 + 3] * r * nw[col + 3]);
    *(float4*)&out[base + col] = o;
  }
}

extern "C" void kernel_launch(void* const* d_in, const int* in_sizes, int n_in,
                              void* d_out, int out_size, void* d_ws, size_t ws_size,
                              hipStream_t stream) {
  const float* x    = (const float*)d_in[0];
  const float* ain  = (const float*)d_in[1];
  const int* ids    = (const int*)d_in[3];
  const float* n1w  = (const float*)d_in[4];
  const float* n2w  = (const float*)d_in[5];
  const float* fn1w = (const float*)d_in[6];
  const float* fn2w = (const float*)d_in[7];
  const float* nqw  = (const float*)d_in[8];
  const float* nkw  = (const float*)d_in[9];
  const float* wq   = (const float*)d_in[10];
  const float* wk   = (const float*)d_in[11];
  const float* wv   = (const float*)d_in[12];
  const float* wo   = (const float*)d_in[13];
  const float* w1   = (const float*)d_in[14];
  const float* w2   = (const float*)d_in[15];
  const float* w3   = (const float*)d_in[16];
  const float* adw  = (const float*)d_in[17];
  const float* adb  = (const float*)d_in[18];

  if (ws_size < 395362304ULL) return;

  char* ws = (char*)d_ws;
  bf16* wqkvT = (bf16*)(ws + 0LL);             // [9216][3072]
  bf16* woT   = (bf16*)(ws + 56623104LL);      // [3072][3072]
  bf16* w13T  = (bf16*)(ws + 75497472LL);      // [16384][3072] 16-granular interleave
  bf16* w2T   = (bf16*)(ws + 176160768LL);     // [3072][8192]
  float* cosT = (float*)(ws + 226492416LL);    // [2048][64]
  float* sinT = (float*)(ws + 227016704LL);
  float* adv  = (float*)(ws + 227540992LL);    // [4][3072]
  bf16* xs    = (bf16*)(ws + 227590144LL);     // [2048][3072], reused as xf
  char* big   = ws + 240173056LL;              // overlay region (155,189,248 B)
  // phase lifetimes (all disjoint per phase, stride/layout unchanged vs R17):
  //  QKV gemm -> qkvP[2]; qknorm combines q,k in place into qkvP[0];
  //  vtrans sums v partials -> vt; flash reads qkvP[0](q,k)+vt, writes Opb+mlp;
  //  fa_combine -> attn; Wo -> aoP (qkvP dead); resid1 -> x1,xs; FFN-up ->
  //  hbuf; FFN-down -> ffnP; resid2 -> out.
  float* x1   = (float*)(big);                 // 0 .. 25165824
  bf16* qkvP  = (bf16*)(big + 25165824LL);     // [2][2048][9216] .. 100663296
  bf16* vt    = (bf16*)(big + 100663296LL);    // [24][128][2048] .. 113246208
  bf16* attn  = (bf16*)(big + 113246208LL);    // [2048][3072]    .. 125829120
  bf16* Opb   = (bf16*)(big + 125829120LL);    // [2][2048][3072] .. 150994944
  float* mlp  = (float*)(big + 150994944LL);   // [2][49152][2]   .. 151781376
  bf16* aoP   = (bf16*)(big + 25165824LL);     // [2][2048][3072] (qkvP dead)
  bf16* hbuf  = (bf16*)(big + 50331648LL);     // [2048][8192] (aoP dead after resid1)
  bf16* ffnP  = (bf16*)(big + 83886080LL);     // [2][2048][3072] .. 109051904

  const dim3 b256(256);
  const dim3 b512(512);

  ropetab_k<<<dim3(512), b256, 0, stream>>>(ids, cosT, sinT);
  adaln_kernel<<<dim3(48), b256, 0, stream>>>(ain, adw, adb, adv);

  convAll<<<dim3(27648), b256, 0, stream>>>(wq, wk, wv, wo, w1, w3, w2, wqkvT, woT, w13T,
                                            w2T);

  rmsnorm_scale_k<<<dim3(2048), b256, 0, stream>>>(x, n1w, adv, xs);

  // QKV: split-K z=2 (proven in R17: 768 blocks = 3 exact rounds).  The
  // partial-sum is folded into the consumers below — no qkvsum pass.
  gemm192<1><<<dim3(8, 48, 2), b512, 0, stream>>>(xs, wqkvT, qkvP, 1536, 3072, 3072, 9216,
                                                  1536LL, 18874368LL);

  // combine partials + norm + rope in place (q,k); sum partials in vtrans (v)
  qknorm_rope_k<<<dim3(12288, 2), b256, 0, stream>>>(qkvP, cosT, sinT, nqw, nkw);
  vtrans_k<<<dim3(32, 2, 24), b256, 0, stream>>>(qkvP, vt);

  // flash attention (byte-identical kernel; reads qkvP[0] with stride 9216)
  flash_attn_k<<<dim3(16, 24, 2), b256, 0, stream>>>(qkvP, vt, Opb, mlp);
  fa_combine_k<<<dim3(12288), b256, 0, stream>>>(Opb, mlp, attn);

  // Wo: attn @ woT^T, split-K 2, bf16 partials (gemm192: grid 256 exact)
  gemm192<1><<<dim3(8, 16, 2), b512, 0, stream>>>(attn, woT, aoP, 1536, 3072, 3072, 3072,
                                                  1536LL, 6291456LL);
  resid1_k<<<dim3(2048), b256, 0, stream>>>(x, aoP, aoP + 6291456LL, n2w, adv + 3072, fn1w,
                                            adv + 6144, x1, xs);
  // FFN up + fused silu-mul (16-granular interleave): xf @ w13T^T -> hbuf bf16
  gemm256<2><<<dim3(8, 64, 1), b512, 0, stream>>>(xs, w13T, hbuf, 3072, 3072, 3072, 8192,
                                                  0LL, 0LL);
  // FFN down: h @ w2T^T, split-K 2, bf16 partials (gemm192: grid 256 exact)
  gemm192<1><<<dim3(8, 16, 2), b512, 0, stream>>>(hbuf, w2T, ffnP, 4096, 8192, 8192, 3072,
                                                  4096LL, 6291456LL);
  resid2_k<<<dim3(2048), b256, 0, stream>>>(x1, ffnP, ffnP + 6291456LL, fn2w, adv + 9216,
                                            (float*)d_out);
}

// Round 19
// 784.727 us; speedup vs baseline: 1.0272x; 1.0139x over previous
//
#include <hip/hip_runtime.h>

#define AS1 __attribute__((address_space(1)))
#define AS3 __attribute__((address_space(3)))

typedef __bf16 bf16;
using bf16x8 = __attribute__((ext_vector_type(8))) __bf16;
using bf16x4 = __attribute__((ext_vector_type(4))) __bf16;
using bf16x2 = __attribute__((ext_vector_type(2))) __bf16;
using f32x4  = __attribute__((ext_vector_type(4))) float;

// Problem constants: B=1, S=2048, D=3072, H=24, HD=128, FFN=8192

__device__ inline float wsum(float v) {
#pragma unroll
  for (int o = 32; o; o >>= 1) v += __shfl_xor(v, o, 64);
  return v;
}

// ---------------------------------------------------------------------------
// gemm256 — K-loop byte-identical to R11-R18 (single barrier/phase, vmcnt(6);
// do NOT refactor LDS decl or loop body — R8/R9 lesson).
// EPI: 0=f32, 1=bf16, 2=fused silu(w1)*w3 with 16-granular interleaved B.
// ---------------------------------------------------------------------------
template <int EPI>
__global__ __launch_bounds__(512, 1) void gemm256(
    const bf16* __restrict__ A, const bf16* __restrict__ Bt, void* __restrict__ Cv,
    int K, int lda, int ldb, int ldc, long long kOff, long long sC) {
  __shared__ bf16 lds[2][2][256 * 64];  // [buf][A/B][row*64+col]
  const int t = threadIdx.x;
  const int lane = t & 63, wid = t >> 6;
  const int wm = wid >> 2, wn = wid & 3;
  const int row16 = lane & 15, kg = lane >> 4;
  const int m0 = blockIdx.x * 256, n0 = blockIdx.y * 256;
  const int NT = K >> 6;
  const int sgran = (lane & 7) ^ (lane >> 3);  // pre-swizzled source granule
  A += (long long)blockIdx.z * kOff;
  Bt += (long long)blockIdx.z * kOff;

  auto stageA = [&](int buf, int r, int tk) {
    const int wrow = ((wid & 4) << 5) + (r << 5) + ((wid & 3) << 3);  // wave-uniform
    __builtin_amdgcn_global_load_lds(
        (const AS1 void*)(A + (long long)(m0 + wrow + (lane >> 3)) * lda + tk * 64 +
                          (sgran << 3)),
        (AS3 void*)&lds[buf][0][wrow * 64], 16, 0, 0);
  };
  auto stageB = [&](int buf, int r, int tk) {
    const int wrow = ((wid & 4) << 5) + (r << 5) + ((wid & 3) << 3);
    __builtin_amdgcn_global_load_lds(
        (const AS1 void*)(Bt + (long long)(n0 + wrow + (lane >> 3)) * ldb + tk * 64 +
                          (sgran << 3)),
        (AS3 void*)&lds[buf][1][wrow * 64], 16, 0, 0);
  };

  f32x4 acc[8][4];
#pragma unroll
  for (int i = 0; i < 8; ++i)
#pragma unroll
    for (int j = 0; j < 4; ++j) acc[i][j] = (f32x4){0.f, 0.f, 0.f, 0.f};

  // prologue: stage tile0 fully (8), tile1 rounds 0-2 (6)
#pragma unroll
  for (int r = 0; r < 4; ++r) { stageA(0, r, 0); stageB(0, r, 0); }
#pragma unroll
  for (int r = 0; r < 3; ++r) { stageA(1, r, 1); stageB(1, r, 1); }

  bf16x8 bfr[4][2], af[2][2];

  for (int kt = 0; kt < NT; ++kt) {
    const int cb = kt & 1, nb = cb ^ 1;
    if (kt + 1 < NT) asm volatile("s_waitcnt vmcnt(6)" ::: "memory");
    else             asm volatile("s_waitcnt vmcnt(0)" ::: "memory");
    __builtin_amdgcn_s_barrier();

    // ---- phase 0: stage(t+1) round 3; read all B frags + A quad 0
    if (kt + 1 < NT) { stageA(nb, 3, kt + 1); stageB(nb, 3, kt + 1); }
#pragma unroll
    for (int ni = 0; ni < 4; ++ni)
#pragma unroll
      for (int kk = 0; kk < 2; ++kk) {
        const int r = wn * 64 + ni * 16 + row16;
        bfr[ni][kk] = *(const bf16x8*)&lds[cb][1][r * 64 + (((kk * 4 + kg) ^ (r & 7)) << 3)];
      }
#pragma unroll
    for (int mi = 0; mi < 2; ++mi)
#pragma unroll
      for (int kk = 0; kk < 2; ++kk) {
        const int r = wm * 128 + mi * 16 + row16;
        af[mi][kk] = *(const bf16x8*)&lds[cb][0][r * 64 + (((kk * 4 + kg) ^ (r & 7)) << 3)];
      }
    asm volatile("s_waitcnt lgkmcnt(0)" ::: "memory");
    __builtin_amdgcn_s_setprio(1);
#pragma unroll
    for (int kk = 0; kk < 2; ++kk)
#pragma unroll
      for (int mi = 0; mi < 2; ++mi)
#pragma unroll
        for (int ni = 0; ni < 4; ++ni)
          acc[mi][ni] =
              __builtin_amdgcn_mfma_f32_16x16x32_bf16(af[mi][kk], bfr[ni][kk], acc[mi][ni], 0, 0, 0);
    __builtin_amdgcn_s_setprio(0);

    // ---- phases 1..3: stage(t+2) round q-1; read A quad q
#pragma unroll
    for (int q = 1; q < 4; ++q) {
      __builtin_amdgcn_s_barrier();
      if (kt + 2 < NT) { stageA(cb, q - 1, kt + 2); stageB(cb, q - 1, kt + 2); }
#pragma unroll
      for (int mi = 0; mi < 2; ++mi)
#pragma unroll
        for (int kk = 0; kk < 2; ++kk) {
          const int r = wm * 128 + q * 32 + mi * 16 + row16;
          af[mi][kk] = *(const bf16x8*)&lds[cb][0][r * 64 + (((kk * 4 + kg) ^ (r & 7)) << 3)];
        }
      asm volatile("s_waitcnt lgkmcnt(0)" ::: "memory");
      __builtin_amdgcn_s_setprio(1);
#pragma unroll
      for (int kk = 0; kk < 2; ++kk)
#pragma unroll
        for (int mi = 0; mi < 2; ++mi)
#pragma unroll
          for (int ni = 0; ni < 4; ++ni)
            acc[q * 2 + mi][ni] = __builtin_amdgcn_mfma_f32_16x16x32_bf16(
                af[mi][kk], bfr[ni][kk], acc[q * 2 + mi][ni], 0, 0, 0);
      __builtin_amdgcn_s_setprio(0);
    }
  }

  float* Cf = (float*)Cv;
  bf16* Cb = (bf16*)Cv;
  const long long cz = (long long)blockIdx.z * sC;
  if constexpr (EPI == 2) {
#pragma unroll
    for (int mf = 0; mf < 8; ++mf)
#pragma unroll
      for (int np = 0; np < 2; ++np)
#pragma unroll
        for (int rr = 0; rr < 4; ++rr) {
          const int row = m0 + wm * 128 + (mf >> 1) * 32 + (mf & 1) * 16 + kg * 4 + rr;
          const int col = (n0 >> 1) + wn * 32 + np * 16 + row16;
          const float a = acc[mf][np * 2][rr];
          const float b = acc[mf][np * 2 + 1][rr];
          const float sl = a / (1.f + __expf(-a));
          Cb[cz + (long long)row * ldc + col] = (bf16)(sl * b);
        }
  } else {
#pragma unroll
    for (int mf = 0; mf < 8; ++mf)
#pragma unroll
      for (int ni = 0; ni < 4; ++ni)
#pragma unroll
        for (int rr = 0; rr < 4; ++rr) {
          const int row = m0 + wm * 128 + (mf >> 1) * 32 + (mf & 1) * 16 + kg * 4 + rr;
          const int col = n0 + wn * 64 + ni * 16 + row16;
          const long long idx = cz + (long long)row * ldc + col;
          const float v = acc[mf][ni][rr];
          if constexpr (EPI == 0) Cf[idx] = v;
          else Cb[idx] = (bf16)v;
        }
  }
}

// ---------------------------------------------------------------------------
// gemm192 — UNTOUCHED (healthy since R10).  Two barriers per phase, vmcnt(6),
// single LDS array (A rows 0-255, B rows 256-447).  Split-K via blockIdx.z.
// EPI: 0=f32 store, 1=bf16 store.
// ---------------------------------------------------------------------------
template <int EPI>
__global__ __launch_bounds__(512, 1) void gemm192(
    const bf16* __restrict__ A, const bf16* __restrict__ Bt, void* __restrict__ Cv,
    int K, int lda, int ldb, int ldc, long long kOff, long long sC) {
  __shared__ bf16 lds[2][448 * 64];  // [buf][A(0-255)|B(256-447)][col]
  const int t = threadIdx.x;
  const int lane = t & 63, wid = t >> 6;
  const int wm = wid >> 2, wn = wid & 3;
  const int row16 = lane & 15, kg = lane >> 4;
  const int m0 = blockIdx.x * 256, n0 = blockIdx.y * 192;
  const int NT = K >> 6;
  const int sgran = (lane & 7) ^ (lane >> 3);
  A += (long long)blockIdx.z * kOff;
  Bt += (long long)blockIdx.z * kOff;

  auto stageA = [&](int buf, int r, int tk) {
    const int wrow = ((wid & 4) << 5) + (r << 5) + ((wid & 3) << 3);
    __builtin_amdgcn_global_load_lds(
        (const AS1 void*)(A + (long long)(m0 + wrow + (lane >> 3)) * lda + tk * 64 +
                          (sgran << 3)),
        (AS3 void*)&lds[buf][wrow * 64], 16, 0, 0);
  };
  auto stageB = [&](int buf, int r, int tk) {
    const int wrow = r * 64 + wid * 8;  // r in 0..2 covers 192 rows
    __builtin_amdgcn_global_load_lds(
        (const AS1 void*)(Bt + (long long)(n0 + wrow + (lane >> 3)) * ldb + tk * 64 +
                          (sgran << 3)),
        (AS3 void*)&lds[buf][(256 + wrow) * 64], 16, 0, 0);
  };

  f32x4 acc[8][3];
#pragma unroll
  for (int i = 0; i < 8; ++i)
#pragma unroll
    for (int j = 0; j < 3; ++j) acc[i][j] = (f32x4){0.f, 0.f, 0.f, 0.f};

  // prologue: tile0 fully (4A+3B), tile1 rounds 0-2 (3A+3B)
#pragma unroll
  for (int r = 0; r < 4; ++r) stageA(0, r, 0);
#pragma unroll
  for (int r = 0; r < 3; ++r) stageB(0, r, 0);
#pragma unroll
  for (int r = 0; r < 3; ++r) { stageA(1, r, 1); stageB(1, r, 1); }

  bf16x8 bfr[3][2], af[2][2];

  for (int kt = 0; kt < NT; ++kt) {
    const int cb = kt & 1, nb = cb ^ 1;
    if (kt + 1 < NT) asm volatile("s_waitcnt vmcnt(6)" ::: "memory");
    else             asm volatile("s_waitcnt vmcnt(0)" ::: "memory");
    __builtin_amdgcn_s_barrier();

    // ---- phase 0: stage(t+1) A round 3; read all B frags + A quad 0
    if (kt + 1 < NT) stageA(nb, 3, kt + 1);
#pragma unroll
    for (int ni = 0; ni < 3; ++ni)
#pragma unroll
      for (int kk = 0; kk < 2; ++kk) {
        const int r = wn * 48 + ni * 16 + row16;
        bfr[ni][kk] =
            *(const bf16x8*)&lds[cb][(256 + r) * 64 + (((kk * 4 + kg) ^ (r & 7)) << 3)];
      }
#pragma unroll
    for (int mi = 0; mi < 2; ++mi)
#pragma unroll
      for (int kk = 0; kk < 2; ++kk) {
        const int r = wm * 128 + mi * 16 + row16;
        af[mi][kk] = *(const bf16x8*)&lds[cb][r * 64 + (((kk * 4 + kg) ^ (r & 7)) << 3)];
      }
    __builtin_amdgcn_s_barrier();
    asm volatile("s_waitcnt lgkmcnt(0)" ::: "memory");
    __builtin_amdgcn_s_setprio(1);
#pragma unroll
    for (int kk = 0; kk < 2; ++kk)
#pragma unroll
      for (int mi = 0; mi < 2; ++mi)
#pragma unroll
        for (int ni = 0; ni < 3; ++ni)
          acc[mi][ni] =
              __builtin_amdgcn_mfma_f32_16x16x32_bf16(af[mi][kk], bfr[ni][kk], acc[mi][ni], 0, 0, 0);
    __builtin_amdgcn_s_setprio(0);

    // ---- phases 1..3: stage(t+2) round q-1 (A and B); read A quad q
#pragma unroll
    for (int q = 1; q < 4; ++q) {
      __builtin_amdgcn_s_barrier();
      if (kt + 2 < NT) { stageA(cb, q - 1, kt + 2); stageB(cb, q - 1, kt + 2); }
#pragma unroll
      for (int mi = 0; mi < 2; ++mi)
#pragma unroll
        for (int kk = 0; kk < 2; ++kk) {
          const int r = wm * 128 + q * 32 + mi * 16 + row16;
          af[mi][kk] = *(const bf16x8*)&lds[cb][r * 64 + (((kk * 4 + kg) ^ (r & 7)) << 3)];
        }
      __builtin_amdgcn_s_barrier();
      asm volatile("s_waitcnt lgkmcnt(0)" ::: "memory");
      __builtin_amdgcn_s_setprio(1);
#pragma unroll
      for (int kk = 0; kk < 2; ++kk)
#pragma unroll
        for (int mi = 0; mi < 2; ++mi)
#pragma unroll
          for (int ni = 0; ni < 3; ++ni)
            acc[q * 2 + mi][ni] = __builtin_amdgcn_mfma_f32_16x16x32_bf16(
                af[mi][kk], bfr[ni][kk], acc[q * 2 + mi][ni], 0, 0, 0);
      __builtin_amdgcn_s_setprio(0);
    }
  }

  float* Cf = (float*)Cv;
  bf16* Cb = (bf16*)Cv;
  const long long cz = (long long)blockIdx.z * sC;
#pragma unroll
  for (int mf = 0; mf < 8; ++mf)
#pragma unroll
    for (int ni = 0; ni < 3; ++ni)
#pragma unroll
      for (int rr = 0; rr < 4; ++rr) {
        const int row = m0 + wm * 128 + (mf >> 1) * 32 + (mf & 1) * 16 + kg * 4 + rr;
        const int col = n0 + wn * 48 + ni * 16 + row16;
        const long long idx = cz + (long long)row * ldc + col;
        const float v = acc[mf][ni][rr];
        if constexpr (EPI == 0) Cf[idx] = v;
        else Cb[idx] = (bf16)v;
      }
}

// ---------------------------------------------------------------------------
// Flash attention, KV-split.  Grid (16 q-tiles, 24 heads, 2 kv-splits).
// Writes unnormalized O (bf16) + per-row (m, l) f32.  Byte-identical to
// R16-R18 (reads qkv buffer with row stride 9216).
// ---------------------------------------------------------------------------
__global__ __launch_bounds__(256) void flash_attn_k(const bf16* __restrict__ qkv,
                                                    const bf16* __restrict__ vt,
                                                    bf16* __restrict__ Opb,
                                                    float* __restrict__ mlp) {
  __shared__ bf16 Ks[64 * 128];
  __shared__ bf16 Vs[128 * 64];
  __shared__ bf16 Ps[4 * 32 * 64];
  const int t = threadIdx.x, lane = t & 63, wid = t >> 6;
  const int row16 = lane & 15, kg = lane >> 4;
  const int q0 = blockIdx.x * 128;
  const int h = blockIdx.y;
  const int z = blockIdx.z;
  const bf16* Qp = qkv + h * 128;
  const bf16* Kp = qkv + 3072 + h * 128;
  const bf16* Vt = vt + (long long)h * 262144;
  const float iscale = 0.08838834764831845f;

  bf16x8 qf[2][4];
#pragma unroll
  for (int mi = 0; mi < 2; ++mi)
#pragma unroll
    for (int kc = 0; kc < 4; ++kc)
      qf[mi][kc] = *(const bf16x8*)&Qp[(long long)(q0 + wid * 32 + mi * 16 + row16) * 9216 +
                                       kc * 32 + kg * 8];
  bf16x8 ones;
#pragma unroll
  for (int j = 0; j < 8; ++j) ones[j] = (bf16)1.0f;

  f32x4 oacc[2][8];
#pragma unroll
  for (int mi = 0; mi < 2; ++mi)
#pragma unroll
    for (int nd = 0; nd < 8; ++nd) oacc[mi][nd] = (f32x4){0.f, 0.f, 0.f, 0.f};
  f32x4 lacc[2] = {(f32x4){0.f, 0.f, 0.f, 0.f}, (f32x4){0.f, 0.f, 0.f, 0.f}};
  float mst[2][4];
#pragma unroll
  for (int mi = 0; mi < 2; ++mi)
#pragma unroll
    for (int r = 0; r < 4; ++r) mst[mi][r] = -1e30f;

  bf16* Pw = &Ps[wid * 2048];
  const int kvbase = z << 10;

  for (int kv0 = kvbase; kv0 < kvbase + 1024; kv0 += 64) {
#pragma unroll
    for (int p = 0; p < 4; ++p) {
      const int gi = p * 256 + t;
      const int row = gi >> 4, g = gi & 15;
      __builtin_amdgcn_global_load_lds(
          (const AS1 void*)(Kp + (long long)(kv0 + row) * 9216 + ((g ^ (row & 7)) << 3)),
          (AS3 void*)&Ks[(p * 256 + wid * 64) * 8], 16, 0, 0);
    }
#pragma unroll
    for (int p = 0; p < 4; ++p) {
      const int gi = p * 256 + t;
      const int row = gi >> 3, g = gi & 7;
      __builtin_amdgcn_global_load_lds(
          (const AS1 void*)(Vt + (long long)row * 2048 + kv0 + ((g ^ (row & 7)) << 3)),
          (AS3 void*)&Vs[(p * 256 + wid * 64) * 8], 16, 0, 0);
    }
    __syncthreads();

    f32x4 sacc[2][4];
#pragma unroll
    for (int mi = 0; mi < 2; ++mi)
#pragma unroll
      for (int nf = 0; nf < 4; ++nf) sacc[mi][nf] = (f32x4){0.f, 0.f, 0.f, 0.f};
#pragma unroll
    for (int kc = 0; kc < 4; ++kc) {
      bf16x8 kf[4];
#pragma unroll
      for (int nf = 0; nf < 4; ++nf) {
        const int row = nf * 16 + row16;
        kf[nf] = *(const bf16x8*)&Ks[(row * 16 + ((kc * 4 + kg) ^ (row & 7))) * 8];
      }
#pragma unroll
      for (int mi = 0; mi < 2; ++mi)
#pragma unroll
        for (int nf = 0; nf < 4; ++nf)
          sacc[mi][nf] =
              __builtin_amdgcn_mfma_f32_16x16x32_bf16(qf[mi][kc], kf[nf], sacc[mi][nf], 0, 0, 0);
    }

    float fac[2][4];
#pragma unroll
    for (int mi = 0; mi < 2; ++mi)
#pragma unroll
      for (int r = 0; r < 4; ++r) {
        float rm = sacc[mi][0][r];
#pragma unroll
        for (int nf = 1; nf < 4; ++nf) rm = fmaxf(rm, sacc[mi][nf][r]);
        rm = fmaxf(rm, __shfl_xor(rm, 1, 64));
        rm = fmaxf(rm, __shfl_xor(rm, 2, 64));
        rm = fmaxf(rm, __shfl_xor(rm, 4, 64));
        rm = fmaxf(rm, __shfl_xor(rm, 8, 64));
        const float mnew = fmaxf(mst[mi][r], rm * iscale);
        fac[mi][r] = __expf(mst[mi][r] - mnew);
        mst[mi][r] = mnew;
#pragma unroll
        for (int nf = 0; nf < 4; ++nf)
          sacc[mi][nf][r] = __expf(sacc[mi][nf][r] * iscale - mnew);
      }
#pragma unroll
    for (int mi = 0; mi < 2; ++mi)
#pragma unroll
      for (int r = 0; r < 4; ++r) {
        lacc[mi][r] *= fac[mi][r];
#pragma unroll
        for (int nd = 0; nd < 8; ++nd) oacc[mi][nd][r] *= fac[mi][r];
      }

#pragma unroll
    for (int mi = 0; mi < 2; ++mi)
#pragma unroll
      for (int nf = 0; nf < 4; ++nf)
#pragma unroll
        for (int r = 0; r < 4; ++r) {
          const int row = mi * 16 + kg * 4 + r;
          const int col = nf * 16 + row16;
          Pw[(row * 8 + ((col >> 3) ^ (row & 7))) * 8 + (col & 7)] = (bf16)sacc[mi][nf][r];
        }

#pragma unroll
    for (int kvc = 0; kvc < 2; ++kvc) {
      bf16x8 pf[2], vf[8];
#pragma unroll
      for (int mi = 0; mi < 2; ++mi) {
        const int row = mi * 16 + row16;
        pf[mi] = *(const bf16x8*)&Pw[(row * 8 + ((kvc * 4 + kg) ^ (row & 7))) * 8];
      }
#pragma unroll
      for (int nd = 0; nd < 8; ++nd) {
        const int row = nd * 16 + row16;
        vf[nd] = *(const bf16x8*)&Vs[(row * 8 + ((kvc * 4 + kg) ^ (row & 7))) * 8];
      }
#pragma unroll
      for (int mi = 0; mi < 2; ++mi) {
        lacc[mi] = __builtin_amdgcn_mfma_f32_16x16x32_bf16(pf[mi], ones, lacc[mi], 0, 0, 0);
#pragma unroll
        for (int nd = 0; nd < 8; ++nd)
          oacc[mi][nd] =
              __builtin_amdgcn_mfma_f32_16x16x32_bf16(pf[mi], vf[nd], oacc[mi][nd], 0, 0, 0);
      }
    }
    __syncthreads();
  }

  // epilogue: store unnormalized O (bf16) and per-row (m, l)
  bf16* Oz = Opb + (long long)z * 6291456;
#pragma unroll
  for (int mi = 0; mi < 2; ++mi)
#pragma unroll
    for (int nd = 0; nd < 8; ++nd)
#pragma unroll
      for (int r = 0; r < 4; ++r) {
        const int row = q0 + wid * 32 + mi * 16 + kg * 4 + r;
        const int col = h * 128 + nd * 16 + row16;
        Oz[(long long)row * 3072 + col] = (bf16)oacc[mi][nd][r];
      }
  if (row16 == 0) {
#pragma unroll
    for (int mi = 0; mi < 2; ++mi)
#pragma unroll
      for (int r = 0; r < 4; ++r) {
        const int s = q0 + wid * 32 + mi * 16 + kg * 4 + r;
        const long long mi2 = ((long long)z * 49152 + s * 24 + h) * 2;
        mlp[mi2] = mst[mi][r];
        mlp[mi2 + 1] = lacc[mi][r];
      }
  }
}

// combine the 2 KV splits (vectorized: 16 lanes/pair, bf16x8 = 16B/lane):
// attn = (O0*a0 + O1*a1) / (l0*a0 + l1*a1).  Grid 3072 x 256 = 49152 pairs.
__global__ __launch_bounds__(256) void fa_combine_k(const bf16* __restrict__ Opb,
                                                    const float* __restrict__ mlp,
                                                    bf16* __restrict__ attn) {
  const int t = threadIdx.x;
  const int pair = blockIdx.x * 16 + (t >> 4);  // s*24 + h
  const int lane16 = t & 15;
  const int s = pair / 24, h = pair % 24;
  const float2 ml0 = *(const float2*)&mlp[(long long)pair * 2];
  const float2 ml1 = *(const float2*)&mlp[(49152LL + pair) * 2];
  const float m = fmaxf(ml0.x, ml1.x);
  const float a0 = __expf(ml0.x - m), a1 = __expf(ml1.x - m);
  const float inv = 1.f / (ml0.y * a0 + ml1.y * a1);
  const long long base = (long long)s * 3072 + h * 128 + lane16 * 8;
  const bf16x8 o0 = *(const bf16x8*)&Opb[base];
  const bf16x8 o1 = *(const bf16x8*)&Opb[6291456LL + base];
  bf16x8 o;
#pragma unroll
  for (int j = 0; j < 8; ++j)
    o[j] = (bf16)(((float)o0[j] * a0 + (float)o1[j] * a1) * inv);
  *(bf16x8*)&attn[base] = o;
}

// ---------------------------------------------------------------------------
// convAll: all 7 weight conversions (f32 [R][C] -> bf16 [C][R]) in one launch.
// interleave16: out row = c0*2 + ((cl>>4)<<5) + (cl&15) + roff (w1/w3
// 16-granular interleave for the fused FFN-up epilogue).
// ---------------------------------------------------------------------------
__device__ inline void convT_tile(const float* __restrict__ in, bf16* __restrict__ out,
                                  int R, int C, int bx, int by, int interleave16,
                                  int roff) {
  __shared__ float tile[64][65];
  const int t = threadIdx.x;
  const int r0 = by * 64, c0 = bx * 64;
#pragma unroll
  for (int it = 0; it < 4; ++it) {
    const int idx = it * 256 + t;
    const int rl = idx >> 4, c4 = (idx & 15) << 2;
    const float4 v = *(const float4*)&in[(long long)(r0 + rl) * C + c0 + c4];
    tile[rl][c4 + 0] = v.x;
    tile[rl][c4 + 1] = v.y;
    tile[rl][c4 + 2] = v.z;
    tile[rl][c4 + 3] = v.w;
  }
  __syncthreads();
#pragma unroll
  for (int it = 0; it < 4; ++it) {
    const int idx = it * 256 + t;
    const int cl = idx >> 4, r4 = (idx & 15) << 2;
    bf16x4 o;
    o[0] = (bf16)tile[r4 + 0][cl];
    o[1] = (bf16)tile[r4 + 1][cl];
    o[2] = (bf16)tile[r4 + 2][cl];
    o[3] = (bf16)tile[r4 + 3][cl];
    const long long orow = interleave16 ? (long long)(c0 * 2 + ((cl >> 4) << 5) +
                                                      (cl & 15) + roff)
                                        : (long long)(c0 + cl);
    *(bf16x4*)&out[orow * R + r0 + r4] = o;
  }
}

__global__ __launch_bounds__(256) void convAll(
    const float* __restrict__ wq, const float* __restrict__ wk,
    const float* __restrict__ wv, const float* __restrict__ wo,
    const float* __restrict__ w1, const float* __restrict__ w3,
    const float* __restrict__ w2, bf16* __restrict__ wqkvT, bf16* __restrict__ woT,
    bf16* __restrict__ w13T, bf16* __restrict__ w2T) {
  const int id = blockIdx.x;
  if (id < 9216) {
    const int m = id / 2304, l = id % 2304;
    const float* in = m == 0 ? wq : m == 1 ? wk : m == 2 ? wv : wo;
    bf16* out = m < 3 ? wqkvT + (long long)m * 9437184 : woT;
    convT_tile(in, out, 3072, 3072, l % 48, l / 48, 0, 0);
  } else if (id < 21504) {
    int l = id - 9216;
    const int m = l / 6144;
    l %= 6144;
    convT_tile(m ? w3 : w1, w13T, 3072, 8192, l % 128, l / 128, 1, m * 16);
  } else {
    const int l = id - 21504;
    convT_tile(w2, w2T, 8192, 3072, l % 48, l / 48, 0, 0);
  }
}

// cos/sin tables: [S][64]
__global__ __launch_bounds__(256) void ropetab_k(const int* __restrict__ ids,
                                                 float* __restrict__ cosT,
                                                 float* __restrict__ sinT) {
  const int i = blockIdx.x * 256 + threadIdx.x;
  const int s = i >> 6, j = i & 63;
  int ax, fi;
  float d;
  if (j < 8) { ax = 0; fi = j; d = 16.f; }
  else if (j < 36) { ax = 1; fi = j - 8; d = 56.f; }
  else { ax = 2; fi = j - 36; d = 56.f; }
  const float freq = exp2f(-16.f * (float)fi / d);
  const float ang = (float)ids[s * 3 + ax] * freq;
  cosT[i] = cosf(ang);
  sinT[i] = sinf(ang);
}

__global__ __launch_bounds__(256) void adaln_kernel(const float* __restrict__ ain,
                                                    const float* __restrict__ W,
                                                    const float* __restrict__ b,
                                                    float* __restrict__ out) {
  __shared__ float a[256];
  const int t = threadIdx.x;
  a[t] = ain[t];
  __syncthreads();
  const int n = blockIdx.x * 256 + t;
  float acc = b[n];
  for (int k = 0; k < 256; ++k) acc = fmaf(a[k], W[(long long)k * 12288 + n], acc);
  const int chunk = n / 3072;
  out[n] = (chunk & 1) ? tanhf(acc) : (1.f + acc);
}

// xs = rmsnorm(x, w, 1e-6) * scale  -> bf16
__global__ __launch_bounds__(256) void rmsnorm_scale_k(const float* __restrict__ x,
                                                       const float* __restrict__ w,
                                                       const float* __restrict__ scale,
                                                       bf16* __restrict__ out) {
  __shared__ float red[4];
  const int t = threadIdx.x, lane = t & 63, wid = t >> 6;
  const long long base = (long long)blockIdx.x * 3072;
  float v[12];
  float ss = 0.f;
#pragma unroll
  for (int ch = 0; ch < 3; ++ch) {
    const float4 f = *(const float4*)&x[base + ch * 1024 + t * 4];
    v[ch * 4 + 0] = f.x; v[ch * 4 + 1] = f.y; v[ch * 4 + 2] = f.z; v[ch * 4 + 3] = f.w;
    ss += f.x * f.x + f.y * f.y + f.z * f.z + f.w * f.w;
  }
  ss = wsum(ss);
  if (!lane) red[wid] = ss;
  __syncthreads();
  const float r = rsqrtf((red[0] + red[1] + red[2] + red[3]) / 3072.f + 1e-6f);
#pragma unroll
  for (int ch = 0; ch < 3; ++ch) {
    const int col = ch * 1024 + t * 4;
    bf16x4 o;
#pragma unroll
    for (int j = 0; j < 4; ++j) o[j] = (bf16)(v[ch * 4 + j] * r * w[col + j] * scale[col + j]);
    *(bf16x4*)&out[base + col] = o;
  }
}

// per (s,h): combine 2 QKV split-K partials, rmsnorm(QK_EPS) over 128 + RoPE,
// in place into partial-0.  Vectorized: 16 lanes/row, bf16x8 (16B) loads,
// float4 weight/cos/sin loads, 16-lane shfl reduce.  Grid (3072, 2) x 256.
__global__ __launch_bounds__(256) void qknorm_rope_k(bf16* __restrict__ qkvP,
                                                     const float* __restrict__ cosT,
                                                     const float* __restrict__ sinT,
                                                     const float* __restrict__ wq,
                                                     const float* __restrict__ wk) {
  const int t = threadIdx.x;
  const int idx = blockIdx.x * 16 + (t >> 4);  // s*24 + h
  const int lane16 = t & 15;
  const int s = idx / 24, h = idx % 24;
  const int isK = blockIdx.y;
  bf16* base = qkvP + (long long)s * 9216 + isK * 3072 + h * 128 + lane16 * 8;
  const bf16x8 p0 = *(const bf16x8*)base;
  const bf16x8 p1 = *(const bf16x8*)(base + 18874368LL);
  float xv[8];
  float ss = 0.f;
#pragma unroll
  for (int j = 0; j < 8; ++j) {
    xv[j] = (float)p0[j] + (float)p1[j];
    ss += xv[j] * xv[j];
  }
  ss += __shfl_xor(ss, 1, 64);
  ss += __shfl_xor(ss, 2, 64);
  ss += __shfl_xor(ss, 4, 64);
  ss += __shfl_xor(ss, 8, 64);
  const float r = rsqrtf(ss / 128.f + 1e-5f);
  const float* w = isK ? wk : wq;
  const float4 w0 = *(const float4*)&w[lane16 * 8];
  const float4 w1 = *(const float4*)&w[lane16 * 8 + 4];
  const float wa[8] = {w0.x, w0.y, w0.z, w0.w, w1.x, w1.y, w1.z, w1.w};
  const float4 cs = *(const float4*)&cosT[s * 64 + lane16 * 4];
  const float4 sn = *(const float4*)&sinT[s * 64 + lane16 * 4];
  const float cc[4] = {cs.x, cs.y, cs.z, cs.w};
  const float sv[4] = {sn.x, sn.y, sn.z, sn.w};
  bf16x8 o;
#pragma unroll
  for (int p = 0; p < 4; ++p) {
    const float xr = xv[2 * p] * r * wa[2 * p];
    const float xi = xv[2 * p + 1] * r * wa[2 * p + 1];
    o[2 * p]     = (bf16)(xr * cc[p] - xi * sv[p]);
    o[2 * p + 1] = (bf16)(xr * sv[p] + xi * cc[p]);
  }
  *(bf16x8*)base = o;
}

// vt[h][d][s] = sum of the 2 v partials qkvP[z][s][6144 + h*128 + d]
__global__ __launch_bounds__(256) void vtrans_k(const bf16* __restrict__ qkvP,
                                                bf16* __restrict__ vt) {
  __shared__ bf16 tile[64][72];
  const int t = threadIdx.x;
  const int s0 = blockIdx.x * 64, d0 = blockIdx.y * 64, h = blockIdx.z;
#pragma unroll
  for (int it = 0; it < 2; ++it) {
    const int idx = it * 256 + t;
    const int sl = idx >> 3, c8 = (idx & 7) << 3;
    const long long base = (long long)(s0 + sl) * 9216 + 6144 + h * 128 + d0 + c8;
    const bf16x8 v0 = *(const bf16x8*)&qkvP[base];
    const bf16x8 v1 = *(const bf16x8*)&qkvP[base + 18874368LL];
    bf16x8 v;
#pragma unroll
    for (int j = 0; j < 8; ++j) v[j] = (bf16)((float)v0[j] + (float)v1[j]);
    *(bf16x8*)&tile[sl][c8] = v;
  }
  __syncthreads();
#pragma unroll
  for (int it = 0; it < 2; ++it) {
    const int idx = it * 256 + t;
    const int dl = idx >> 3, s8 = (idx & 7) << 3;
    bf16x8 o;
#pragma unroll
    for (int j = 0; j < 8; ++j) o[j] = tile[s8 + j][dl];
    *(bf16x8*)&vt[(long long)h * 262144 + (long long)(d0 + dl) * 2048 + s0 + s8] = o;
  }
}

// x1 = x + gate*rmsnorm(p0+p1, n2w, 1e-6); xf = rmsnorm(x1, f1w, 1e-6)*smlp (bf16)
// p0/p1 are bf16 split-K partials.
__global__ __launch_bounds__(256) void resid1_k(
    const float* __restrict__ x, const bf16* __restrict__ p0, const bf16* __restrict__ p1,
    const float* __restrict__ n2w, const float* __restrict__ gate,
    const float* __restrict__ f1w, const float* __restrict__ smlp,
    float* __restrict__ x1, bf16* __restrict__ xf) {
  __shared__ float red[8];
  const int t = threadIdx.x, lane = t & 63, wid = t >> 6;
  const long long base = (long long)blockIdx.x * 3072;
  float av[12];
  float ss = 0.f;
#pragma unroll
  for (int ch = 0; ch < 3; ++ch) {
    const bf16x4 f0 = *(const bf16x4*)&p0[base + ch * 1024 + t * 4];
    const bf16x4 f1 = *(const bf16x4*)&p1[base + ch * 1024 + t * 4];
#pragma unroll
    for (int j = 0; j < 4; ++j) {
      const float a = (float)f0[j] + (float)f1[j];
      av[ch * 4 + j] = a;
      ss += a * a;
    }
  }
  ss = wsum(ss);
  if (!lane) red[wid] = ss;
  __syncthreads();
  const float r = rsqrtf((red[0] + red[1] + red[2] + red[3]) / 3072.f + 1e-6f);
  float xv[12];
  float ss2 = 0.f;
#pragma unroll
  for (int ch = 0; ch < 3; ++ch) {
    const int col = ch * 1024 + t * 4;
    const float4 f = *(const float4*)&x[base + col];
    float4 o;
    o.x = f.x + gate[col + 0] * (av[ch * 4 + 0] * r * n2w[col + 0]);
    o.y = f.y + gate[col + 1] * (av[ch * 4 + 1] * r * n2w[col + 1]);
    o.z = f.z + gate[col + 2] * (av[ch * 4 + 2] * r * n2w[col + 2]);
    o.w = f.w + gate[col + 3] * (av[ch * 4 + 3] * r * n2w[col + 3]);
    *(float4*)&x1[base + col] = o;
    xv[ch * 4 + 0] = o.x; xv[ch * 4 + 1] = o.y; xv[ch * 4 + 2] = o.z; xv[ch * 4 + 3] = o.w;
    ss2 += o.x * o.x + o.y * o.y + o.z * o.z + o.w * o.w;
  }
  ss2 = wsum(ss2);
  if (!lane) red[4 + wid] = ss2;
  __syncthreads();
  const float r2 = rsqrtf((red[4] + red[5] + red[6] + red[7]) / 3072.f + 1e-6f);
#pragma unroll
  for (int ch = 0; ch < 3; ++ch) {
    const int col = ch * 1024 + t * 4;
    bf16x4 o;
#pragma unroll
    for (int j = 0; j < 4; ++j)
      o[j] = (bf16)(xv[ch * 4 + j] * r2 * f1w[col + j] * smlp[col + j]);
    *(bf16x4*)&xf[base + col] = o;
  }
}

// out = x1 + gate*rmsnorm(f0+f1, nw, 1e-6)  (f32 output; f0/f1 bf16 partials)
__global__ __launch_bounds__(256) void resid2_k(const float* __restrict__ x1,
                                                const bf16* __restrict__ f0,
                                                const bf16* __restrict__ f1,
                                                const float* __restrict__ nw,
                                                const float* __restrict__ gate,
                                                float* __restrict__ out) {
  __shared__ float red[4];
  const int t = threadIdx.x, lane = t & 63, wid = t >> 6;
  const long long base = (long long)blockIdx.x * 3072;
  float fv[12];
  float ss = 0.f;
#pragma unroll
  for (int ch = 0; ch < 3; ++ch) {
    const bf16x4 a = *(const bf16x4*)&f0[base + ch * 1024 + t * 4];
    const bf16x4 b = *(const bf16x4*)&f1[base + ch * 1024 + t * 4];
#pragma unroll
    for (int j = 0; j < 4; ++j) {
      const float v = (float)a[j] + (float)b[j];
      fv[ch * 4 + j] = v;
      ss += v * v;
    }
  }
  ss = wsum(ss);
  if (!lane) red[wid] = ss;
  __syncthreads();
  const float r = rsqrtf((red[0] + red[1] + red[2] + red[3]) / 3072.f + 1e-6f);
#pragma unroll
  for (int ch = 0; ch < 3; ++ch) {
    const int col = ch * 1024 + t * 4;
    const float4 f = *(const float4*)&x1[base + col];
    float4 o;
    o.x = f.x + gate[col + 0] * (fv[ch * 4 + 0] * r * nw[col + 0]);
    o.y = f.y + gate[col + 1] * (fv[ch * 4 + 1] * r * nw[col + 1]);
    o.z = f.z + gate[col + 2] * (fv[ch * 4 + 2] * r * nw[col + 2]);
    o.w = f.w + gate[col + 3] * (fv[ch * 4 + 3] * r * nw[col + 3]);
    *(float4*)&out[base + col] = o;
  }
}

extern "C" void kernel_launch(void* const* d_in, const int* in_sizes, int n_in,
                              void* d_out, int out_size, void* d_ws, size_t ws_size,
                              hipStream_t stream) {
  const float* x    = (const float*)d_in[0];
  const float* ain  = (const float*)d_in[1];
  const int* ids    = (const int*)d_in[3];
  const float* n1w  = (const float*)d_in[4];
  const float* n2w  = (const float*)d_in[5];
  const float* fn1w = (const float*)d_in[6];
  const float* fn2w = (const float*)d_in[7];
  const float* nqw  = (const float*)d_in[8];
  const float* nkw  = (const float*)d_in[9];
  const float* wq   = (const float*)d_in[10];
  const float* wk   = (const float*)d_in[11];
  const float* wv   = (const float*)d_in[12];
  const float* wo   = (const float*)d_in[13];
  const float* w1   = (const float*)d_in[14];
  const float* w2   = (const float*)d_in[15];
  const float* w3   = (const float*)d_in[16];
  const float* adw  = (const float*)d_in[17];
  const float* adb  = (const float*)d_in[18];

  if (ws_size < 395362304ULL) return;

  char* ws = (char*)d_ws;
  bf16* wqkvT = (bf16*)(ws + 0LL);             // [9216][3072]
  bf16* woT   = (bf16*)(ws + 56623104LL);      // [3072][3072]
  bf16* w13T  = (bf16*)(ws + 75497472LL);      // [16384][3072] 16-granular interleave
  bf16* w2T   = (bf16*)(ws + 176160768LL);     // [3072][8192]
  float* cosT = (float*)(ws + 226492416LL);    // [2048][64]
  float* sinT = (float*)(ws + 227016704LL);
  float* adv  = (float*)(ws + 227540992LL);    // [4][3072]
  bf16* xs    = (bf16*)(ws + 227590144LL);     // [2048][3072], reused as xf
  char* big   = ws + 240173056LL;              // overlay region (155,189,248 B)
  float* x1   = (float*)(big);                 // 0 .. 25165824
  bf16* qkvP  = (bf16*)(big + 25165824LL);     // [2][2048][9216] .. 100663296
  bf16* vt    = (bf16*)(big + 100663296LL);    // [24][128][2048] .. 113246208
  bf16* attn  = (bf16*)(big + 113246208LL);    // [2048][3072]    .. 125829120
  bf16* Opb   = (bf16*)(big + 125829120LL);    // [2][2048][3072] .. 150994944
  float* mlp  = (float*)(big + 150994944LL);   // [2][49152][2]   .. 151781376
  bf16* aoP   = (bf16*)(big + 25165824LL);     // [2][2048][3072] (qkvP dead)
  bf16* hbuf  = (bf16*)(big + 50331648LL);     // [2048][8192] (aoP dead after resid1)
  bf16* ffnP  = (bf16*)(big + 83886080LL);     // [2][2048][3072] .. 109051904

  const dim3 b256(256);
  const dim3 b512(512);

  ropetab_k<<<dim3(512), b256, 0, stream>>>(ids, cosT, sinT);
  adaln_kernel<<<dim3(48), b256, 0, stream>>>(ain, adw, adb, adv);

  convAll<<<dim3(27648), b256, 0, stream>>>(wq, wk, wv, wo, w1, w3, w2, wqkvT, woT, w13T,
                                            w2T);

  rmsnorm_scale_k<<<dim3(2048), b256, 0, stream>>>(x, n1w, adv, xs);

  // QKV: split-K z=2 (768 blocks = 3 exact rounds); partial-sum folded into
  // the consumers below.
  gemm192<1><<<dim3(8, 48, 2), b512, 0, stream>>>(xs, wqkvT, qkvP, 1536, 3072, 3072, 9216,
                                                  1536LL, 18874368LL);

  // combine partials + norm + rope in place (q,k); sum partials in vtrans (v)
  qknorm_rope_k<<<dim3(3072, 2), b256, 0, stream>>>(qkvP, cosT, sinT, nqw, nkw);
  vtrans_k<<<dim3(32, 2, 24), b256, 0, stream>>>(qkvP, vt);

  // flash attention (reads qkvP[0] with stride 9216) + vectorized combine
  flash_attn_k<<<dim3(16, 24, 2), b256, 0, stream>>>(qkvP, vt, Opb, mlp);
  fa_combine_k<<<dim3(3072), b256, 0, stream>>>(Opb, mlp, attn);

  // Wo: attn @ woT^T, split-K 2, bf16 partials (gemm192: grid 256 exact)
  gemm192<1><<<dim3(8, 16, 2), b512, 0, stream>>>(attn, woT, aoP, 1536, 3072, 3072, 3072,
                                                  1536LL, 6291456LL);
  resid1_k<<<dim3(2048), b256, 0, stream>>>(x, aoP, aoP + 6291456LL, n2w, adv + 3072, fn1w,
                                            adv + 6144, x1, xs);
  // FFN up + fused silu-mul (16-granular interleave): xf @ w13T^T -> hbuf bf16
  gemm256<2><<<dim3(8, 64, 1), b512, 0, stream>>>(xs, w13T, hbuf, 3072, 3072, 3072, 8192,
                                                  0LL, 0LL);
  // FFN down: h @ w2T^T, split-K 2, bf16 partials (gemm192: grid 256 exact)
  gemm192<1><<<dim3(8, 16, 2), b512, 0, stream>>>(hbuf, w2T, ffnP, 4096, 8192, 8192, 3072,
                                                  4096LL, 6291456LL);
  resid2_k<<<dim3(2048), b256, 0, stream>>>(x1, ffnP, ffnP + 6291456LL, fn2w, adv + 9216,
                                            (float*)d_out);
}

// Round 20
// 777.408 us; speedup vs baseline: 1.0368x; 1.0094x over previous
//
#include <hip/hip_runtime.h>

#define AS1 __attribute__((address_space(1)))
#define AS3 __attribute__((address_space(3)))

typedef __bf16 bf16;
using bf16x8 = __attribute__((ext_vector_type(8))) __bf16;
using bf16x4 = __attribute__((ext_vector_type(4))) __bf16;
using bf16x2 = __attribute__((ext_vector_type(2))) __bf16;
using f32x4  = __attribute__((ext_vector_type(4))) float;

// Problem constants: B=1, S=2048, D=3072, H=24, HD=128, FFN=8192

__device__ inline float wsum(float v) {
#pragma unroll
  for (int o = 32; o; o >>= 1) v += __shfl_xor(v, o, 64);
  return v;
}

// ---------------------------------------------------------------------------
// gemm256 — K-loop byte-identical to R11-R19 (single barrier/phase, vmcnt(6);
// do NOT refactor LDS decl or loop body — R8/R9 lesson).
// EPI: 0=f32, 1=bf16, 2=fused silu(w1)*w3 with 16-granular interleaved B.
// ---------------------------------------------------------------------------
template <int EPI>
__global__ __launch_bounds__(512, 1) void gemm256(
    const bf16* __restrict__ A, const bf16* __restrict__ Bt, void* __restrict__ Cv,
    int K, int lda, int ldb, int ldc, long long kOff, long long sC) {
  __shared__ bf16 lds[2][2][256 * 64];  // [buf][A/B][row*64+col]
  const int t = threadIdx.x;
  const int lane = t & 63, wid = t >> 6;
  const int wm = wid >> 2, wn = wid & 3;
  const int row16 = lane & 15, kg = lane >> 4;
  const int m0 = blockIdx.x * 256, n0 = blockIdx.y * 256;
  const int NT = K >> 6;
  const int sgran = (lane & 7) ^ (lane >> 3);  // pre-swizzled source granule
  A += (long long)blockIdx.z * kOff;
  Bt += (long long)blockIdx.z * kOff;

  auto stageA = [&](int buf, int r, int tk) {
    const int wrow = ((wid & 4) << 5) + (r << 5) + ((wid & 3) << 3);  // wave-uniform
    __builtin_amdgcn_global_load_lds(
        (const AS1 void*)(A + (long long)(m0 + wrow + (lane >> 3)) * lda + tk * 64 +
                          (sgran << 3)),
        (AS3 void*)&lds[buf][0][wrow * 64], 16, 0, 0);
  };
  auto stageB = [&](int buf, int r, int tk) {
    const int wrow = ((wid & 4) << 5) + (r << 5) + ((wid & 3) << 3);
    __builtin_amdgcn_global_load_lds(
        (const AS1 void*)(Bt + (long long)(n0 + wrow + (lane >> 3)) * ldb + tk * 64 +
                          (sgran << 3)),
        (AS3 void*)&lds[buf][1][wrow * 64], 16, 0, 0);
  };

  f32x4 acc[8][4];
#pragma unroll
  for (int i = 0; i < 8; ++i)
#pragma unroll
    for (int j = 0; j < 4; ++j) acc[i][j] = (f32x4){0.f, 0.f, 0.f, 0.f};

  // prologue: stage tile0 fully (8), tile1 rounds 0-2 (6)
#pragma unroll
  for (int r = 0; r < 4; ++r) { stageA(0, r, 0); stageB(0, r, 0); }
#pragma unroll
  for (int r = 0; r < 3; ++r) { stageA(1, r, 1); stageB(1, r, 1); }

  bf16x8 bfr[4][2], af[2][2];

  for (int kt = 0; kt < NT; ++kt) {
    const int cb = kt & 1, nb = cb ^ 1;
    if (kt + 1 < NT) asm volatile("s_waitcnt vmcnt(6)" ::: "memory");
    else             asm volatile("s_waitcnt vmcnt(0)" ::: "memory");
    __builtin_amdgcn_s_barrier();

    // ---- phase 0: stage(t+1) round 3; read all B frags + A quad 0
    if (kt + 1 < NT) { stageA(nb, 3, kt + 1); stageB(nb, 3, kt + 1); }
#pragma unroll
    for (int ni = 0; ni < 4; ++ni)
#pragma unroll
      for (int kk = 0; kk < 2; ++kk) {
        const int r = wn * 64 + ni * 16 + row16;
        bfr[ni][kk] = *(const bf16x8*)&lds[cb][1][r * 64 + (((kk * 4 + kg) ^ (r & 7)) << 3)];
      }
#pragma unroll
    for (int mi = 0; mi < 2; ++mi)
#pragma unroll
      for (int kk = 0; kk < 2; ++kk) {
        const int r = wm * 128 + mi * 16 + row16;
        af[mi][kk] = *(const bf16x8*)&lds[cb][0][r * 64 + (((kk * 4 + kg) ^ (r & 7)) << 3)];
      }
    asm volatile("s_waitcnt lgkmcnt(0)" ::: "memory");
    __builtin_amdgcn_s_setprio(1);
#pragma unroll
    for (int kk = 0; kk < 2; ++kk)
#pragma unroll
      for (int mi = 0; mi < 2; ++mi)
#pragma unroll
        for (int ni = 0; ni < 4; ++ni)
          acc[mi][ni] =
              __builtin_amdgcn_mfma_f32_16x16x32_bf16(af[mi][kk], bfr[ni][kk], acc[mi][ni], 0, 0, 0);
    __builtin_amdgcn_s_setprio(0);

    // ---- phases 1..3: stage(t+2) round q-1; read A quad q
#pragma unroll
    for (int q = 1; q < 4; ++q) {
      __builtin_amdgcn_s_barrier();
      if (kt + 2 < NT) { stageA(cb, q - 1, kt + 2); stageB(cb, q - 1, kt + 2); }
#pragma unroll
      for (int mi = 0; mi < 2; ++mi)
#pragma unroll
        for (int kk = 0; kk < 2; ++kk) {
          const int r = wm * 128 + q * 32 + mi * 16 + row16;
          af[mi][kk] = *(const bf16x8*)&lds[cb][0][r * 64 + (((kk * 4 + kg) ^ (r & 7)) << 3)];
        }
      asm volatile("s_waitcnt lgkmcnt(0)" ::: "memory");
      __builtin_amdgcn_s_setprio(1);
#pragma unroll
      for (int kk = 0; kk < 2; ++kk)
#pragma unroll
        for (int mi = 0; mi < 2; ++mi)
#pragma unroll
          for (int ni = 0; ni < 4; ++ni)
            acc[q * 2 + mi][ni] = __builtin_amdgcn_mfma_f32_16x16x32_bf16(
                af[mi][kk], bfr[ni][kk], acc[q * 2 + mi][ni], 0, 0, 0);
      __builtin_amdgcn_s_setprio(0);
    }
  }

  float* Cf = (float*)Cv;
  bf16* Cb = (bf16*)Cv;
  const long long cz = (long long)blockIdx.z * sC;
  if constexpr (EPI == 2) {
#pragma unroll
    for (int mf = 0; mf < 8; ++mf)
#pragma unroll
      for (int np = 0; np < 2; ++np)
#pragma unroll
        for (int rr = 0; rr < 4; ++rr) {
          const int row = m0 + wm * 128 + (mf >> 1) * 32 + (mf & 1) * 16 + kg * 4 + rr;
          const int col = (n0 >> 1) + wn * 32 + np * 16 + row16;
          const float a = acc[mf][np * 2][rr];
          const float b = acc[mf][np * 2 + 1][rr];
          const float sl = a / (1.f + __expf(-a));
          Cb[cz + (long long)row * ldc + col] = (bf16)(sl * b);
        }
  } else {
#pragma unroll
    for (int mf = 0; mf < 8; ++mf)
#pragma unroll
      for (int ni = 0; ni < 4; ++ni)
#pragma unroll
        for (int rr = 0; rr < 4; ++rr) {
          const int row = m0 + wm * 128 + (mf >> 1) * 32 + (mf & 1) * 16 + kg * 4 + rr;
          const int col = n0 + wn * 64 + ni * 16 + row16;
          const long long idx = cz + (long long)row * ldc + col;
          const float v = acc[mf][ni][rr];
          if constexpr (EPI == 0) Cf[idx] = v;
          else Cb[idx] = (bf16)v;
        }
  }
}

// ---------------------------------------------------------------------------
// gemm192 — R19 kernel with the R11-validated edit: mid-phase s_barrier
// removed (phase 0 and q-loop).  Race-free: each wave's lgkmcnt(0) precedes
// its next barrier, so phase-q reads drain before phase-q+1 stages overwrite
// those rows.  Everything else untouched (single LDS array, vmcnt(6),
// split-K via blockIdx.z).  EPI: 0=f32 store, 1=bf16 store.
// ---------------------------------------------------------------------------
template <int EPI>
__global__ __launch_bounds__(512, 1) void gemm192(
    const bf16* __restrict__ A, const bf16* __restrict__ Bt, void* __restrict__ Cv,
    int K, int lda, int ldb, int ldc, long long kOff, long long sC) {
  __shared__ bf16 lds[2][448 * 64];  // [buf][A(0-255)|B(256-447)][col]
  const int t = threadIdx.x;
  const int lane = t & 63, wid = t >> 6;
  const int wm = wid >> 2, wn = wid & 3;
  const int row16 = lane & 15, kg = lane >> 4;
  const int m0 = blockIdx.x * 256, n0 = blockIdx.y * 192;
  const int NT = K >> 6;
  const int sgran = (lane & 7) ^ (lane >> 3);
  A += (long long)blockIdx.z * kOff;
  Bt += (long long)blockIdx.z * kOff;

  auto stageA = [&](int buf, int r, int tk) {
    const int wrow = ((wid & 4) << 5) + (r << 5) + ((wid & 3) << 3);
    __builtin_amdgcn_global_load_lds(
        (const AS1 void*)(A + (long long)(m0 + wrow + (lane >> 3)) * lda + tk * 64 +
                          (sgran << 3)),
        (AS3 void*)&lds[buf][wrow * 64], 16, 0, 0);
  };
  auto stageB = [&](int buf, int r, int tk) {
    const int wrow = r * 64 + wid * 8;  // r in 0..2 covers 192 rows
    __builtin_amdgcn_global_load_lds(
        (const AS1 void*)(Bt + (long long)(n0 + wrow + (lane >> 3)) * ldb + tk * 64 +
                          (sgran << 3)),
        (AS3 void*)&lds[buf][(256 + wrow) * 64], 16, 0, 0);
  };

  f32x4 acc[8][3];
#pragma unroll
  for (int i = 0; i < 8; ++i)
#pragma unroll
    for (int j = 0; j < 3; ++j) acc[i][j] = (f32x4){0.f, 0.f, 0.f, 0.f};

  // prologue: tile0 fully (4A+3B), tile1 rounds 0-2 (3A+3B)
#pragma unroll
  for (int r = 0; r < 4; ++r) stageA(0, r, 0);
#pragma unroll
  for (int r = 0; r < 3; ++r) stageB(0, r, 0);
#pragma unroll
  for (int r = 0; r < 3; ++r) { stageA(1, r, 1); stageB(1, r, 1); }

  bf16x8 bfr[3][2], af[2][2];

  for (int kt = 0; kt < NT; ++kt) {
    const int cb = kt & 1, nb = cb ^ 1;
    if (kt + 1 < NT) asm volatile("s_waitcnt vmcnt(6)" ::: "memory");
    else             asm volatile("s_waitcnt vmcnt(0)" ::: "memory");
    __builtin_amdgcn_s_barrier();

    // ---- phase 0: stage(t+1) A round 3; read all B frags + A quad 0
    if (kt + 1 < NT) stageA(nb, 3, kt + 1);
#pragma unroll
    for (int ni = 0; ni < 3; ++ni)
#pragma unroll
      for (int kk = 0; kk < 2; ++kk) {
        const int r = wn * 48 + ni * 16 + row16;
        bfr[ni][kk] =
            *(const bf16x8*)&lds[cb][(256 + r) * 64 + (((kk * 4 + kg) ^ (r & 7)) << 3)];
      }
#pragma unroll
    for (int mi = 0; mi < 2; ++mi)
#pragma unroll
      for (int kk = 0; kk < 2; ++kk) {
        const int r = wm * 128 + mi * 16 + row16;
        af[mi][kk] = *(const bf16x8*)&lds[cb][r * 64 + (((kk * 4 + kg) ^ (r & 7)) << 3)];
      }
    asm volatile("s_waitcnt lgkmcnt(0)" ::: "memory");
    __builtin_amdgcn_s_setprio(1);
#pragma unroll
    for (int kk = 0; kk < 2; ++kk)
#pragma unroll
      for (int mi = 0; mi < 2; ++mi)
#pragma unroll
        for (int ni = 0; ni < 3; ++ni)
          acc[mi][ni] =
              __builtin_amdgcn_mfma_f32_16x16x32_bf16(af[mi][kk], bfr[ni][kk], acc[mi][ni], 0, 0, 0);
    __builtin_amdgcn_s_setprio(0);

    // ---- phases 1..3: stage(t+2) round q-1 (A and B); read A quad q
#pragma unroll
    for (int q = 1; q < 4; ++q) {
      __builtin_amdgcn_s_barrier();
      if (kt + 2 < NT) { stageA(cb, q - 1, kt + 2); stageB(cb, q - 1, kt + 2); }
#pragma unroll
      for (int mi = 0; mi < 2; ++mi)
#pragma unroll
        for (int kk = 0; kk < 2; ++kk) {
          const int r = wm * 128 + q * 32 + mi * 16 + row16;
          af[mi][kk] = *(const bf16x8*)&lds[cb][r * 64 + (((kk * 4 + kg) ^ (r & 7)) << 3)];
        }
      asm volatile("s_waitcnt lgkmcnt(0)" ::: "memory");
      __builtin_amdgcn_s_setprio(1);
#pragma unroll
      for (int kk = 0; kk < 2; ++kk)
#pragma unroll
        for (int mi = 0; mi < 2; ++mi)
#pragma unroll
          for (int ni = 0; ni < 3; ++ni)
            acc[q * 2 + mi][ni] = __builtin_amdgcn_mfma_f32_16x16x32_bf16(
                af[mi][kk], bfr[ni][kk], acc[q * 2 + mi][ni], 0, 0, 0);
      __builtin_amdgcn_s_setprio(0);
    }
  }

  float* Cf = (float*)Cv;
  bf16* Cb = (bf16*)Cv;
  const long long cz = (long long)blockIdx.z * sC;
#pragma unroll
  for (int mf = 0; mf < 8; ++mf)
#pragma unroll
    for (int ni = 0; ni < 3; ++ni)
#pragma unroll
      for (int rr = 0; rr < 4; ++rr) {
        const int row = m0 + wm * 128 + (mf >> 1) * 32 + (mf & 1) * 16 + kg * 4 + rr;
        const int col = n0 + wn * 48 + ni * 16 + row16;
        const long long idx = cz + (long long)row * ldc + col;
        const float v = acc[mf][ni][rr];
        if constexpr (EPI == 0) Cf[idx] = v;
        else Cb[idx] = (bf16)v;
      }
}

// ---------------------------------------------------------------------------
// Flash attention, KV-split.  Grid (16 q-tiles, 24 heads, 2 kv-splits).
// Writes unnormalized O (bf16) + per-row (m, l) f32.  Byte-identical to
// R16-R19 (reads qkv buffer with row stride 9216).
// ---------------------------------------------------------------------------
__global__ __launch_bounds__(256) void flash_attn_k(const bf16* __restrict__ qkv,
                                                    const bf16* __restrict__ vt,
                                                    bf16* __restrict__ Opb,
                                                    float* __restrict__ mlp) {
  __shared__ bf16 Ks[64 * 128];
  __shared__ bf16 Vs[128 * 64];
  __shared__ bf16 Ps[4 * 32 * 64];
  const int t = threadIdx.x, lane = t & 63, wid = t >> 6;
  const int row16 = lane & 15, kg = lane >> 4;
  const int q0 = blockIdx.x * 128;
  const int h = blockIdx.y;
  const int z = blockIdx.z;
  const bf16* Qp = qkv + h * 128;
  const bf16* Kp = qkv + 3072 + h * 128;
  const bf16* Vt = vt + (long long)h * 262144;
  const float iscale = 0.08838834764831845f;

  bf16x8 qf[2][4];
#pragma unroll
  for (int mi = 0; mi < 2; ++mi)
#pragma unroll
    for (int kc = 0; kc < 4; ++kc)
      qf[mi][kc] = *(const bf16x8*)&Qp[(long long)(q0 + wid * 32 + mi * 16 + row16) * 9216 +
                                       kc * 32 + kg * 8];
  bf16x8 ones;
#pragma unroll
  for (int j = 0; j < 8; ++j) ones[j] = (bf16)1.0f;

  f32x4 oacc[2][8];
#pragma unroll
  for (int mi = 0; mi < 2; ++mi)
#pragma unroll
    for (int nd = 0; nd < 8; ++nd) oacc[mi][nd] = (f32x4){0.f, 0.f, 0.f, 0.f};
  f32x4 lacc[2] = {(f32x4){0.f, 0.f, 0.f, 0.f}, (f32x4){0.f, 0.f, 0.f, 0.f}};
  float mst[2][4];
#pragma unroll
  for (int mi = 0; mi < 2; ++mi)
#pragma unroll
    for (int r = 0; r < 4; ++r) mst[mi][r] = -1e30f;

  bf16* Pw = &Ps[wid * 2048];
  const int kvbase = z << 10;

  for (int kv0 = kvbase; kv0 < kvbase + 1024; kv0 += 64) {
#pragma unroll
    for (int p = 0; p < 4; ++p) {
      const int gi = p * 256 + t;
      const int row = gi >> 4, g = gi & 15;
      __builtin_amdgcn_global_load_lds(
          (const AS1 void*)(Kp + (long long)(kv0 + row) * 9216 + ((g ^ (row & 7)) << 3)),
          (AS3 void*)&Ks[(p * 256 + wid * 64) * 8], 16, 0, 0);
    }
#pragma unroll
    for (int p = 0; p < 4; ++p) {
      const int gi = p * 256 + t;
      const int row = gi >> 3, g = gi & 7;
      __builtin_amdgcn_global_load_lds(
          (const AS1 void*)(Vt + (long long)row * 2048 + kv0 + ((g ^ (row & 7)) << 3)),
          (AS3 void*)&Vs[(p * 256 + wid * 64) * 8], 16, 0, 0);
    }
    __syncthreads();

    f32x4 sacc[2][4];
#pragma unroll
    for (int mi = 0; mi < 2; ++mi)
#pragma unroll
      for (int nf = 0; nf < 4; ++nf) sacc[mi][nf] = (f32x4){0.f, 0.f, 0.f, 0.f};
#pragma unroll
    for (int kc = 0; kc < 4; ++kc) {
      bf16x8 kf[4];
#pragma unroll
      for (int nf = 0; nf < 4; ++nf) {
        const int row = nf * 16 + row16;
        kf[nf] = *(const bf16x8*)&Ks[(row * 16 + ((kc * 4 + kg) ^ (row & 7))) * 8];
      }
#pragma unroll
      for (int mi = 0; mi < 2; ++mi)
#pragma unroll
        for (int nf = 0; nf < 4; ++nf)
          sacc[mi][nf] =
              __builtin_amdgcn_mfma_f32_16x16x32_bf16(qf[mi][kc], kf[nf], sacc[mi][nf], 0, 0, 0);
    }

    float fac[2][4];
#pragma unroll
    for (int mi = 0; mi < 2; ++mi)
#pragma unroll
      for (int r = 0; r < 4; ++r) {
        float rm = sacc[mi][0][r];
#pragma unroll
        for (int nf = 1; nf < 4; ++nf) rm = fmaxf(rm, sacc[mi][nf][r]);
        rm = fmaxf(rm, __shfl_xor(rm, 1, 64));
        rm = fmaxf(rm, __shfl_xor(rm, 2, 64));
        rm = fmaxf(rm, __shfl_xor(rm, 4, 64));
        rm = fmaxf(rm, __shfl_xor(rm, 8, 64));
        const float mnew = fmaxf(mst[mi][r], rm * iscale);
        fac[mi][r] = __expf(mst[mi][r] - mnew);
        mst[mi][r] = mnew;
#pragma unroll
        for (int nf = 0; nf < 4; ++nf)
          sacc[mi][nf][r] = __expf(sacc[mi][nf][r] * iscale - mnew);
      }
#pragma unroll
    for (int mi = 0; mi < 2; ++mi)
#pragma unroll
      for (int r = 0; r < 4; ++r) {
        lacc[mi][r] *= fac[mi][r];
#pragma unroll
        for (int nd = 0; nd < 8; ++nd) oacc[mi][nd][r] *= fac[mi][r];
      }

#pragma unroll
    for (int mi = 0; mi < 2; ++mi)
#pragma unroll
      for (int nf = 0; nf < 4; ++nf)
#pragma unroll
        for (int r = 0; r < 4; ++r) {
          const int row = mi * 16 + kg * 4 + r;
          const int col = nf * 16 + row16;
          Pw[(row * 8 + ((col >> 3) ^ (row & 7))) * 8 + (col & 7)] = (bf16)sacc[mi][nf][r];
        }

#pragma unroll
    for (int kvc = 0; kvc < 2; ++kvc) {
      bf16x8 pf[2], vf[8];
#pragma unroll
      for (int mi = 0; mi < 2; ++mi) {
        const int row = mi * 16 + row16;
        pf[mi] = *(const bf16x8*)&Pw[(row * 8 + ((kvc * 4 + kg) ^ (row & 7))) * 8];
      }
#pragma unroll
      for (int nd = 0; nd < 8; ++nd) {
        const int row = nd * 16 + row16;
        vf[nd] = *(const bf16x8*)&Vs[(row * 8 + ((kvc * 4 + kg) ^ (row & 7))) * 8];
      }
#pragma unroll
      for (int mi = 0; mi < 2; ++mi) {
        lacc[mi] = __builtin_amdgcn_mfma_f32_16x16x32_bf16(pf[mi], ones, lacc[mi], 0, 0, 0);
#pragma unroll
        for (int nd = 0; nd < 8; ++nd)
          oacc[mi][nd] =
              __builtin_amdgcn_mfma_f32_16x16x32_bf16(pf[mi], vf[nd], oacc[mi][nd], 0, 0, 0);
      }
    }
    __syncthreads();
  }

  // epilogue: store unnormalized O (bf16) and per-row (m, l)
  bf16* Oz = Opb + (long long)z * 6291456;
#pragma unroll
  for (int mi = 0; mi < 2; ++mi)
#pragma unroll
    for (int nd = 0; nd < 8; ++nd)
#pragma unroll
      for (int r = 0; r < 4; ++r) {
        const int row = q0 + wid * 32 + mi * 16 + kg * 4 + r;
        const int col = h * 128 + nd * 16 + row16;
        Oz[(long long)row * 3072 + col] = (bf16)oacc[mi][nd][r];
      }
  if (row16 == 0) {
#pragma unroll
    for (int mi = 0; mi < 2; ++mi)
#pragma unroll
      for (int r = 0; r < 4; ++r) {
        const int s = q0 + wid * 32 + mi * 16 + kg * 4 + r;
        const long long mi2 = ((long long)z * 49152 + s * 24 + h) * 2;
        mlp[mi2] = mst[mi][r];
        mlp[mi2 + 1] = lacc[mi][r];
      }
  }
}

// combine the 2 KV splits (vectorized: 16 lanes/pair, bf16x8 = 16B/lane)
__global__ __launch_bounds__(256) void fa_combine_k(const bf16* __restrict__ Opb,
                                                    const float* __restrict__ mlp,
                                                    bf16* __restrict__ attn) {
  const int t = threadIdx.x;
  const int pair = blockIdx.x * 16 + (t >> 4);  // s*24 + h
  const int lane16 = t & 15;
  const int s = pair / 24, h = pair % 24;
  const float2 ml0 = *(const float2*)&mlp[(long long)pair * 2];
  const float2 ml1 = *(const float2*)&mlp[(49152LL + pair) * 2];
  const float m = fmaxf(ml0.x, ml1.x);
  const float a0 = __expf(ml0.x - m), a1 = __expf(ml1.x - m);
  const float inv = 1.f / (ml0.y * a0 + ml1.y * a1);
  const long long base = (long long)s * 3072 + h * 128 + lane16 * 8;
  const bf16x8 o0 = *(const bf16x8*)&Opb[base];
  const bf16x8 o1 = *(const bf16x8*)&Opb[6291456LL + base];
  bf16x8 o;
#pragma unroll
  for (int j = 0; j < 8; ++j)
    o[j] = (bf16)(((float)o0[j] * a0 + (float)o1[j] * a1) * inv);
  *(bf16x8*)&attn[base] = o;
}

// ---------------------------------------------------------------------------
// convAll: all 7 weight conversions (f32 [R][C] -> bf16 [C][R]) in one launch.
// interleave16: out row = c0*2 + ((cl>>4)<<5) + (cl&15) + roff (w1/w3).
// ---------------------------------------------------------------------------
__device__ inline void convT_tile(const float* __restrict__ in, bf16* __restrict__ out,
                                  int R, int C, int bx, int by, int interleave16,
                                  int roff) {
  __shared__ float tile[64][65];
  const int t = threadIdx.x;
  const int r0 = by * 64, c0 = bx * 64;
#pragma unroll
  for (int it = 0; it < 4; ++it) {
    const int idx = it * 256 + t;
    const int rl = idx >> 4, c4 = (idx & 15) << 2;
    const float4 v = *(const float4*)&in[(long long)(r0 + rl) * C + c0 + c4];
    tile[rl][c4 + 0] = v.x;
    tile[rl][c4 + 1] = v.y;
    tile[rl][c4 + 2] = v.z;
    tile[rl][c4 + 3] = v.w;
  }
  __syncthreads();
#pragma unroll
  for (int it = 0; it < 4; ++it) {
    const int idx = it * 256 + t;
    const int cl = idx >> 4, r4 = (idx & 15) << 2;
    bf16x4 o;
    o[0] = (bf16)tile[r4 + 0][cl];
    o[1] = (bf16)tile[r4 + 1][cl];
    o[2] = (bf16)tile[r4 + 2][cl];
    o[3] = (bf16)tile[r4 + 3][cl];
    const long long orow = interleave16 ? (long long)(c0 * 2 + ((cl >> 4) << 5) +
                                                      (cl & 15) + roff)
                                        : (long long)(c0 + cl);
    *(bf16x4*)&out[orow * R + r0 + r4] = o;
  }
}

__global__ __launch_bounds__(256) void convAll(
    const float* __restrict__ wq, const float* __restrict__ wk,
    const float* __restrict__ wv, const float* __restrict__ wo,
    const float* __restrict__ w1, const float* __restrict__ w3,
    const float* __restrict__ w2, bf16* __restrict__ wqkvT, bf16* __restrict__ woT,
    bf16* __restrict__ w13T, bf16* __restrict__ w2T) {
  const int id = blockIdx.x;
  if (id < 9216) {
    const int m = id / 2304, l = id % 2304;
    const float* in = m == 0 ? wq : m == 1 ? wk : m == 2 ? wv : wo;
    bf16* out = m < 3 ? wqkvT + (long long)m * 9437184 : woT;
    convT_tile(in, out, 3072, 3072, l % 48, l / 48, 0, 0);
  } else if (id < 21504) {
    int l = id - 9216;
    const int m = l / 6144;
    l %= 6144;
    convT_tile(m ? w3 : w1, w13T, 3072, 8192, l % 128, l / 128, 1, m * 16);
  } else {
    const int l = id - 21504;
    convT_tile(w2, w2T, 8192, 3072, l % 48, l / 48, 0, 0);
  }
}

// merged setup: blocks 0-47 = adaln GEMV+gates; blocks 48-559 = rope tables
__global__ __launch_bounds__(256) void setup_k(const float* __restrict__ ain,
                                               const float* __restrict__ W,
                                               const float* __restrict__ b,
                                               float* __restrict__ adv,
                                               const int* __restrict__ ids,
                                               float* __restrict__ cosT,
                                               float* __restrict__ sinT) {
  const int t = threadIdx.x;
  if (blockIdx.x < 48) {
    __shared__ float a[256];
    a[t] = ain[t];
    __syncthreads();
    const int n = blockIdx.x * 256 + t;
    float acc = b[n];
    for (int k = 0; k < 256; ++k) acc = fmaf(a[k], W[(long long)k * 12288 + n], acc);
    const int chunk = n / 3072;
    adv[n] = (chunk & 1) ? tanhf(acc) : (1.f + acc);
  } else {
    const int i = (blockIdx.x - 48) * 256 + t;  // S*64
    const int s = i >> 6, j = i & 63;
    int ax, fi;
    float d;
    if (j < 8) { ax = 0; fi = j; d = 16.f; }
    else if (j < 36) { ax = 1; fi = j - 8; d = 56.f; }
    else { ax = 2; fi = j - 36; d = 56.f; }
    const float freq = exp2f(-16.f * (float)fi / d);
    const float ang = (float)ids[s * 3 + ax] * freq;
    cosT[i] = cosf(ang);
    sinT[i] = sinf(ang);
  }
}

// xs = rmsnorm(x, w, 1e-6) * scale  -> bf16
__global__ __launch_bounds__(256) void rmsnorm_scale_k(const float* __restrict__ x,
                                                       const float* __restrict__ w,
                                                       const float* __restrict__ scale,
                                                       bf16* __restrict__ out) {
  __shared__ float red[4];
  const int t = threadIdx.x, lane = t & 63, wid = t >> 6;
  const long long base = (long long)blockIdx.x * 3072;
  float v[12];
  float ss = 0.f;
#pragma unroll
  for (int ch = 0; ch < 3; ++ch) {
    const float4 f = *(const float4*)&x[base + ch * 1024 + t * 4];
    v[ch * 4 + 0] = f.x; v[ch * 4 + 1] = f.y; v[ch * 4 + 2] = f.z; v[ch * 4 + 3] = f.w;
    ss += f.x * f.x + f.y * f.y + f.z * f.z + f.w * f.w;
  }
  ss = wsum(ss);
  if (!lane) red[wid] = ss;
  __syncthreads();
  const float r = rsqrtf((red[0] + red[1] + red[2] + red[3]) / 3072.f + 1e-6f);
#pragma unroll
  for (int ch = 0; ch < 3; ++ch) {
    const int col = ch * 1024 + t * 4;
    bf16x4 o;
#pragma unroll
    for (int j = 0; j < 4; ++j) o[j] = (bf16)(v[ch * 4 + j] * r * w[col + j] * scale[col + j]);
    *(bf16x4*)&out[base + col] = o;
  }
}

// per (s,h): combine 2 QKV split-K partials, rmsnorm(QK_EPS) over 128 + RoPE,
// in place into partial-0.  Vectorized: 16 lanes/row, bf16x8 loads.
__global__ __launch_bounds__(256) void qknorm_rope_k(bf16* __restrict__ qkvP,
                                                     const float* __restrict__ cosT,
                                                     const float* __restrict__ sinT,
                                                     const float* __restrict__ wq,
                                                     const float* __restrict__ wk) {
  const int t = threadIdx.x;
  const int idx = blockIdx.x * 16 + (t >> 4);  // s*24 + h
  const int lane16 = t & 15;
  const int s = idx / 24, h = idx % 24;
  const int isK = blockIdx.y;
  bf16* base = qkvP + (long long)s * 9216 + isK * 3072 + h * 128 + lane16 * 8;
  const bf16x8 p0 = *(const bf16x8*)base;
  const bf16x8 p1 = *(const bf16x8*)(base + 18874368LL);
  float xv[8];
  float ss = 0.f;
#pragma unroll
  for (int j = 0; j < 8; ++j) {
    xv[j] = (float)p0[j] + (float)p1[j];
    ss += xv[j] * xv[j];
  }
  ss += __shfl_xor(ss, 1, 64);
  ss += __shfl_xor(ss, 2, 64);
  ss += __shfl_xor(ss, 4, 64);
  ss += __shfl_xor(ss, 8, 64);
  const float r = rsqrtf(ss / 128.f + 1e-5f);
  const float* w = isK ? wk : wq;
  const float4 w0 = *(const float4*)&w[lane16 * 8];
  const float4 w1 = *(const float4*)&w[lane16 * 8 + 4];
  const float wa[8] = {w0.x, w0.y, w0.z, w0.w, w1.x, w1.y, w1.z, w1.w};
  const float4 cs = *(const float4*)&cosT[s * 64 + lane16 * 4];
  const float4 sn = *(const float4*)&sinT[s * 64 + lane16 * 4];
  const float cc[4] = {cs.x, cs.y, cs.z, cs.w};
  const float sv[4] = {sn.x, sn.y, sn.z, sn.w};
  bf16x8 o;
#pragma unroll
  for (int p = 0; p < 4; ++p) {
    const float xr = xv[2 * p] * r * wa[2 * p];
    const float xi = xv[2 * p + 1] * r * wa[2 * p + 1];
    o[2 * p]     = (bf16)(xr * cc[p] - xi * sv[p]);
    o[2 * p + 1] = (bf16)(xr * sv[p] + xi * cc[p]);
  }
  *(bf16x8*)base = o;
}

// vt[h][d][s] = sum of the 2 v partials qkvP[z][s][6144 + h*128 + d]
__global__ __launch_bounds__(256) void vtrans_k(const bf16* __restrict__ qkvP,
                                                bf16* __restrict__ vt) {
  __shared__ bf16 tile[64][72];
  const int t = threadIdx.x;
  const int s0 = blockIdx.x * 64, d0 = blockIdx.y * 64, h = blockIdx.z;
#pragma unroll
  for (int it = 0; it < 2; ++it) {
    const int idx = it * 256 + t;
    const int sl = idx >> 3, c8 = (idx & 7) << 3;
    const long long base = (long long)(s0 + sl) * 9216 + 6144 + h * 128 + d0 + c8;
    const bf16x8 v0 = *(const bf16x8*)&qkvP[base];
    const bf16x8 v1 = *(const bf16x8*)&qkvP[base + 18874368LL];
    bf16x8 v;
#pragma unroll
    for (int j = 0; j < 8; ++j) v[j] = (bf16)((float)v0[j] + (float)v1[j]);
    *(bf16x8*)&tile[sl][c8] = v;
  }
  __syncthreads();
#pragma unroll
  for (int it = 0; it < 2; ++it) {
    const int idx = it * 256 + t;
    const int dl = idx >> 3, s8 = (idx & 7) << 3;
    bf16x8 o;
#pragma unroll
    for (int j = 0; j < 8; ++j) o[j] = tile[s8 + j][dl];
    *(bf16x8*)&vt[(long long)h * 262144 + (long long)(d0 + dl) * 2048 + s0 + s8] = o;
  }
}

// x1 = x + gate*rmsnorm(p0+p1, n2w, 1e-6); xf = rmsnorm(x1, f1w, 1e-6)*smlp (bf16)
__global__ __launch_bounds__(256) void resid1_k(
    const float* __restrict__ x, const bf16* __restrict__ p0, const bf16* __restrict__ p1,
    const float* __restrict__ n2w, const float* __restrict__ gate,
    const float* __restrict__ f1w, const float* __restrict__ smlp,
    float* __restrict__ x1, bf16* __restrict__ xf) {
  __shared__ float red[8];
  const int t = threadIdx.x, lane = t & 63, wid = t >> 6;
  const long long base = (long long)blockIdx.x * 3072;
  float av[12];
  float ss = 0.f;
#pragma unroll
  for (int ch = 0; ch < 3; ++ch) {
    const bf16x4 f0 = *(const bf16x4*)&p0[base + ch * 1024 + t * 4];
    const bf16x4 f1 = *(const bf16x4*)&p1[base + ch * 1024 + t * 4];
#pragma unroll
    for (int j = 0; j < 4; ++j) {
      const float a = (float)f0[j] + (float)f1[j];
      av[ch * 4 + j] = a;
      ss += a * a;
    }
  }
  ss = wsum(ss);
  if (!lane) red[wid] = ss;
  __syncthreads();
  const float r = rsqrtf((red[0] + red[1] + red[2] + red[3]) / 3072.f + 1e-6f);
  float xv[12];
  float ss2 = 0.f;
#pragma unroll
  for (int ch = 0; ch < 3; ++ch) {
    const int col = ch * 1024 + t * 4;
    const float4 f = *(const float4*)&x[base + col];
    float4 o;
    o.x = f.x + gate[col + 0] * (av[ch * 4 + 0] * r * n2w[col + 0]);
    o.y = f.y + gate[col + 1] * (av[ch * 4 + 1] * r * n2w[col + 1]);
    o.z = f.z + gate[col + 2] * (av[ch * 4 + 2] * r * n2w[col + 2]);
    o.w = f.w + gate[col + 3] * (av[ch * 4 + 3] * r * n2w[col + 3]);
    *(float4*)&x1[base + col] = o;
    xv[ch * 4 + 0] = o.x; xv[ch * 4 + 1] = o.y; xv[ch * 4 + 2] = o.z; xv[ch * 4 + 3] = o.w;
    ss2 += o.x * o.x + o.y * o.y + o.z * o.z + o.w * o.w;
  }
  ss2 = wsum(ss2);
  if (!lane) red[4 + wid] = ss2;
  __syncthreads();
  const float r2 = rsqrtf((red[4] + red[5] + red[6] + red[7]) / 3072.f + 1e-6f);
#pragma unroll
  for (int ch = 0; ch < 3; ++ch) {
    const int col = ch * 1024 + t * 4;
    bf16x4 o;
#pragma unroll
    for (int j = 0; j < 4; ++j)
      o[j] = (bf16)(xv[ch * 4 + j] * r2 * f1w[col + j] * smlp[col + j]);
    *(bf16x4*)&xf[base + col] = o;
  }
}

// out = x1 + gate*rmsnorm(f0+f1, nw, 1e-6)  (f32 output; f0/f1 bf16 partials)
__global__ __launch_bounds__(256) void resid2_k(const float* __restrict__ x1,
                                                const bf16* __restrict__ f0,
                                                const bf16* __restrict__ f1,
                                                const float* __restrict__ nw,
                                                const float* __restrict__ gate,
                                                float* __restrict__ out) {
  __shared__ float red[4];
  const int t = threadIdx.x, lane = t & 63, wid = t >> 6;
  const long long base = (long long)blockIdx.x * 3072;
  float fv[12];
  float ss = 0.f;
#pragma unroll
  for (int ch = 0; ch < 3; ++ch) {
    const bf16x4 a = *(const bf16x4*)&f0[base + ch * 1024 + t * 4];
    const bf16x4 b = *(const bf16x4*)&f1[base + ch * 1024 + t * 4];
#pragma unroll
    for (int j = 0; j < 4; ++j) {
      const float v = (float)a[j] + (float)b[j];
      fv[ch * 4 + j] = v;
      ss += v * v;
    }
  }
  ss = wsum(ss);
  if (!lane) red[wid] = ss;
  __syncthreads();
  const float r = rsqrtf((red[0] + red[1] + red[2] + red[3]) / 3072.f + 1e-6f);
#pragma unroll
  for (int ch = 0; ch < 3; ++ch) {
    const int col = ch * 1024 + t * 4;
    const float4 f = *(const float4*)&x1[base + col];
    float4 o;
    o.x = f.x + gate[col + 0] * (fv[ch * 4 + 0] * r * nw[col + 0]);
    o.y = f.y + gate[col + 1] * (fv[ch * 4 + 1] * r * nw[col + 1]);
    o.z = f.z + gate[col + 2] * (fv[ch * 4 + 2] * r * nw[col + 2]);
    o.w = f.w + gate[col + 3] * (fv[ch * 4 + 3] * r * nw[col + 3]);
    *(float4*)&out[base + col] = o;
  }
}

extern "C" void kernel_launch(void* const* d_in, const int* in_sizes, int n_in,
                              void* d_out, int out_size, void* d_ws, size_t ws_size,
                              hipStream_t stream) {
  const float* x    = (const float*)d_in[0];
  const float* ain  = (const float*)d_in[1];
  const int* ids    = (const int*)d_in[3];
  const float* n1w  = (const float*)d_in[4];
  const float* n2w  = (const float*)d_in[5];
  const float* fn1w = (const float*)d_in[6];
  const float* fn2w = (const float*)d_in[7];
  const float* nqw  = (const float*)d_in[8];
  const float* nkw  = (const float*)d_in[9];
  const float* wq   = (const float*)d_in[10];
  const float* wk   = (const float*)d_in[11];
  const float* wv   = (const float*)d_in[12];
  const float* wo   = (const float*)d_in[13];
  const float* w1   = (const float*)d_in[14];
  const float* w2   = (const float*)d_in[15];
  const float* w3   = (const float*)d_in[16];
  const float* adw  = (const float*)d_in[17];
  const float* adb  = (const float*)d_in[18];

  if (ws_size < 395362304ULL) return;

  char* ws = (char*)d_ws;
  bf16* wqkvT = (bf16*)(ws + 0LL);             // [9216][3072]
  bf16* woT   = (bf16*)(ws + 56623104LL);      // [3072][3072]
  bf16* w13T  = (bf16*)(ws + 75497472LL);      // [16384][3072] 16-granular interleave
  bf16* w2T   = (bf16*)(ws + 176160768LL);     // [3072][8192]
  float* cosT = (float*)(ws + 226492416LL);    // [2048][64]
  float* sinT = (float*)(ws + 227016704LL);
  float* adv  = (float*)(ws + 227540992LL);    // [4][3072]
  bf16* xs    = (bf16*)(ws + 227590144LL);     // [2048][3072], reused as xf
  char* big   = ws + 240173056LL;              // overlay region (155,189,248 B)
  float* x1   = (float*)(big);                 // 0 .. 25165824
  bf16* qkvP  = (bf16*)(big + 25165824LL);     // [2][2048][9216] .. 100663296
  bf16* vt    = (bf16*)(big + 100663296LL);    // [24][128][2048] .. 113246208
  bf16* attn  = (bf16*)(big + 113246208LL);    // [2048][3072]    .. 125829120
  bf16* Opb   = (bf16*)(big + 125829120LL);    // [2][2048][3072] .. 150994944
  float* mlp  = (float*)(big + 150994944LL);   // [2][49152][2]   .. 151781376
  bf16* aoP   = (bf16*)(big + 25165824LL);     // [2][2048][3072] (qkvP dead)
  bf16* hbuf  = (bf16*)(big + 50331648LL);     // [2048][8192] (aoP dead after resid1)
  bf16* ffnP  = (bf16*)(big + 83886080LL);     // [2][2048][3072] .. 109051904

  const dim3 b256(256);
  const dim3 b512(512);

  setup_k<<<dim3(560), b256, 0, stream>>>(ain, adw, adb, adv, ids, cosT, sinT);

  convAll<<<dim3(27648), b256, 0, stream>>>(wq, wk, wv, wo, w1, w3, w2, wqkvT, woT, w13T,
                                            w2T);

  rmsnorm_scale_k<<<dim3(2048), b256, 0, stream>>>(x, n1w, adv, xs);

  // QKV: split-K z=2 (768 blocks = 3 exact rounds); partial-sum folded into
  // the consumers below.
  gemm192<1><<<dim3(8, 48, 2), b512, 0, stream>>>(xs, wqkvT, qkvP, 1536, 3072, 3072, 9216,
                                                  1536LL, 18874368LL);

  // combine partials + norm + rope in place (q,k); sum partials in vtrans (v)
  qknorm_rope_k<<<dim3(3072, 2), b256, 0, stream>>>(qkvP, cosT, sinT, nqw, nkw);
  vtrans_k<<<dim3(32, 2, 24), b256, 0, stream>>>(qkvP, vt);

  // flash attention (reads qkvP[0] with stride 9216) + vectorized combine
  flash_attn_k<<<dim3(16, 24, 2), b256, 0, stream>>>(qkvP, vt, Opb, mlp);
  fa_combine_k<<<dim3(3072), b256, 0, stream>>>(Opb, mlp, attn);

  // Wo: attn @ woT^T, split-K 2, bf16 partials (gemm192: grid 256 exact)
  gemm192<1><<<dim3(8, 16, 2), b512, 0, stream>>>(attn, woT, aoP, 1536, 3072, 3072, 3072,
                                                  1536LL, 6291456LL);
  resid1_k<<<dim3(2048), b256, 0, stream>>>(x, aoP, aoP + 6291456LL, n2w, adv + 3072, fn1w,
                                            adv + 6144, x1, xs);
  // FFN up + fused silu-mul (16-granular interleave): xf @ w13T^T -> hbuf bf16
  gemm256<2><<<dim3(8, 64, 1), b512, 0, stream>>>(xs, w13T, hbuf, 3072, 3072, 3072, 8192,
                                                  0LL, 0LL);
  // FFN down: h @ w2T^T, split-K 2, bf16 partials (gemm192: grid 256 exact)
  gemm192<1><<<dim3(8, 16, 2), b512, 0, stream>>>(hbuf, w2T, ffnP, 4096, 8192, 8192, 3072,
                                                  4096LL, 6291456LL);
  resid2_k<<<dim3(2048), b256, 0, stream>>>(x1, ffnP, ffnP + 6291456LL, fn2w, adv + 9216,
                                            (float*)d_out);
}

// Round 21
// 776.333 us; speedup vs baseline: 1.0383x; 1.0014x over previous
//
#include <hip/hip_runtime.h>

#define AS1 __attribute__((address_space(1)))
#define AS3 __attribute__((address_space(3)))

typedef __bf16 bf16;
using bf16x8 = __attribute__((ext_vector_type(8))) __bf16;
using bf16x4 = __attribute__((ext_vector_type(4))) __bf16;
using bf16x2 = __attribute__((ext_vector_type(2))) __bf16;
using f32x4  = __attribute__((ext_vector_type(4))) float;

// Problem constants: B=1, S=2048, D=3072, H=24, HD=128, FFN=8192

__device__ inline float wsum(float v) {
#pragma unroll
  for (int o = 32; o; o >>= 1) v += __shfl_xor(v, o, 64);
  return v;
}

// ---------------------------------------------------------------------------
// gemm256 — K-loop byte-identical to R11-R20 (single barrier/phase, vmcnt(6);
// do NOT refactor LDS decl or loop body — R8/R9 lesson).
// EPI: 0=f32, 1=bf16, 2=fused silu(w1)*w3 with 16-granular interleaved B.
// ---------------------------------------------------------------------------
template <int EPI>
__global__ __launch_bounds__(512, 1) void gemm256(
    const bf16* __restrict__ A, const bf16* __restrict__ Bt, void* __restrict__ Cv,
    int K, int lda, int ldb, int ldc, long long kOff, long long sC) {
  __shared__ bf16 lds[2][2][256 * 64];  // [buf][A/B][row*64+col]
  const int t = threadIdx.x;
  const int lane = t & 63, wid = t >> 6;
  const int wm = wid >> 2, wn = wid & 3;
  const int row16 = lane & 15, kg = lane >> 4;
  const int m0 = blockIdx.x * 256, n0 = blockIdx.y * 256;
  const int NT = K >> 6;
  const int sgran = (lane & 7) ^ (lane >> 3);  // pre-swizzled source granule
  A += (long long)blockIdx.z * kOff;
  Bt += (long long)blockIdx.z * kOff;

  auto stageA = [&](int buf, int r, int tk) {
    const int wrow = ((wid & 4) << 5) + (r << 5) + ((wid & 3) << 3);  // wave-uniform
    __builtin_amdgcn_global_load_lds(
        (const AS1 void*)(A + (long long)(m0 + wrow + (lane >> 3)) * lda + tk * 64 +
                          (sgran << 3)),
        (AS3 void*)&lds[buf][0][wrow * 64], 16, 0, 0);
  };
  auto stageB = [&](int buf, int r, int tk) {
    const int wrow = ((wid & 4) << 5) + (r << 5) + ((wid & 3) << 3);
    __builtin_amdgcn_global_load_lds(
        (const AS1 void*)(Bt + (long long)(n0 + wrow + (lane >> 3)) * ldb + tk * 64 +
                          (sgran << 3)),
        (AS3 void*)&lds[buf][1][wrow * 64], 16, 0, 0);
  };

  f32x4 acc[8][4];
#pragma unroll
  for (int i = 0; i < 8; ++i)
#pragma unroll
    for (int j = 0; j < 4; ++j) acc[i][j] = (f32x4){0.f, 0.f, 0.f, 0.f};

  // prologue: stage tile0 fully (8), tile1 rounds 0-2 (6)
#pragma unroll
  for (int r = 0; r < 4; ++r) { stageA(0, r, 0); stageB(0, r, 0); }
#pragma unroll
  for (int r = 0; r < 3; ++r) { stageA(1, r, 1); stageB(1, r, 1); }

  bf16x8 bfr[4][2], af[2][2];

  for (int kt = 0; kt < NT; ++kt) {
    const int cb = kt & 1, nb = cb ^ 1;
    if (kt + 1 < NT) asm volatile("s_waitcnt vmcnt(6)" ::: "memory");
    else             asm volatile("s_waitcnt vmcnt(0)" ::: "memory");
    __builtin_amdgcn_s_barrier();

    // ---- phase 0: stage(t+1) round 3; read all B frags + A quad 0
    if (kt + 1 < NT) { stageA(nb, 3, kt + 1); stageB(nb, 3, kt + 1); }
#pragma unroll
    for (int ni = 0; ni < 4; ++ni)
#pragma unroll
      for (int kk = 0; kk < 2; ++kk) {
        const int r = wn * 64 + ni * 16 + row16;
        bfr[ni][kk] = *(const bf16x8*)&lds[cb][1][r * 64 + (((kk * 4 + kg) ^ (r & 7)) << 3)];
      }
#pragma unroll
    for (int mi = 0; mi < 2; ++mi)
#pragma unroll
      for (int kk = 0; kk < 2; ++kk) {
        const int r = wm * 128 + mi * 16 + row16;
        af[mi][kk] = *(const bf16x8*)&lds[cb][0][r * 64 + (((kk * 4 + kg) ^ (r & 7)) << 3)];
      }
    asm volatile("s_waitcnt lgkmcnt(0)" ::: "memory");
    __builtin_amdgcn_s_setprio(1);
#pragma unroll
    for (int kk = 0; kk < 2; ++kk)
#pragma unroll
      for (int mi = 0; mi < 2; ++mi)
#pragma unroll
        for (int ni = 0; ni < 4; ++ni)
          acc[mi][ni] =
              __builtin_amdgcn_mfma_f32_16x16x32_bf16(af[mi][kk], bfr[ni][kk], acc[mi][ni], 0, 0, 0);
    __builtin_amdgcn_s_setprio(0);

    // ---- phases 1..3: stage(t+2) round q-1; read A quad q
#pragma unroll
    for (int q = 1; q < 4; ++q) {
      __builtin_amdgcn_s_barrier();
      if (kt + 2 < NT) { stageA(cb, q - 1, kt + 2); stageB(cb, q - 1, kt + 2); }
#pragma unroll
      for (int mi = 0; mi < 2; ++mi)
#pragma unroll
        for (int kk = 0; kk < 2; ++kk) {
          const int r = wm * 128 + q * 32 + mi * 16 + row16;
          af[mi][kk] = *(const bf16x8*)&lds[cb][0][r * 64 + (((kk * 4 + kg) ^ (r & 7)) << 3)];
        }
      asm volatile("s_waitcnt lgkmcnt(0)" ::: "memory");
      __builtin_amdgcn_s_setprio(1);
#pragma unroll
      for (int kk = 0; kk < 2; ++kk)
#pragma unroll
        for (int mi = 0; mi < 2; ++mi)
#pragma unroll
          for (int ni = 0; ni < 4; ++ni)
            acc[q * 2 + mi][ni] = __builtin_amdgcn_mfma_f32_16x16x32_bf16(
                af[mi][kk], bfr[ni][kk], acc[q * 2 + mi][ni], 0, 0, 0);
      __builtin_amdgcn_s_setprio(0);
    }
  }

  float* Cf = (float*)Cv;
  bf16* Cb = (bf16*)Cv;
  const long long cz = (long long)blockIdx.z * sC;
  if constexpr (EPI == 2) {
#pragma unroll
    for (int mf = 0; mf < 8; ++mf)
#pragma unroll
      for (int np = 0; np < 2; ++np)
#pragma unroll
        for (int rr = 0; rr < 4; ++rr) {
          const int row = m0 + wm * 128 + (mf >> 1) * 32 + (mf & 1) * 16 + kg * 4 + rr;
          const int col = (n0 >> 1) + wn * 32 + np * 16 + row16;
          const float a = acc[mf][np * 2][rr];
          const float b = acc[mf][np * 2 + 1][rr];
          const float sl = a / (1.f + __expf(-a));
          Cb[cz + (long long)row * ldc + col] = (bf16)(sl * b);
        }
  } else {
#pragma unroll
    for (int mf = 0; mf < 8; ++mf)
#pragma unroll
      for (int ni = 0; ni < 4; ++ni)
#pragma unroll
        for (int rr = 0; rr < 4; ++rr) {
          const int row = m0 + wm * 128 + (mf >> 1) * 32 + (mf & 1) * 16 + kg * 4 + rr;
          const int col = n0 + wn * 64 + ni * 16 + row16;
          const long long idx = cz + (long long)row * ldc + col;
          const float v = acc[mf][ni][rr];
          if constexpr (EPI == 0) Cf[idx] = v;
          else Cb[idx] = (bf16)v;
        }
  }
}

// ---------------------------------------------------------------------------
// gemm192 — single barrier/phase (R20-validated), vmcnt(6), single LDS array
// (A rows 0-255, B rows 256-447).  Split-K via blockIdx.z.
// EPI: 0=f32 store, 1=bf16 store.
// ---------------------------------------------------------------------------
template <int EPI>
__global__ __launch_bounds__(512, 1) void gemm192(
    const bf16* __restrict__ A, const bf16* __restrict__ Bt, void* __restrict__ Cv,
    int K, int lda, int ldb, int ldc, long long kOff, long long sC) {
  __shared__ bf16 lds[2][448 * 64];  // [buf][A(0-255)|B(256-447)][col]
  const int t = threadIdx.x;
  const int lane = t & 63, wid = t >> 6;
  const int wm = wid >> 2, wn = wid & 3;
  const int row16 = lane & 15, kg = lane >> 4;
  const int m0 = blockIdx.x * 256, n0 = blockIdx.y * 192;
  const int NT = K >> 6;
  const int sgran = (lane & 7) ^ (lane >> 3);
  A += (long long)blockIdx.z * kOff;
  Bt += (long long)blockIdx.z * kOff;

  auto stageA = [&](int buf, int r, int tk) {
    const int wrow = ((wid & 4) << 5) + (r << 5) + ((wid & 3) << 3);
    __builtin_amdgcn_global_load_lds(
        (const AS1 void*)(A + (long long)(m0 + wrow + (lane >> 3)) * lda + tk * 64 +
                          (sgran << 3)),
        (AS3 void*)&lds[buf][wrow * 64], 16, 0, 0);
  };
  auto stageB = [&](int buf, int r, int tk) {
    const int wrow = r * 64 + wid * 8;  // r in 0..2 covers 192 rows
    __builtin_amdgcn_global_load_lds(
        (const AS1 void*)(Bt + (long long)(n0 + wrow + (lane >> 3)) * ldb + tk * 64 +
                          (sgran << 3)),
        (AS3 void*)&lds[buf][(256 + wrow) * 64], 16, 0, 0);
  };

  f32x4 acc[8][3];
#pragma unroll
  for (int i = 0; i < 8; ++i)
#pragma unroll
    for (int j = 0; j < 3; ++j) acc[i][j] = (f32x4){0.f, 0.f, 0.f, 0.f};

  // prologue: tile0 fully (4A+3B), tile1 rounds 0-2 (3A+3B)
#pragma unroll
  for (int r = 0; r < 4; ++r) stageA(0, r, 0);
#pragma unroll
  for (int r = 0; r < 3; ++r) stageB(0, r, 0);
#pragma unroll
  for (int r = 0; r < 3; ++r) { stageA(1, r, 1); stageB(1, r, 1); }

  bf16x8 bfr[3][2], af[2][2];

  for (int kt = 0; kt < NT; ++kt) {
    const int cb = kt & 1, nb = cb ^ 1;
    if (kt + 1 < NT) asm volatile("s_waitcnt vmcnt(6)" ::: "memory");
    else             asm volatile("s_waitcnt vmcnt(0)" ::: "memory");
    __builtin_amdgcn_s_barrier();

    // ---- phase 0: stage(t+1) A round 3; read all B frags + A quad 0
    if (kt + 1 < NT) stageA(nb, 3, kt + 1);
#pragma unroll
    for (int ni = 0; ni < 3; ++ni)
#pragma unroll
      for (int kk = 0; kk < 2; ++kk) {
        const int r = wn * 48 + ni * 16 + row16;
        bfr[ni][kk] =
            *(const bf16x8*)&lds[cb][(256 + r) * 64 + (((kk * 4 + kg) ^ (r & 7)) << 3)];
      }
#pragma unroll
    for (int mi = 0; mi < 2; ++mi)
#pragma unroll
      for (int kk = 0; kk < 2; ++kk) {
        const int r = wm * 128 + mi * 16 + row16;
        af[mi][kk] = *(const bf16x8*)&lds[cb][r * 64 + (((kk * 4 + kg) ^ (r & 7)) << 3)];
      }
    asm volatile("s_waitcnt lgkmcnt(0)" ::: "memory");
    __builtin_amdgcn_s_setprio(1);
#pragma unroll
    for (int kk = 0; kk < 2; ++kk)
#pragma unroll
      for (int mi = 0; mi < 2; ++mi)
#pragma unroll
        for (int ni = 0; ni < 3; ++ni)
          acc[mi][ni] =
              __builtin_amdgcn_mfma_f32_16x16x32_bf16(af[mi][kk], bfr[ni][kk], acc[mi][ni], 0, 0, 0);
    __builtin_amdgcn_s_setprio(0);

    // ---- phases 1..3: stage(t+2) round q-1 (A and B); read A quad q
#pragma unroll
    for (int q = 1; q < 4; ++q) {
      __builtin_amdgcn_s_barrier();
      if (kt + 2 < NT) { stageA(cb, q - 1, kt + 2); stageB(cb, q - 1, kt + 2); }
#pragma unroll
      for (int mi = 0; mi < 2; ++mi)
#pragma unroll
        for (int kk = 0; kk < 2; ++kk) {
          const int r = wm * 128 + q * 32 + mi * 16 + row16;
          af[mi][kk] = *(const bf16x8*)&lds[cb][r * 64 + (((kk * 4 + kg) ^ (r & 7)) << 3)];
        }
      asm volatile("s_waitcnt lgkmcnt(0)" ::: "memory");
      __builtin_amdgcn_s_setprio(1);
#pragma unroll
      for (int kk = 0; kk < 2; ++kk)
#pragma unroll
        for (int mi = 0; mi < 2; ++mi)
#pragma unroll
          for (int ni = 0; ni < 3; ++ni)
            acc[q * 2 + mi][ni] = __builtin_amdgcn_mfma_f32_16x16x32_bf16(
                af[mi][kk], bfr[ni][kk], acc[q * 2 + mi][ni], 0, 0, 0);
      __builtin_amdgcn_s_setprio(0);
    }
  }

  float* Cf = (float*)Cv;
  bf16* Cb = (bf16*)Cv;
  const long long cz = (long long)blockIdx.z * sC;
#pragma unroll
  for (int mf = 0; mf < 8; ++mf)
#pragma unroll
    for (int ni = 0; ni < 3; ++ni)
#pragma unroll
      for (int rr = 0; rr < 4; ++rr) {
        const int row = m0 + wm * 128 + (mf >> 1) * 32 + (mf & 1) * 16 + kg * 4 + rr;
        const int col = n0 + wn * 48 + ni * 16 + row16;
        const long long idx = cz + (long long)row * ldc + col;
        const float v = acc[mf][ni][rr];
        if constexpr (EPI == 0) Cf[idx] = v;
        else Cb[idx] = (bf16)v;
      }
}

// ---------------------------------------------------------------------------
// Flash attention, KV-split.  Grid (16 q-tiles, 24 heads, 2 kv-splits).
// Writes unnormalized O (bf16) + per-row (m, l) f32.  Byte-identical to
// R16-R20 (reads qkv buffer with row stride 9216).
// ---------------------------------------------------------------------------
__global__ __launch_bounds__(256) void flash_attn_k(const bf16* __restrict__ qkv,
                                                    const bf16* __restrict__ vt,
                                                    bf16* __restrict__ Opb,
                                                    float* __restrict__ mlp) {
  __shared__ bf16 Ks[64 * 128];
  __shared__ bf16 Vs[128 * 64];
  __shared__ bf16 Ps[4 * 32 * 64];
  const int t = threadIdx.x, lane = t & 63, wid = t >> 6;
  const int row16 = lane & 15, kg = lane >> 4;
  const int q0 = blockIdx.x * 128;
  const int h = blockIdx.y;
  const int z = blockIdx.z;
  const bf16* Qp = qkv + h * 128;
  const bf16* Kp = qkv + 3072 + h * 128;
  const bf16* Vt = vt + (long long)h * 262144;
  const float iscale = 0.08838834764831845f;

  bf16x8 qf[2][4];
#pragma unroll
  for (int mi = 0; mi < 2; ++mi)
#pragma unroll
    for (int kc = 0; kc < 4; ++kc)
      qf[mi][kc] = *(const bf16x8*)&Qp[(long long)(q0 + wid * 32 + mi * 16 + row16) * 9216 +
                                       kc * 32 + kg * 8];
  bf16x8 ones;
#pragma unroll
  for (int j = 0; j < 8; ++j) ones[j] = (bf16)1.0f;

  f32x4 oacc[2][8];
#pragma unroll
  for (int mi = 0; mi < 2; ++mi)
#pragma unroll
    for (int nd = 0; nd < 8; ++nd) oacc[mi][nd] = (f32x4){0.f, 0.f, 0.f, 0.f};
  f32x4 lacc[2] = {(f32x4){0.f, 0.f, 0.f, 0.f}, (f32x4){0.f, 0.f, 0.f, 0.f}};
  float mst[2][4];
#pragma unroll
  for (int mi = 0; mi < 2; ++mi)
#pragma unroll
    for (int r = 0; r < 4; ++r) mst[mi][r] = -1e30f;

  bf16* Pw = &Ps[wid * 2048];
  const int kvbase = z << 10;

  for (int kv0 = kvbase; kv0 < kvbase + 1024; kv0 += 64) {
#pragma unroll
    for (int p = 0; p < 4; ++p) {
      const int gi = p * 256 + t;
      const int row = gi >> 4, g = gi & 15;
      __builtin_amdgcn_global_load_lds(
          (const AS1 void*)(Kp + (long long)(kv0 + row) * 9216 + ((g ^ (row & 7)) << 3)),
          (AS3 void*)&Ks[(p * 256 + wid * 64) * 8], 16, 0, 0);
    }
#pragma unroll
    for (int p = 0; p < 4; ++p) {
      const int gi = p * 256 + t;
      const int row = gi >> 3, g = gi & 7;
      __builtin_amdgcn_global_load_lds(
          (const AS1 void*)(Vt + (long long)row * 2048 + kv0 + ((g ^ (row & 7)) << 3)),
          (AS3 void*)&Vs[(p * 256 + wid * 64) * 8], 16, 0, 0);
    }
    __syncthreads();

    f32x4 sacc[2][4];
#pragma unroll
    for (int mi = 0; mi < 2; ++mi)
#pragma unroll
      for (int nf = 0; nf < 4; ++nf) sacc[mi][nf] = (f32x4){0.f, 0.f, 0.f, 0.f};
#pragma unroll
    for (int kc = 0; kc < 4; ++kc) {
      bf16x8 kf[4];
#pragma unroll
      for (int nf = 0; nf < 4; ++nf) {
        const int row = nf * 16 + row16;
        kf[nf] = *(const bf16x8*)&Ks[(row * 16 + ((kc * 4 + kg) ^ (row & 7))) * 8];
      }
#pragma unroll
      for (int mi = 0; mi < 2; ++mi)
#pragma unroll
        for (int nf = 0; nf < 4; ++nf)
          sacc[mi][nf] =
              __builtin_amdgcn_mfma_f32_16x16x32_bf16(qf[mi][kc], kf[nf], sacc[mi][nf], 0, 0, 0);
    }

    float fac[2][4];
#pragma unroll
    for (int mi = 0; mi < 2; ++mi)
#pragma unroll
      for (int r = 0; r < 4; ++r) {
        float rm = sacc[mi][0][r];
#pragma unroll
        for (int nf = 1; nf < 4; ++nf) rm = fmaxf(rm, sacc[mi][nf][r]);
        rm = fmaxf(rm, __shfl_xor(rm, 1, 64));
        rm = fmaxf(rm, __shfl_xor(rm, 2, 64));
        rm = fmaxf(rm, __shfl_xor(rm, 4, 64));
        rm = fmaxf(rm, __shfl_xor(rm, 8, 64));
        const float mnew = fmaxf(mst[mi][r], rm * iscale);
        fac[mi][r] = __expf(mst[mi][r] - mnew);
        mst[mi][r] = mnew;
#pragma unroll
        for (int nf = 0; nf < 4; ++nf)
          sacc[mi][nf][r] = __expf(sacc[mi][nf][r] * iscale - mnew);
      }
#pragma unroll
    for (int mi = 0; mi < 2; ++mi)
#pragma unroll
      for (int r = 0; r < 4; ++r) {
        lacc[mi][r] *= fac[mi][r];
#pragma unroll
        for (int nd = 0; nd < 8; ++nd) oacc[mi][nd][r] *= fac[mi][r];
      }

#pragma unroll
    for (int mi = 0; mi < 2; ++mi)
#pragma unroll
      for (int nf = 0; nf < 4; ++nf)
#pragma unroll
        for (int r = 0; r < 4; ++r) {
          const int row = mi * 16 + kg * 4 + r;
          const int col = nf * 16 + row16;
          Pw[(row * 8 + ((col >> 3) ^ (row & 7))) * 8 + (col & 7)] = (bf16)sacc[mi][nf][r];
        }

#pragma unroll
    for (int kvc = 0; kvc < 2; ++kvc) {
      bf16x8 pf[2], vf[8];
#pragma unroll
      for (int mi = 0; mi < 2; ++mi) {
        const int row = mi * 16 + row16;
        pf[mi] = *(const bf16x8*)&Pw[(row * 8 + ((kvc * 4 + kg) ^ (row & 7))) * 8];
      }
#pragma unroll
      for (int nd = 0; nd < 8; ++nd) {
        const int row = nd * 16 + row16;
        vf[nd] = *(const bf16x8*)&Vs[(row * 8 + ((kvc * 4 + kg) ^ (row & 7))) * 8];
      }
#pragma unroll
      for (int mi = 0; mi < 2; ++mi) {
        lacc[mi] = __builtin_amdgcn_mfma_f32_16x16x32_bf16(pf[mi], ones, lacc[mi], 0, 0, 0);
#pragma unroll
        for (int nd = 0; nd < 8; ++nd)
          oacc[mi][nd] =
              __builtin_amdgcn_mfma_f32_16x16x32_bf16(pf[mi], vf[nd], oacc[mi][nd], 0, 0, 0);
      }
    }
    __syncthreads();
  }

  // epilogue: store unnormalized O (bf16) and per-row (m, l)
  bf16* Oz = Opb + (long long)z * 6291456;
#pragma unroll
  for (int mi = 0; mi < 2; ++mi)
#pragma unroll
    for (int nd = 0; nd < 8; ++nd)
#pragma unroll
      for (int r = 0; r < 4; ++r) {
        const int row = q0 + wid * 32 + mi * 16 + kg * 4 + r;
        const int col = h * 128 + nd * 16 + row16;
        Oz[(long long)row * 3072 + col] = (bf16)oacc[mi][nd][r];
      }
  if (row16 == 0) {
#pragma unroll
    for (int mi = 0; mi < 2; ++mi)
#pragma unroll
      for (int r = 0; r < 4; ++r) {
        const int s = q0 + wid * 32 + mi * 16 + kg * 4 + r;
        const long long mi2 = ((long long)z * 49152 + s * 24 + h) * 2;
        mlp[mi2] = mst[mi][r];
        mlp[mi2 + 1] = lacc[mi][r];
      }
  }
}

// combine the 2 KV splits (vectorized: 16 lanes/pair, bf16x8 = 16B/lane)
__global__ __launch_bounds__(256) void fa_combine_k(const bf16* __restrict__ Opb,
                                                    const float* __restrict__ mlp,
                                                    bf16* __restrict__ attn) {
  const int t = threadIdx.x;
  const int pair = blockIdx.x * 16 + (t >> 4);  // s*24 + h
  const int lane16 = t & 15;
  const int s = pair / 24, h = pair % 24;
  const float2 ml0 = *(const float2*)&mlp[(long long)pair * 2];
  const float2 ml1 = *(const float2*)&mlp[(49152LL + pair) * 2];
  const float m = fmaxf(ml0.x, ml1.x);
  const float a0 = __expf(ml0.x - m), a1 = __expf(ml1.x - m);
  const float inv = 1.f / (ml0.y * a0 + ml1.y * a1);
  const long long base = (long long)s * 3072 + h * 128 + lane16 * 8;
  const bf16x8 o0 = *(const bf16x8*)&Opb[base];
  const bf16x8 o1 = *(const bf16x8*)&Opb[6291456LL + base];
  bf16x8 o;
#pragma unroll
  for (int j = 0; j < 8; ++j)
    o[j] = (bf16)(((float)o0[j] * a0 + (float)o1[j] * a1) * inv);
  *(bf16x8*)&attn[base] = o;
}

// ---------------------------------------------------------------------------
// convAll: all 7 weight conversions (f32 [R][C] -> bf16 [C][R]) in one launch.
// interleave16: out row = c0*2 + ((cl>>4)<<5) + (cl&15) + roff (w1/w3).
// ---------------------------------------------------------------------------
__device__ inline void convT_tile(const float* __restrict__ in, bf16* __restrict__ out,
                                  int R, int C, int bx, int by, int interleave16,
                                  int roff) {
  __shared__ float tile[64][65];
  const int t = threadIdx.x;
  const int r0 = by * 64, c0 = bx * 64;
#pragma unroll
  for (int it = 0; it < 4; ++it) {
    const int idx = it * 256 + t;
    const int rl = idx >> 4, c4 = (idx & 15) << 2;
    const float4 v = *(const float4*)&in[(long long)(r0 + rl) * C + c0 + c4];
    tile[rl][c4 + 0] = v.x;
    tile[rl][c4 + 1] = v.y;
    tile[rl][c4 + 2] = v.z;
    tile[rl][c4 + 3] = v.w;
  }
  __syncthreads();
#pragma unroll
  for (int it = 0; it < 4; ++it) {
    const int idx = it * 256 + t;
    const int cl = idx >> 4, r4 = (idx & 15) << 2;
    bf16x4 o;
    o[0] = (bf16)tile[r4 + 0][cl];
    o[1] = (bf16)tile[r4 + 1][cl];
    o[2] = (bf16)tile[r4 + 2][cl];
    o[3] = (bf16)tile[r4 + 3][cl];
    const long long orow = interleave16 ? (long long)(c0 * 2 + ((cl >> 4) << 5) +
                                                      (cl & 15) + roff)
                                        : (long long)(c0 + cl);
    *(bf16x4*)&out[orow * R + r0 + r4] = o;
  }
}

__global__ __launch_bounds__(256) void convAll(
    const float* __restrict__ wq, const float* __restrict__ wk,
    const float* __restrict__ wv, const float* __restrict__ wo,
    const float* __restrict__ w1, const float* __restrict__ w3,
    const float* __restrict__ w2, bf16* __restrict__ wqkvT, bf16* __restrict__ woT,
    bf16* __restrict__ w13T, bf16* __restrict__ w2T) {
  const int id = blockIdx.x;
  if (id < 9216) {
    const int m = id / 2304, l = id % 2304;
    const float* in = m == 0 ? wq : m == 1 ? wk : m == 2 ? wv : wo;
    bf16* out = m < 3 ? wqkvT + (long long)m * 9437184 : woT;
    convT_tile(in, out, 3072, 3072, l % 48, l / 48, 0, 0);
  } else if (id < 21504) {
    int l = id - 9216;
    const int m = l / 6144;
    l %= 6144;
    convT_tile(m ? w3 : w1, w13T, 3072, 8192, l % 128, l / 128, 1, m * 16);
  } else {
    const int l = id - 21504;
    convT_tile(w2, w2T, 8192, 3072, l % 48, l / 48, 0, 0);
  }
}

// merged setup: blocks 0-47 = adaln GEMV+gates; blocks 48-559 = rope tables
__global__ __launch_bounds__(256) void setup_k(const float* __restrict__ ain,
                                               const float* __restrict__ W,
                                               const float* __restrict__ b,
                                               float* __restrict__ adv,
                                               const int* __restrict__ ids,
                                               float* __restrict__ cosT,
                                               float* __restrict__ sinT) {
  const int t = threadIdx.x;
  if (blockIdx.x < 48) {
    __shared__ float a[256];
    a[t] = ain[t];
    __syncthreads();
    const int n = blockIdx.x * 256 + t;
    float acc = b[n];
    for (int k = 0; k < 256; ++k) acc = fmaf(a[k], W[(long long)k * 12288 + n], acc);
    const int chunk = n / 3072;
    adv[n] = (chunk & 1) ? tanhf(acc) : (1.f + acc);
  } else {
    const int i = (blockIdx.x - 48) * 256 + t;  // S*64
    const int s = i >> 6, j = i & 63;
    int ax, fi;
    float d;
    if (j < 8) { ax = 0; fi = j; d = 16.f; }
    else if (j < 36) { ax = 1; fi = j - 8; d = 56.f; }
    else { ax = 2; fi = j - 36; d = 56.f; }
    const float freq = exp2f(-16.f * (float)fi / d);
    const float ang = (float)ids[s * 3 + ax] * freq;
    cosT[i] = cosf(ang);
    sinT[i] = sinf(ang);
  }
}

// xs = rmsnorm(x, w, 1e-6) * scale  -> bf16
__global__ __launch_bounds__(256) void rmsnorm_scale_k(const float* __restrict__ x,
                                                       const float* __restrict__ w,
                                                       const float* __restrict__ scale,
                                                       bf16* __restrict__ out) {
  __shared__ float red[4];
  const int t = threadIdx.x, lane = t & 63, wid = t >> 6;
  const long long base = (long long)blockIdx.x * 3072;
  float v[12];
  float ss = 0.f;
#pragma unroll
  for (int ch = 0; ch < 3; ++ch) {
    const float4 f = *(const float4*)&x[base + ch * 1024 + t * 4];
    v[ch * 4 + 0] = f.x; v[ch * 4 + 1] = f.y; v[ch * 4 + 2] = f.z; v[ch * 4 + 3] = f.w;
    ss += f.x * f.x + f.y * f.y + f.z * f.z + f.w * f.w;
  }
  ss = wsum(ss);
  if (!lane) red[wid] = ss;
  __syncthreads();
  const float r = rsqrtf((red[0] + red[1] + red[2] + red[3]) / 3072.f + 1e-6f);
#pragma unroll
  for (int ch = 0; ch < 3; ++ch) {
    const int col = ch * 1024 + t * 4;
    bf16x4 o;
#pragma unroll
    for (int j = 0; j < 4; ++j) o[j] = (bf16)(v[ch * 4 + j] * r * w[col + j] * scale[col + j]);
    *(bf16x4*)&out[base + col] = o;
  }
}

// ---------------------------------------------------------------------------
// qkprep_k: merged qknorm_rope + vtrans (the two were independent launches
// touching disjoint qkvP regions — q/k cols 0-6143 vs v cols 6144-9215).
// Blocks 0-6143: per (s,h,isK) combine partials + rmsnorm + rope in place.
// Blocks 6144-7679: v partial-sum + transpose into vt.
// ---------------------------------------------------------------------------
__global__ __launch_bounds__(256) void qkprep_k(bf16* __restrict__ qkvP,
                                                bf16* __restrict__ vt,
                                                const float* __restrict__ cosT,
                                                const float* __restrict__ sinT,
                                                const float* __restrict__ wq,
                                                const float* __restrict__ wk) {
  const int t = threadIdx.x;
  if (blockIdx.x < 6144) {
    const int bx = blockIdx.x;
    const int isK = bx >= 3072;
    const int bxx = isK ? bx - 3072 : bx;
    const int idx = bxx * 16 + (t >> 4);  // s*24 + h
    const int lane16 = t & 15;
    const int s = idx / 24, h = idx % 24;
    bf16* base = qkvP + (long long)s * 9216 + isK * 3072 + h * 128 + lane16 * 8;
    const bf16x8 p0 = *(const bf16x8*)base;
    const bf16x8 p1 = *(const bf16x8*)(base + 18874368LL);
    float xv[8];
    float ss = 0.f;
#pragma unroll
    for (int j = 0; j < 8; ++j) {
      xv[j] = (float)p0[j] + (float)p1[j];
      ss += xv[j] * xv[j];
    }
    ss += __shfl_xor(ss, 1, 64);
    ss += __shfl_xor(ss, 2, 64);
    ss += __shfl_xor(ss, 4, 64);
    ss += __shfl_xor(ss, 8, 64);
    const float r = rsqrtf(ss / 128.f + 1e-5f);
    const float* w = isK ? wk : wq;
    const float4 w0 = *(const float4*)&w[lane16 * 8];
    const float4 w1 = *(const float4*)&w[lane16 * 8 + 4];
    const float wa[8] = {w0.x, w0.y, w0.z, w0.w, w1.x, w1.y, w1.z, w1.w};
    const float4 cs = *(const float4*)&cosT[s * 64 + lane16 * 4];
    const float4 sn = *(const float4*)&sinT[s * 64 + lane16 * 4];
    const float cc[4] = {cs.x, cs.y, cs.z, cs.w};
    const float sv[4] = {sn.x, sn.y, sn.z, sn.w};
    bf16x8 o;
#pragma unroll
    for (int p = 0; p < 4; ++p) {
      const float xr = xv[2 * p] * r * wa[2 * p];
      const float xi = xv[2 * p + 1] * r * wa[2 * p + 1];
      o[2 * p]     = (bf16)(xr * cc[p] - xi * sv[p]);
      o[2 * p + 1] = (bf16)(xr * sv[p] + xi * cc[p]);
    }
    *(bf16x8*)base = o;
  } else {
    __shared__ bf16 tile[64][72];
    const int l = blockIdx.x - 6144;      // 1536 blocks = 32 x 2 x 24
    const int h = l / 64;
    const int rem = l % 64;
    const int d0 = (rem / 32) * 64;
    const int s0 = (rem % 32) * 64;
#pragma unroll
    for (int it = 0; it < 2; ++it) {
      const int idx = it * 256 + t;
      const int sl = idx >> 3, c8 = (idx & 7) << 3;
      const long long base = (long long)(s0 + sl) * 9216 + 6144 + h * 128 + d0 + c8;
      const bf16x8 v0 = *(const bf16x8*)&qkvP[base];
      const bf16x8 v1 = *(const bf16x8*)&qkvP[base + 18874368LL];
      bf16x8 v;
#pragma unroll
      for (int j = 0; j < 8; ++j) v[j] = (bf16)((float)v0[j] + (float)v1[j]);
      *(bf16x8*)&tile[sl][c8] = v;
    }
    __syncthreads();
#pragma unroll
    for (int it = 0; it < 2; ++it) {
      const int idx = it * 256 + t;
      const int dl = idx >> 3, s8 = (idx & 7) << 3;
      bf16x8 o;
#pragma unroll
      for (int j = 0; j < 8; ++j) o[j] = tile[s8 + j][dl];
      *(bf16x8*)&vt[(long long)h * 262144 + (long long)(d0 + dl) * 2048 + s0 + s8] = o;
    }
  }
}

// x1 = x + gate*rmsnorm(p0+p1, n2w, 1e-6); xf = rmsnorm(x1, f1w, 1e-6)*smlp (bf16)
__global__ __launch_bounds__(256) void resid1_k(
    const float* __restrict__ x, const bf16* __restrict__ p0, const bf16* __restrict__ p1,
    const float* __restrict__ n2w, const float* __restrict__ gate,
    const float* __restrict__ f1w, const float* __restrict__ smlp,
    float* __restrict__ x1, bf16* __restrict__ xf) {
  __shared__ float red[8];
  const int t = threadIdx.x, lane = t & 63, wid = t >> 6;
  const long long base = (long long)blockIdx.x * 3072;
  float av[12];
  float ss = 0.f;
#pragma unroll
  for (int ch = 0; ch < 3; ++ch) {
    const bf16x4 f0 = *(const bf16x4*)&p0[base + ch * 1024 + t * 4];
    const bf16x4 f1 = *(const bf16x4*)&p1[base + ch * 1024 + t * 4];
#pragma unroll
    for (int j = 0; j < 4; ++j) {
      const float a = (float)f0[j] + (float)f1[j];
      av[ch * 4 + j] = a;
      ss += a * a;
    }
  }
  ss = wsum(ss);
  if (!lane) red[wid] = ss;
  __syncthreads();
  const float r = rsqrtf((red[0] + red[1] + red[2] + red[3]) / 3072.f + 1e-6f);
  float xv[12];
  float ss2 = 0.f;
#pragma unroll
  for (int ch = 0; ch < 3; ++ch) {
    const int col = ch * 1024 + t * 4;
    const float4 f = *(const float4*)&x[base + col];
    float4 o;
    o.x = f.x + gate[col + 0] * (av[ch * 4 + 0] * r * n2w[col + 0]);
    o.y = f.y + gate[col + 1] * (av[ch * 4 + 1] * r * n2w[col + 1]);
    o.z = f.z + gate[col + 2] * (av[ch * 4 + 2] * r * n2w[col + 2]);
    o.w = f.w + gate[col + 3] * (av[ch * 4 + 3] * r * n2w[col + 3]);
    *(float4*)&x1[base + col] = o;
    xv[ch * 4 + 0] = o.x; xv[ch * 4 + 1] = o.y; xv[ch * 4 + 2] = o.z; xv[ch * 4 + 3] = o.w;
    ss2 += o.x * o.x + o.y * o.y + o.z * o.z + o.w * o.w;
  }
  ss2 = wsum(ss2);
  if (!lane) red[4 + wid] = ss2;
  __syncthreads();
  const float r2 = rsqrtf((red[4] + red[5] + red[6] + red[7]) / 3072.f + 1e-6f);
#pragma unroll
  for (int ch = 0; ch < 3; ++ch) {
    const int col = ch * 1024 + t * 4;
    bf16x4 o;
#pragma unroll
    for (int j = 0; j < 4; ++j)
      o[j] = (bf16)(xv[ch * 4 + j] * r2 * f1w[col + j] * smlp[col + j]);
    *(bf16x4*)&xf[base + col] = o;
  }
}

// out = x1 + gate*rmsnorm(f0+f1, nw, 1e-6)  (f32 output; f0/f1 bf16 partials)
__global__ __launch_bounds__(256) void resid2_k(const float* __restrict__ x1,
                                                const bf16* __restrict__ f0,
                                                const bf16* __restrict__ f1,
                                                const float* __restrict__ nw,
                                                const float* __restrict__ gate,
                                                float* __restrict__ out) {
  __shared__ float red[4];
  const int t = threadIdx.x, lane = t & 63, wid = t >> 6;
  const long long base = (long long)blockIdx.x * 3072;
  float fv[12];
  float ss = 0.f;
#pragma unroll
  for (int ch = 0; ch < 3; ++ch) {
    const bf16x4 a = *(const bf16x4*)&f0[base + ch * 1024 + t * 4];
    const bf16x4 b = *(const bf16x4*)&f1[base + ch * 1024 + t * 4];
#pragma unroll
    for (int j = 0; j < 4; ++j) {
      const float v = (float)a[j] + (float)b[j];
      fv[ch * 4 + j] = v;
      ss += v * v;
    }
  }
  ss = wsum(ss);
  if (!lane) red[wid] = ss;
  __syncthreads();
  const float r = rsqrtf((red[0] + red[1] + red[2] + red[3]) / 3072.f + 1e-6f);
#pragma unroll
  for (int ch = 0; ch < 3; ++ch) {
    const int col = ch * 1024 + t * 4;
    const float4 f = *(const float4*)&x1[base + col];
    float4 o;
    o.x = f.x + gate[col + 0] * (fv[ch * 4 + 0] * r * nw[col + 0]);
    o.y = f.y + gate[col + 1] * (fv[ch * 4 + 1] * r * nw[col + 1]);
    o.z = f.z + gate[col + 2] * (fv[ch * 4 + 2] * r * nw[col + 2]);
    o.w = f.w + gate[col + 3] * (fv[ch * 4 + 3] * r * nw[col + 3]);
    *(float4*)&out[base + col] = o;
  }
}

extern "C" void kernel_launch(void* const* d_in, const int* in_sizes, int n_in,
                              void* d_out, int out_size, void* d_ws, size_t ws_size,
                              hipStream_t stream) {
  const float* x    = (const float*)d_in[0];
  const float* ain  = (const float*)d_in[1];
  const int* ids    = (const int*)d_in[3];
  const float* n1w  = (const float*)d_in[4];
  const float* n2w  = (const float*)d_in[5];
  const float* fn1w = (const float*)d_in[6];
  const float* fn2w = (const float*)d_in[7];
  const float* nqw  = (const float*)d_in[8];
  const float* nkw  = (const float*)d_in[9];
  const float* wq   = (const float*)d_in[10];
  const float* wk   = (const float*)d_in[11];
  const float* wv   = (const float*)d_in[12];
  const float* wo   = (const float*)d_in[13];
  const float* w1   = (const float*)d_in[14];
  const float* w2   = (const float*)d_in[15];
  const float* w3   = (const float*)d_in[16];
  const float* adw  = (const float*)d_in[17];
  const float* adb  = (const float*)d_in[18];

  if (ws_size < 395362304ULL) return;

  char* ws = (char*)d_ws;
  bf16* wqkvT = (bf16*)(ws + 0LL);             // [9216][3072]
  bf16* woT   = (bf16*)(ws + 56623104LL);      // [3072][3072]
  bf16* w13T  = (bf16*)(ws + 75497472LL);      // [16384][3072] 16-granular interleave
  bf16* w2T   = (bf16*)(ws + 176160768LL);     // [3072][8192]
  float* cosT = (float*)(ws + 226492416LL);    // [2048][64]
  float* sinT = (float*)(ws + 227016704LL);
  float* adv  = (float*)(ws + 227540992LL);    // [4][3072]
  bf16* xs    = (bf16*)(ws + 227590144LL);     // [2048][3072], reused as xf
  char* big   = ws + 240173056LL;              // overlay region (155,189,248 B)
  float* x1   = (float*)(big);                 // 0 .. 25165824
  bf16* qkvP  = (bf16*)(big + 25165824LL);     // [2][2048][9216] .. 100663296
  bf16* vt    = (bf16*)(big + 100663296LL);    // [24][128][2048] .. 113246208
  bf16* attn  = (bf16*)(big + 113246208LL);    // [2048][3072]    .. 125829120
  bf16* Opb   = (bf16*)(big + 125829120LL);    // [2][2048][3072] .. 150994944
  float* mlp  = (float*)(big + 150994944LL);   // [2][49152][2]   .. 151781376
  bf16* aoP   = (bf16*)(big + 25165824LL);     // [2][2048][3072] (qkvP dead)
  bf16* hbuf  = (bf16*)(big + 50331648LL);     // [2048][8192] (aoP dead after resid1)
  bf16* ffnP  = (bf16*)(big + 83886080LL);     // [2][2048][3072] .. 109051904

  const dim3 b256(256);
  const dim3 b512(512);

  setup_k<<<dim3(560), b256, 0, stream>>>(ain, adw, adb, adv, ids, cosT, sinT);

  convAll<<<dim3(27648), b256, 0, stream>>>(wq, wk, wv, wo, w1, w3, w2, wqkvT, woT, w13T,
                                            w2T);

  rmsnorm_scale_k<<<dim3(2048), b256, 0, stream>>>(x, n1w, adv, xs);

  // QKV: split-K z=2 (768 blocks = 3 exact rounds); partial-sum folded into
  // the consumers below.
  gemm192<1><<<dim3(8, 48, 2), b512, 0, stream>>>(xs, wqkvT, qkvP, 1536, 3072, 3072, 9216,
                                                  1536LL, 18874368LL);

  // merged: combine partials + norm + rope in place (q,k) AND v-sum+transpose
  qkprep_k<<<dim3(7680), b256, 0, stream>>>(qkvP, vt, cosT, sinT, nqw, nkw);

  // flash attention (reads qkvP[0] with stride 9216) + vectorized combine
  flash_attn_k<<<dim3(16, 24, 2), b256, 0, stream>>>(qkvP, vt, Opb, mlp);
  fa_combine_k<<<dim3(3072), b256, 0, stream>>>(Opb, mlp, attn);

  // Wo: attn @ woT^T, split-K 2, bf16 partials (gemm192: grid 256 exact)
  gemm192<1><<<dim3(8, 16, 2), b512, 0, stream>>>(attn, woT, aoP, 1536, 3072, 3072, 3072,
                                                  1536LL, 6291456LL);
  resid1_k<<<dim3(2048), b256, 0, stream>>>(x, aoP, aoP + 6291456LL, n2w, adv + 3072, fn1w,
                                            adv + 6144, x1, xs);
  // FFN up + fused silu-mul (16-granular interleave): xf @ w13T^T -> hbuf bf16
  gemm256<2><<<dim3(8, 64, 1), b512, 0, stream>>>(xs, w13T, hbuf, 3072, 3072, 3072, 8192,
                                                  0LL, 0LL);
  // FFN down: h @ w2T^T, split-K 2, bf16 partials (gemm192: grid 256 exact)
  gemm192<1><<<dim3(8, 16, 2), b512, 0, stream>>>(hbuf, w2T, ffnP, 4096, 8192, 8192, 3072,
                                                  4096LL, 6291456LL);
  resid2_k<<<dim3(2048), b256, 0, stream>>>(x1, ffnP, ffnP + 6291456LL, fn2w, adv + 9216,
                                            (float*)d_out);
}